// Round 1
// baseline (1361.046 us; speedup 1.0000x reference)
//
#include <hip/hip_runtime.h>

#define N_ 32
#define C_ 64
#define T_ 400
#define V_ 27
#define S_ 2
#define CI_ 16
#define CO_ 64
#define TCHUNK 8
#define NCHUNK 50            // T_/TCHUNK
#define ATT_N 1458           // S_*V_*V_
#define TT 4                 // t-tile in fused kernel

// ---------------- K1: qk partial outer products -> ws ----------------
__global__ __launch_bounds__(256) void k1_qk_partial(
    const float* __restrict__ x, const float* __restrict__ pe,
    const float* __restrict__ w_in, const float* __restrict__ b_in,
    float* __restrict__ partial)
{
  const int n = blockIdx.x;
  const int chunk = blockIdx.y;
  const int tid = threadIdx.x;
  __shared__ float ylds[C_][28];
  __shared__ float qlds[C_][28];
  __shared__ float wlds[C_][65];
  for (int i = tid; i < C_ * C_; i += 256) wlds[i >> 6][i & 63] = w_in[i];
  float acc[6];
#pragma unroll
  for (int j = 0; j < 6; ++j) acc[j] = 0.f;
  const int t0 = chunk * TCHUNK;
  for (int tt = 0; tt < TCHUNK; ++tt) {
    const int t = t0 + tt;
    __syncthreads();
    for (int i = tid; i < C_ * V_; i += 256) {
      int c = i / V_, v = i - c * V_;
      ylds[c][v] = x[((size_t)(n * C_ + c) * T_ + t) * V_ + v] + pe[(c * T_ + t) * V_ + v];
    }
    __syncthreads();
    for (int i = tid; i < C_ * V_; i += 256) {
      int o = i / V_, v = i - o * V_;
      float s = b_in[o];
#pragma unroll
      for (int c = 0; c < C_; ++c) s += wlds[o][c] * ylds[c][v];
      qlds[o][v] = s;
    }
    __syncthreads();
#pragma unroll
    for (int j = 0; j < 6; ++j) {
      int i = tid + j * 256;
      if (i < ATT_N) {
        int s = i / 729, r = i - s * 729, u = r / 27, v = r - u * 27;
        float a = 0.f;
#pragma unroll
        for (int c = 0; c < CI_; ++c)
          a += qlds[s * CI_ + c][u] * qlds[S_ * CI_ + s * CI_ + c][v];
        acc[j] += a;
      }
    }
  }
  float* dst = partial + (size_t)(n * NCHUNK + chunk) * ATT_N;
#pragma unroll
  for (int j = 0; j < 6; ++j) {
    int i = tid + j * 256;
    if (i < ATT_N) dst[i] = acc[j];
  }
}

// ---------------- K2: reduce partials, finalize att ----------------
__global__ __launch_bounds__(256) void k2_att_fin(
    const float* __restrict__ partial, const float* __restrict__ alphas,
    const float* __restrict__ att0, float* __restrict__ att)
{
  int i = blockIdx.x * 256 + threadIdx.x;
  if (i >= N_ * ATT_N) return;
  int n = i / ATT_N, r = i - n * ATT_N;
  int s = r / 729;
  float a = 0.f;
  const float* p = partial + (size_t)n * NCHUNK * ATT_N + r;
  for (int ch = 0; ch < NCHUNK; ++ch) a += p[(size_t)ch * ATT_N];
  a = tanhf(a * (1.0f / (CI_ * (float)T_))) * alphas[s] + att0[r];
  att[i] = a;
}

// ---------------- K3: fused x*att -> w_out -> bn1 -> w_ff -> bn2 -> conv_t -> bn3 ----------------
__global__ __launch_bounds__(256) void k3_main(
    const float* __restrict__ x, const float* __restrict__ att,
    const float* __restrict__ w_out, const float* __restrict__ b_out,
    const float* __restrict__ bn1_g, const float* __restrict__ bn1_b,
    const float* __restrict__ bn1_m, const float* __restrict__ bn1_v,
    const float* __restrict__ w_ff, const float* __restrict__ b_ff,
    const float* __restrict__ bn2_g, const float* __restrict__ bn2_b,
    const float* __restrict__ bn2_m, const float* __restrict__ bn2_v,
    const float* __restrict__ w_t, const float* __restrict__ b_t,
    const float* __restrict__ bn3_g, const float* __restrict__ bn3_b,
    const float* __restrict__ bn3_m, const float* __restrict__ bn3_v,
    float* __restrict__ out)
{
  const int n = blockIdx.x;
  const int t0 = blockIdx.y * TT;
  const int tid = threadIdx.x;
  __shared__ float xlds[C_][28];
  __shared__ float attlds[S_][V_][28];
  __shared__ float y2lds[S_ * C_][28];
  __shared__ float h1lds[C_][28];
  __shared__ float h2ring[TT + 2][C_][28];

  // load att for this n (pad col zeroed)
  for (int i = tid; i < S_ * V_ * 28; i += 256) {
    int s = i / (V_ * 28), r2 = i - s * V_ * 28, u = r2 / 28, v = r2 - u * 28;
    attlds[s][u][v] = (v < V_) ? att[(size_t)n * ATT_N + s * 729 + u * 27 + v] : 0.f;
  }

  // mapping for phases 3/4/conv: 4 lanes per o, 8-aligned v blocks
  const int o  = tid >> 2;
  const int rr = tid & 3;
  const int v0 = rr * 8;
  const int nv = (27 - v0) < 8 ? (27 - v0) : 8;   // 8,8,8,3
  const float bo  = b_out[o];
  const float s1  = bn1_g[o] * rsqrtf(bn1_v[o] + 1e-5f);
  const float m1  = bn1_m[o];
  const float bb1 = bn1_b[o];
  const float bf  = b_ff[o];
  const float s2  = bn2_g[o] * rsqrtf(bn2_v[o] + 1e-5f);
  const float m2  = bn2_m[o];
  const float bb2 = bn2_b[o];
  const float bt  = b_t[o];
  const float s3  = bn3_g[o] * rsqrtf(bn3_v[o] + 1e-5f);
  const float m3  = bn3_m[o];
  const float bb3 = bn3_b[o];
  // mapping for phase2: 2 lanes per sc, 16-aligned v blocks
  const int sc   = tid >> 1;
  const int r2b  = tid & 1;
  const int w0   = r2b * 16;
  const int nw   = r2b ? 11 : 16;
  const int s_p2 = sc >> 6, c_p2 = sc & 63;

  for (int sl = 0; sl < TT + 2; ++sl) {
    const int t = t0 - 1 + sl;
    __syncthreads();
    if (t < 0 || t >= T_) {
      for (int i = tid; i < C_ * 28; i += 256) ((float*)h2ring[sl])[i] = 0.f;
      continue;
    }
    for (int i = tid; i < C_ * V_; i += 256) {
      int c = i / V_, v = i - c * V_;
      xlds[c][v] = x[((size_t)(n * C_ + c) * T_ + t) * V_ + v];
    }
    __syncthreads();
    // phase2: y2[sc][v] = sum_u x[c][u] * att[s][u][v]
    {
      float acc[16];
#pragma unroll
      for (int j = 0; j < 16; ++j) acc[j] = 0.f;
      for (int u = 0; u < V_; ++u) {
        float xv = xlds[c_p2][u];
#pragma unroll
        for (int j = 0; j < 16; ++j) acc[j] += xv * attlds[s_p2][u][w0 + j];
      }
#pragma unroll
      for (int j = 0; j < 16; ++j) if (j < nw) y2lds[sc][w0 + j] = acc[j];
      if (r2b) y2lds[sc][27] = 0.f;
    }
    __syncthreads();
    // phase3: h1 = lrelu(x + bn1(w_out @ y2))
    {
      float acc[8];
#pragma unroll
      for (int j = 0; j < 8; ++j) acc[j] = bo;
#pragma unroll 4
      for (int k = 0; k < S_ * C_; ++k) {
        float w = w_out[o * (S_ * C_) + k];
#pragma unroll
        for (int j = 0; j < 8; ++j) acc[j] += w * y2lds[k][v0 + j];
      }
#pragma unroll
      for (int j = 0; j < 8; ++j) if (j < nv) {
        float h = (acc[j] - m1) * s1 + bb1 + xlds[o][v0 + j];
        h1lds[o][v0 + j] = (h >= 0.f) ? h : 0.1f * h;
      }
      if (rr == 3) h1lds[o][27] = 0.f;
    }
    __syncthreads();
    // phase4: h2 = lrelu(x + bn2(w_ff @ h1))
    {
      float acc[8];
#pragma unroll
      for (int j = 0; j < 8; ++j) acc[j] = bf;
#pragma unroll 4
      for (int k = 0; k < C_; ++k) {
        float w = w_ff[o * C_ + k];
#pragma unroll
        for (int j = 0; j < 8; ++j) acc[j] += w * h1lds[k][v0 + j];
      }
#pragma unroll
      for (int j = 0; j < 8; ++j) if (j < nv) {
        float h = (acc[j] - m2) * s2 + bb2 + xlds[o][v0 + j];
        h2ring[sl][o][v0 + j] = (h >= 0.f) ? h : 0.1f * h;
      }
      if (rr == 3) h2ring[sl][o][27] = 0.f;
    }
  }
  __syncthreads();
  // conv_t (3 taps) + bn3 + residual + lrelu -> out
  for (int j = 0; j < TT; ++j) {
    const int t = t0 + j;
    float acc[8];
#pragma unroll
    for (int q = 0; q < 8; ++q) acc[q] = bt;
#pragma unroll 2
    for (int i = 0; i < C_; ++i) {
      float wta = w_t[(o * C_ + i) * 3 + 0];
      float wtb = w_t[(o * C_ + i) * 3 + 1];
      float wtc = w_t[(o * C_ + i) * 3 + 2];
#pragma unroll
      for (int q = 0; q < 8; ++q) {
        acc[q] += wta * h2ring[j][i][v0 + q]
                + wtb * h2ring[j + 1][i][v0 + q]
                + wtc * h2ring[j + 2][i][v0 + q];
      }
    }
#pragma unroll
    for (int q = 0; q < 8; ++q) if (q < nv) {
      float h2c = h2ring[j + 1][o][v0 + q];
      float h = (acc[q] - m3) * s3 + bb3 + h2c;
      out[((size_t)(n * CO_ + o) * T_ + t) * V_ + v0 + q] = (h >= 0.f) ? h : 0.1f * h;
    }
  }
}

extern "C" void kernel_launch(void* const* d_in, const int* in_sizes, int n_in,
                              void* d_out, int out_size, void* d_ws, size_t ws_size,
                              hipStream_t stream)
{
  (void)in_sizes; (void)n_in; (void)out_size; (void)ws_size;
  const float* x      = (const float*)d_in[0];
  const float* pe     = (const float*)d_in[1];
  const float* w_in   = (const float*)d_in[2];
  const float* b_in   = (const float*)d_in[3];
  const float* alphas = (const float*)d_in[4];
  const float* att0   = (const float*)d_in[5];
  const float* w_out  = (const float*)d_in[6];
  const float* b_out  = (const float*)d_in[7];
  const float* bn1_g  = (const float*)d_in[8];
  const float* bn1_b  = (const float*)d_in[9];
  const float* bn1_m  = (const float*)d_in[10];
  const float* bn1_v  = (const float*)d_in[11];
  const float* w_ff   = (const float*)d_in[12];
  const float* b_ff   = (const float*)d_in[13];
  const float* bn2_g  = (const float*)d_in[14];
  const float* bn2_b  = (const float*)d_in[15];
  const float* bn2_m  = (const float*)d_in[16];
  const float* bn2_v  = (const float*)d_in[17];
  const float* w_t    = (const float*)d_in[18];
  const float* b_t    = (const float*)d_in[19];
  const float* bn3_g  = (const float*)d_in[20];
  const float* bn3_b  = (const float*)d_in[21];
  const float* bn3_m  = (const float*)d_in[22];
  const float* bn3_v  = (const float*)d_in[23];
  float* out = (float*)d_out;

  float* partial = (float*)d_ws;                           // N*NCHUNK*ATT_N floats
  float* att     = partial + (size_t)N_ * NCHUNK * ATT_N;  // N*ATT_N floats

  k1_qk_partial<<<dim3(N_, NCHUNK), 256, 0, stream>>>(x, pe, w_in, b_in, partial);
  k2_att_fin<<<(N_ * ATT_N + 255) / 256, 256, 0, stream>>>(partial, alphas, att0, att);
  k3_main<<<dim3(N_, T_ / TT), 256, 0, stream>>>(x, att,
      w_out, b_out, bn1_g, bn1_b, bn1_m, bn1_v,
      w_ff, b_ff, bn2_g, bn2_b, bn2_m, bn2_v,
      w_t, b_t, bn3_g, bn3_b, bn3_m, bn3_v, out);
}

// Round 2
// 1096.894 us; speedup vs baseline: 1.2408x; 1.2408x over previous
//
#include <hip/hip_runtime.h>

#define N_ 32
#define C_ 64
#define T_ 400
#define V_ 27
#define S_ 2
#define CI_ 16
#define CO_ 64
#define TCHUNK 8
#define NCHUNK 50            // T_/TCHUNK
#define ATT_N 1458           // S_*V_*V_
#define TT 4                 // t-tile in fallback fused kernel

// ---------------- K1: qk partial outer products -> ws ----------------
__global__ __launch_bounds__(256) void k1_qk_partial(
    const float* __restrict__ x, const float* __restrict__ pe,
    const float* __restrict__ w_in, const float* __restrict__ b_in,
    float* __restrict__ partial)
{
  const int n = blockIdx.x;
  const int chunk = blockIdx.y;
  const int tid = threadIdx.x;
  __shared__ float ylds[C_][28];
  __shared__ float qlds[C_][28];
  __shared__ float wlds[C_][65];
  for (int i = tid; i < C_ * C_; i += 256) wlds[i >> 6][i & 63] = w_in[i];
  float acc[6];
#pragma unroll
  for (int j = 0; j < 6; ++j) acc[j] = 0.f;
  const int t0 = chunk * TCHUNK;
  for (int tt = 0; tt < TCHUNK; ++tt) {
    const int t = t0 + tt;
    __syncthreads();
    for (int i = tid; i < C_ * V_; i += 256) {
      int c = i / V_, v = i - c * V_;
      ylds[c][v] = x[((size_t)(n * C_ + c) * T_ + t) * V_ + v] + pe[(c * T_ + t) * V_ + v];
    }
    __syncthreads();
    for (int i = tid; i < C_ * V_; i += 256) {
      int o = i / V_, v = i - o * V_;
      float s = b_in[o];
#pragma unroll
      for (int c = 0; c < C_; ++c) s += wlds[o][c] * ylds[c][v];
      qlds[o][v] = s;
    }
    __syncthreads();
#pragma unroll
    for (int j = 0; j < 6; ++j) {
      int i = tid + j * 256;
      if (i < ATT_N) {
        int s = i / 729, r = i - s * 729, u = r / 27, v = r - u * 27;
        float a = 0.f;
#pragma unroll
        for (int c = 0; c < CI_; ++c)
          a += qlds[s * CI_ + c][u] * qlds[S_ * CI_ + s * CI_ + c][v];
        acc[j] += a;
      }
    }
  }
  float* dst = partial + (size_t)(n * NCHUNK + chunk) * ATT_N;
#pragma unroll
  for (int j = 0; j < 6; ++j) {
    int i = tid + j * 256;
    if (i < ATT_N) dst[i] = acc[j];
  }
}

// ---------------- K2: reduce partials, finalize att ----------------
__global__ __launch_bounds__(256) void k2_att_fin(
    const float* __restrict__ partial, const float* __restrict__ alphas,
    const float* __restrict__ att0, float* __restrict__ att)
{
  int i = blockIdx.x * 256 + threadIdx.x;
  if (i >= N_ * ATT_N) return;
  int n = i / ATT_N, r = i - n * ATT_N;
  int s = r / 729;
  float a = 0.f;
  const float* p = partial + (size_t)n * NCHUNK * ATT_N + r;
  for (int ch = 0; ch < NCHUNK; ++ch) a += p[(size_t)ch * ATT_N];
  a = tanhf(a * (1.0f / (CI_ * (float)T_))) * alphas[s] + att0[r];
  att[i] = a;
}

// ---------------- K3a: x*att -> w_out -> bn1 -> w_ff -> bn2 -> h2(global) ----------------
// lanes: v = tid&31 (valid <27), tloc = (tid>>5)&1, wave rg = tid>>6 owns 16 output rows.
__global__ __launch_bounds__(256) void k3a(
    const float* __restrict__ x, const float* __restrict__ att,
    const float* __restrict__ w_out, const float* __restrict__ b_out,
    const float* __restrict__ bn1_g, const float* __restrict__ bn1_b,
    const float* __restrict__ bn1_m, const float* __restrict__ bn1_v,
    const float* __restrict__ w_ff, const float* __restrict__ b_ff,
    const float* __restrict__ bn2_g, const float* __restrict__ bn2_b,
    const float* __restrict__ bn2_m, const float* __restrict__ bn2_v,
    float* __restrict__ h2g)
{
  const int n = blockIdx.x;
  const int t0 = blockIdx.y * 2;
  const int tid = threadIdx.x;
  const int v = tid & 31;
  const int tloc = (tid >> 5) & 1;
  const int col = tid & 63;
  const int rg = __builtin_amdgcn_readfirstlane(tid >> 6);
  const int t = t0 + tloc;

  __shared__ float xlds[C_][64];          // [c][tloc*32+v]
  __shared__ float zlds[S_ * C_][64];     // [s*64+c][col]; rows 0..63 reused as H1

  // stage x
  for (int i = tid; i < C_ * 64; i += 256) {
    int c = i >> 6, cl = i & 63, tl = cl >> 5, vv = cl & 31;
    xlds[c][cl] = (vv < V_) ? x[((size_t)(n * C_ + c) * T_ + t0 + tl) * V_ + vv] : 0.f;
  }
  // att column for this lane's v, both s, all u  (54 regs)
  float attreg[S_][V_];
  {
    const float* ab = att + (size_t)n * ATT_N + v;
#pragma unroll
    for (int s = 0; s < S_; ++s)
#pragma unroll
      for (int u = 0; u < V_; ++u)
        attreg[s][u] = (v < V_) ? ab[s * 729 + u * 27] : 0.f;
  }
  __syncthreads();

  // ---- phase 2: Z[(s, rg*16+cc)][col] = sum_u x[c][t,u] * att[s][u][v] ----
#pragma unroll 1
  for (int cc = 0; cc < 16; ++cc) {
    const int c = rg * 16 + cc;
    float xr[V_];
#pragma unroll
    for (int u = 0; u < V_; ++u) xr[u] = xlds[c][tloc * 32 + u];
    float a0 = 0.f, a1 = 0.f;
#pragma unroll
    for (int u = 0; u < V_; ++u) {
      a0 += xr[u] * attreg[0][u];
      a1 += xr[u] * attreg[1][u];
    }
    zlds[c][col] = a0;
    zlds[C_ + c][col] = a1;
  }
  __syncthreads();

  // ---- phase 3: y3[o] = w_out[o, :] . Z[:, col]  (weights via scalar loads) ----
  float acc[16];
#pragma unroll
  for (int oo = 0; oo < 16; ++oo) acc[oo] = 0.f;
#pragma unroll 1
  for (int kc = 0; kc < 4; ++kc) {
    float zk[32];
#pragma unroll
    for (int j = 0; j < 32; ++j) zk[j] = zlds[kc * 32 + j][col];
#pragma unroll
    for (int oo = 0; oo < 16; ++oo) {
      const float* wr = w_out + (rg * 16 + oo) * (S_ * C_) + kc * 32;
      float s = acc[oo];
#pragma unroll
      for (int j = 0; j < 32; ++j) s += wr[j] * zk[j];
      acc[oo] = s;
    }
  }
  float h1v[16];
#pragma unroll
  for (int oo = 0; oo < 16; ++oo) {
    const int o = rg * 16 + oo;
    float y3 = acc[oo] + b_out[o];
    float h = (y3 - bn1_m[o]) * (bn1_g[o] * rsqrtf(bn1_v[o] + 1e-5f)) + bn1_b[o]
              + xlds[o][col];
    h1v[oo] = (h >= 0.f) ? h : 0.1f * h;
  }
  __syncthreads();          // all waves done reading Z
#pragma unroll
  for (int oo = 0; oo < 16; ++oo) zlds[rg * 16 + oo][col] = h1v[oo];
  __syncthreads();

  // ---- phase 4: f[o] = w_ff[o, :] . H1[:, col] ----
#pragma unroll
  for (int oo = 0; oo < 16; ++oo) acc[oo] = 0.f;
#pragma unroll 1
  for (int kc = 0; kc < 2; ++kc) {
    float zk[32];
#pragma unroll
    for (int j = 0; j < 32; ++j) zk[j] = zlds[kc * 32 + j][col];
#pragma unroll
    for (int oo = 0; oo < 16; ++oo) {
      const float* wr = w_ff + (rg * 16 + oo) * C_ + kc * 32;
      float s = acc[oo];
#pragma unroll
      for (int j = 0; j < 32; ++j) s += wr[j] * zk[j];
      acc[oo] = s;
    }
  }
  if (v < V_) {
#pragma unroll
    for (int oo = 0; oo < 16; ++oo) {
      const int o = rg * 16 + oo;
      float f = acc[oo] + b_ff[o];
      float h = (f - bn2_m[o]) * (bn2_g[o] * rsqrtf(bn2_v[o] + 1e-5f)) + bn2_b[o]
                + xlds[o][col];
      h2g[((size_t)(n * CO_ + o) * T_ + t) * V_ + v] = (h >= 0.f) ? h : 0.1f * h;
    }
  }
}

// ---------------- K3b: temporal conv (3 taps) + bn3 + residual + lrelu ----------------
__global__ __launch_bounds__(256) void k3b(
    const float* __restrict__ h2g, const float* __restrict__ w_t,
    const float* __restrict__ b_t,
    const float* __restrict__ bn3_g, const float* __restrict__ bn3_b,
    const float* __restrict__ bn3_m, const float* __restrict__ bn3_v,
    float* __restrict__ out)
{
  const int n = blockIdx.x;
  const int t0 = blockIdx.y * 2;
  const int tid = threadIdx.x;
  const int v = tid & 31;
  const int tloc = (tid >> 5) & 1;
  const int rg = __builtin_amdgcn_readfirstlane(tid >> 6);
  const int t = t0 + tloc;

  __shared__ float hl[C_][4][32];   // [i][slice t0-1..t0+2][v]

  for (int idx = tid; idx < C_ * 4 * 32; idx += 256) {
    int i = idx >> 7, r = idx & 127, sl = r >> 5, vv = r & 31;
    int tg = t0 - 1 + sl;
    hl[i][sl][vv] = (vv < V_ && tg >= 0 && tg < T_)
                    ? h2g[((size_t)(n * CO_ + i) * T_ + tg) * V_ + vv] : 0.f;
  }
  __syncthreads();

  float acc[16];
#pragma unroll
  for (int oo = 0; oo < 16; ++oo) acc[oo] = 0.f;
#pragma unroll 1
  for (int ic = 0; ic < 4; ++ic) {
    float h[16][3];
#pragma unroll
    for (int ii = 0; ii < 16; ++ii) {
      h[ii][0] = hl[ic * 16 + ii][tloc][v];
      h[ii][1] = hl[ic * 16 + ii][tloc + 1][v];
      h[ii][2] = hl[ic * 16 + ii][tloc + 2][v];
    }
#pragma unroll
    for (int oo = 0; oo < 16; ++oo) {
      const float* wr = w_t + ((size_t)(rg * 16 + oo) * C_ + ic * 16) * 3;
      float s = acc[oo];
#pragma unroll
      for (int ii = 0; ii < 16; ++ii) {
        s += wr[ii * 3 + 0] * h[ii][0]
           + wr[ii * 3 + 1] * h[ii][1]
           + wr[ii * 3 + 2] * h[ii][2];
      }
      acc[oo] = s;
    }
  }
  if (v < V_) {
#pragma unroll
    for (int oo = 0; oo < 16; ++oo) {
      const int o = rg * 16 + oo;
      float zv = acc[oo] + b_t[o];
      float r = (zv - bn3_m[o]) * (bn3_g[o] * rsqrtf(bn3_v[o] + 1e-5f)) + bn3_b[o]
                + hl[o][tloc + 1][v];
      out[((size_t)(n * CO_ + o) * T_ + t) * V_ + v] = (r >= 0.f) ? r : 0.1f * r;
    }
  }
}

// ---------------- fallback fused k3 (used only if ws too small) ----------------
__global__ __launch_bounds__(256) void k3_main(
    const float* __restrict__ x, const float* __restrict__ att,
    const float* __restrict__ w_out, const float* __restrict__ b_out,
    const float* __restrict__ bn1_g, const float* __restrict__ bn1_b,
    const float* __restrict__ bn1_m, const float* __restrict__ bn1_v,
    const float* __restrict__ w_ff, const float* __restrict__ b_ff,
    const float* __restrict__ bn2_g, const float* __restrict__ bn2_b,
    const float* __restrict__ bn2_m, const float* __restrict__ bn2_v,
    const float* __restrict__ w_t, const float* __restrict__ b_t,
    const float* __restrict__ bn3_g, const float* __restrict__ bn3_b,
    const float* __restrict__ bn3_m, const float* __restrict__ bn3_v,
    float* __restrict__ out)
{
  const int n = blockIdx.x;
  const int t0 = blockIdx.y * TT;
  const int tid = threadIdx.x;
  __shared__ float xlds[C_][28];
  __shared__ float attlds[S_][V_][28];
  __shared__ float y2lds[S_ * C_][28];
  __shared__ float h1lds[C_][28];
  __shared__ float h2ring[TT + 2][C_][28];

  for (int i = tid; i < S_ * V_ * 28; i += 256) {
    int s = i / (V_ * 28), r2 = i - s * V_ * 28, u = r2 / 28, v = r2 - u * 28;
    attlds[s][u][v] = (v < V_) ? att[(size_t)n * ATT_N + s * 729 + u * 27 + v] : 0.f;
  }
  const int o  = tid >> 2;
  const int rr = tid & 3;
  const int v0 = rr * 8;
  const int nv = (27 - v0) < 8 ? (27 - v0) : 8;
  const float bo  = b_out[o];
  const float s1  = bn1_g[o] * rsqrtf(bn1_v[o] + 1e-5f);
  const float m1  = bn1_m[o];
  const float bb1 = bn1_b[o];
  const float bf  = b_ff[o];
  const float s2  = bn2_g[o] * rsqrtf(bn2_v[o] + 1e-5f);
  const float m2  = bn2_m[o];
  const float bb2 = bn2_b[o];
  const float bt  = b_t[o];
  const float s3  = bn3_g[o] * rsqrtf(bn3_v[o] + 1e-5f);
  const float m3  = bn3_m[o];
  const float bb3 = bn3_b[o];
  const int sc   = tid >> 1;
  const int r2b  = tid & 1;
  const int w0   = r2b * 16;
  const int nw   = r2b ? 11 : 16;
  const int s_p2 = sc >> 6, c_p2 = sc & 63;

  for (int sl = 0; sl < TT + 2; ++sl) {
    const int t = t0 - 1 + sl;
    __syncthreads();
    if (t < 0 || t >= T_) {
      for (int i = tid; i < C_ * 28; i += 256) ((float*)h2ring[sl])[i] = 0.f;
      continue;
    }
    for (int i = tid; i < C_ * V_; i += 256) {
      int c = i / V_, v = i - c * V_;
      xlds[c][v] = x[((size_t)(n * C_ + c) * T_ + t) * V_ + v];
    }
    __syncthreads();
    {
      float acc[16];
#pragma unroll
      for (int j = 0; j < 16; ++j) acc[j] = 0.f;
      for (int u = 0; u < V_; ++u) {
        float xv = xlds[c_p2][u];
#pragma unroll
        for (int j = 0; j < 16; ++j) acc[j] += xv * attlds[s_p2][u][w0 + j];
      }
#pragma unroll
      for (int j = 0; j < 16; ++j) if (j < nw) y2lds[sc][w0 + j] = acc[j];
      if (r2b) y2lds[sc][27] = 0.f;
    }
    __syncthreads();
    {
      float acc[8];
#pragma unroll
      for (int j = 0; j < 8; ++j) acc[j] = bo;
#pragma unroll 4
      for (int k = 0; k < S_ * C_; ++k) {
        float w = w_out[o * (S_ * C_) + k];
#pragma unroll
        for (int j = 0; j < 8; ++j) acc[j] += w * y2lds[k][v0 + j];
      }
#pragma unroll
      for (int j = 0; j < 8; ++j) if (j < nv) {
        float h = (acc[j] - m1) * s1 + bb1 + xlds[o][v0 + j];
        h1lds[o][v0 + j] = (h >= 0.f) ? h : 0.1f * h;
      }
      if (rr == 3) h1lds[o][27] = 0.f;
    }
    __syncthreads();
    {
      float acc[8];
#pragma unroll
      for (int j = 0; j < 8; ++j) acc[j] = bf;
#pragma unroll 4
      for (int k = 0; k < C_; ++k) {
        float w = w_ff[o * C_ + k];
#pragma unroll
        for (int j = 0; j < 8; ++j) acc[j] += w * h1lds[k][v0 + j];
      }
#pragma unroll
      for (int j = 0; j < 8; ++j) if (j < nv) {
        float h = (acc[j] - m2) * s2 + bb2 + xlds[o][v0 + j];
        h2ring[sl][o][v0 + j] = (h >= 0.f) ? h : 0.1f * h;
      }
      if (rr == 3) h2ring[sl][o][27] = 0.f;
    }
  }
  __syncthreads();
  for (int j = 0; j < TT; ++j) {
    const int t = t0 + j;
    float acc[8];
#pragma unroll
    for (int q = 0; q < 8; ++q) acc[q] = bt;
#pragma unroll 2
    for (int i = 0; i < C_; ++i) {
      float wta = w_t[(o * C_ + i) * 3 + 0];
      float wtb = w_t[(o * C_ + i) * 3 + 1];
      float wtc = w_t[(o * C_ + i) * 3 + 2];
#pragma unroll
      for (int q = 0; q < 8; ++q) {
        acc[q] += wta * h2ring[j][i][v0 + q]
                + wtb * h2ring[j + 1][i][v0 + q]
                + wtc * h2ring[j + 2][i][v0 + q];
      }
    }
#pragma unroll
    for (int q = 0; q < 8; ++q) if (q < nv) {
      float h2c = h2ring[j + 1][o][v0 + q];
      float h = (acc[q] - m3) * s3 + bb3 + h2c;
      out[((size_t)(n * CO_ + o) * T_ + t) * V_ + v0 + q] = (h >= 0.f) ? h : 0.1f * h;
    }
  }
}

extern "C" void kernel_launch(void* const* d_in, const int* in_sizes, int n_in,
                              void* d_out, int out_size, void* d_ws, size_t ws_size,
                              hipStream_t stream)
{
  (void)in_sizes; (void)n_in; (void)out_size;
  const float* x      = (const float*)d_in[0];
  const float* pe     = (const float*)d_in[1];
  const float* w_in   = (const float*)d_in[2];
  const float* b_in   = (const float*)d_in[3];
  const float* alphas = (const float*)d_in[4];
  const float* att0   = (const float*)d_in[5];
  const float* w_out  = (const float*)d_in[6];
  const float* b_out  = (const float*)d_in[7];
  const float* bn1_g  = (const float*)d_in[8];
  const float* bn1_b  = (const float*)d_in[9];
  const float* bn1_m  = (const float*)d_in[10];
  const float* bn1_v  = (const float*)d_in[11];
  const float* w_ff   = (const float*)d_in[12];
  const float* b_ff   = (const float*)d_in[13];
  const float* bn2_g  = (const float*)d_in[14];
  const float* bn2_b  = (const float*)d_in[15];
  const float* bn2_m  = (const float*)d_in[16];
  const float* bn2_v  = (const float*)d_in[17];
  const float* w_t    = (const float*)d_in[18];
  const float* b_t    = (const float*)d_in[19];
  const float* bn3_g  = (const float*)d_in[20];
  const float* bn3_b  = (const float*)d_in[21];
  const float* bn3_m  = (const float*)d_in[22];
  const float* bn3_v  = (const float*)d_in[23];
  float* out = (float*)d_out;

  float* partial = (float*)d_ws;                           // N*NCHUNK*ATT_N
  float* att     = partial + (size_t)N_ * NCHUNK * ATT_N;  // N*ATT_N
  float* h2g     = att + (size_t)N_ * ATT_N;               // N*CO*T*V

  const size_t need = ((size_t)N_ * NCHUNK * ATT_N + (size_t)N_ * ATT_N
                       + (size_t)N_ * CO_ * T_ * V_) * sizeof(float);

  k1_qk_partial<<<dim3(N_, NCHUNK), 256, 0, stream>>>(x, pe, w_in, b_in, partial);
  k2_att_fin<<<(N_ * ATT_N + 255) / 256, 256, 0, stream>>>(partial, alphas, att0, att);

  if (ws_size >= need) {
    k3a<<<dim3(N_, T_ / 2), 256, 0, stream>>>(x, att,
        w_out, b_out, bn1_g, bn1_b, bn1_m, bn1_v,
        w_ff, b_ff, bn2_g, bn2_b, bn2_m, bn2_v, h2g);
    k3b<<<dim3(N_, T_ / 2), 256, 0, stream>>>(h2g, w_t, b_t,
        bn3_g, bn3_b, bn3_m, bn3_v, out);
  } else {
    k3_main<<<dim3(N_, T_ / TT), 256, 0, stream>>>(x, att,
        w_out, b_out, bn1_g, bn1_b, bn1_m, bn1_v,
        w_ff, b_ff, bn2_g, bn2_b, bn2_m, bn2_v,
        w_t, b_t, bn3_g, bn3_b, bn3_m, bn3_v, out);
  }
}

// Round 3
// 548.374 us; speedup vs baseline: 2.4820x; 2.0003x over previous
//
#include <hip/hip_runtime.h>

#define N_ 32
#define C_ 64
#define T_ 400
#define V_ 27
#define S_ 2
#define CI_ 16
#define CO_ 64
#define TCHUNK 8
#define NCHUNK 50            // T_/TCHUNK
#define ATT_N 1458           // S_*V_*V_
#define TT 4                 // t-tile in fallback fused kernel
#define P_ 10800             // T_*V_
#define PT_ 10816            // 169*64
#define PTILES 169
#define HGUARD 32
#define HROWS 10896          // HGUARD + PT_ + 48

typedef short bhalf8 __attribute__((ext_vector_type(8)));
typedef float fx4 __attribute__((ext_vector_type(4)));

static __device__ inline unsigned short f2bf(float f) {
  unsigned u = __builtin_bit_cast(unsigned, f);
  u += 0x7fffu + ((u >> 16) & 1u);
  return (unsigned short)(u >> 16);
}
static __device__ inline float bf2f(unsigned short h) {
  unsigned u = ((unsigned)h) << 16;
  return __builtin_bit_cast(float, u);
}

// ---------------- K1: qk partial outer products -> ws ----------------
__global__ __launch_bounds__(256) void k1_qk_partial(
    const float* __restrict__ x, const float* __restrict__ pe,
    const float* __restrict__ w_in, const float* __restrict__ b_in,
    float* __restrict__ partial)
{
  const int n = blockIdx.x;
  const int chunk = blockIdx.y;
  const int tid = threadIdx.x;
  __shared__ float ylds[C_][28];
  __shared__ float qlds[C_][28];
  __shared__ float wlds[C_][65];
  for (int i = tid; i < C_ * C_; i += 256) wlds[i >> 6][i & 63] = w_in[i];
  float acc[6];
#pragma unroll
  for (int j = 0; j < 6; ++j) acc[j] = 0.f;
  const int t0 = chunk * TCHUNK;
  for (int tt = 0; tt < TCHUNK; ++tt) {
    const int t = t0 + tt;
    __syncthreads();
    for (int i = tid; i < C_ * V_; i += 256) {
      int c = i / V_, v = i - c * V_;
      ylds[c][v] = x[((size_t)(n * C_ + c) * T_ + t) * V_ + v] + pe[(c * T_ + t) * V_ + v];
    }
    __syncthreads();
    for (int i = tid; i < C_ * V_; i += 256) {
      int o = i / V_, v = i - o * V_;
      float s = b_in[o];
#pragma unroll
      for (int c = 0; c < C_; ++c) s += wlds[o][c] * ylds[c][v];
      qlds[o][v] = s;
    }
    __syncthreads();
#pragma unroll
    for (int j = 0; j < 6; ++j) {
      int i = tid + j * 256;
      if (i < ATT_N) {
        int s = i / 729, r = i - s * 729, u = r / 27, v = r - u * 27;
        float a = 0.f;
#pragma unroll
        for (int c = 0; c < CI_; ++c)
          a += qlds[s * CI_ + c][u] * qlds[S_ * CI_ + s * CI_ + c][v];
        acc[j] += a;
      }
    }
  }
  float* dst = partial + (size_t)(n * NCHUNK + chunk) * ATT_N;
#pragma unroll
  for (int j = 0; j < 6; ++j) {
    int i = tid + j * 256;
    if (i < ATT_N) dst[i] = acc[j];
  }
}

// ---------------- K2: reduce partials, finalize att ----------------
__global__ __launch_bounds__(256) void k2_att_fin(
    const float* __restrict__ partial, const float* __restrict__ alphas,
    const float* __restrict__ att0, float* __restrict__ att)
{
  int i = blockIdx.x * 256 + threadIdx.x;
  if (i >= N_ * ATT_N) return;
  int n = i / ATT_N, r = i - n * ATT_N;
  int s = r / 729;
  float a = 0.f;
  const float* p = partial + (size_t)n * NCHUNK * ATT_N + r;
  for (int ch = 0; ch < NCHUNK; ++ch) a += p[(size_t)ch * ATT_N];
  a = tanhf(a * (1.0f / (CI_ * (float)T_))) * alphas[s] + att0[r];
  att[i] = a;
}

// ---------------- kprep: weight bf16 conversion + fused bn consts + h2T guard zero ----------------
__global__ __launch_bounds__(256) void kprep(
    const float* __restrict__ w_out, const float* __restrict__ w_ff,
    const float* __restrict__ w_t,
    const float* __restrict__ b_out, const float* __restrict__ b_ff,
    const float* __restrict__ b_t,
    const float* __restrict__ bn1_g, const float* __restrict__ bn1_b,
    const float* __restrict__ bn1_m, const float* __restrict__ bn1_v,
    const float* __restrict__ bn2_g, const float* __restrict__ bn2_b,
    const float* __restrict__ bn2_m, const float* __restrict__ bn2_v,
    const float* __restrict__ bn3_g, const float* __restrict__ bn3_b,
    const float* __restrict__ bn3_m, const float* __restrict__ bn3_v,
    unsigned short* __restrict__ Wb, float* __restrict__ cst,
    unsigned short* __restrict__ h2Tg)
{
  const int tid = threadIdx.x;
  const int bid = blockIdx.x;
  // guard zeroing: per n, rows [0,32) and [10832,10896): 1536 16B-chunks per n
  uint4 z; z.x = 0; z.y = 0; z.z = 0; z.w = 0;
  for (int i = bid * 256 + tid; i < N_ * 1536; i += 64 * 256) {
    int n = i / 1536, r = i - n * 1536;
    size_t off = (r < 512) ? (size_t)r * 8 : (size_t)10832 * 128 + (size_t)(r - 512) * 8;
    *reinterpret_cast<uint4*>(h2Tg + (size_t)n * HROWS * 128 + off) = z;
  }
  if (bid != 0) return;
  for (int i = tid; i < 8192; i += 256) Wb[i] = f2bf(w_out[i]);
  for (int i = tid; i < 4096; i += 256) Wb[8192 + i] = f2bf(w_ff[i]);
  for (int i = tid; i < 12288; i += 256) {
    int o = i / 192, r = i - o * 192, dt = r >> 6, ic = r & 63;
    Wb[12288 + i] = f2bf(w_t[(size_t)(o * 64 + ic) * 3 + dt]);
  }
  if (tid < 64) {
    int o = tid;
    float a1 = bn1_g[o] * rsqrtf(bn1_v[o] + 1e-5f);
    cst[o] = a1;
    cst[64 + o] = (b_out[o] - bn1_m[o]) * a1 + bn1_b[o];
    float a2 = bn2_g[o] * rsqrtf(bn2_v[o] + 1e-5f);
    cst[128 + o] = a2;
    cst[192 + o] = (b_ff[o] - bn2_m[o]) * a2 + bn2_b[o];
    float a3 = bn3_g[o] * rsqrtf(bn3_v[o] + 1e-5f);
    cst[256 + o] = a3;
    cst[320 + o] = (b_t[o] - bn3_m[o]) * a3 + bn3_b[o];
  }
}

// ---------------- kz: phase2 (x . att) -> ZT[n][p][128] bf16 ----------------
__global__ __launch_bounds__(256) void kz_phase2(
    const float* __restrict__ x, const float* __restrict__ att,
    unsigned short* __restrict__ ZT)
{
  const int n = blockIdx.x;
  const int t0 = blockIdx.y * 2;
  const int tid = threadIdx.x;
  const int col = tid & 63;
  const int v = col & 31;
  const int tl = col >> 5;
  const int rg = tid >> 6;

  __shared__ float xlds[C_][64];
  __shared__ unsigned short zlds[128][65];

  for (int i = tid; i < C_ * 64; i += 256) {
    int c = i >> 6, cl = i & 63, tll = cl >> 5, vv = cl & 31;
    xlds[c][cl] = (vv < V_) ? x[((size_t)(n * C_ + c) * T_ + t0 + tll) * V_ + vv] : 0.f;
  }
  float attreg[S_][V_];
  {
    const float* ab = att + (size_t)n * ATT_N + ((v < V_) ? v : 0);
#pragma unroll
    for (int s = 0; s < S_; ++s)
#pragma unroll
      for (int u = 0; u < V_; ++u)
        attreg[s][u] = ab[s * 729 + u * 27];
  }
  __syncthreads();
#pragma unroll 1
  for (int cc = 0; cc < 16; ++cc) {
    const int c = rg * 16 + cc;
    float xr[V_];
#pragma unroll
    for (int u = 0; u < V_; ++u) xr[u] = xlds[c][tl * 32 + u];
    float a0 = 0.f, a1 = 0.f;
#pragma unroll
    for (int u = 0; u < V_; ++u) {
      a0 += xr[u] * attreg[0][u];
      a1 += xr[u] * attreg[1][u];
    }
    zlds[c][col] = f2bf(a0);
    zlds[64 + c][col] = f2bf(a1);
  }
  __syncthreads();
  // transposed coalesced store: 54 valid p-rows x 16 chunks of 16B
  for (int i = tid; i < 54 * 16; i += 256) {
    int r = i >> 4, c8 = i & 15;
    int tll = (r >= 27) ? 1 : 0;
    int vv = r - tll * 27;
    int colr = tll * 32 + vv;
    int p = (t0 + tll) * V_ + vv;
    unsigned int wpk[4];
#pragma unroll
    for (int q = 0; q < 4; ++q) {
      unsigned int lo = zlds[c8 * 8 + 2 * q][colr];
      unsigned int hi = zlds[c8 * 8 + 2 * q + 1][colr];
      wpk[q] = lo | (hi << 16);
    }
    uint4 d; d.x = wpk[0]; d.y = wpk[1]; d.z = wpk[2]; d.w = wpk[3];
    *reinterpret_cast<uint4*>(ZT + ((size_t)n * PT_ + p) * 128 + c8 * 8) = d;
  }
}

// ---------------- k4b: MFMA Wout.Z -> bn1/res/lrelu -> Wff.H1 -> bn2/res/lrelu -> h2T bf16 ----------------
__global__ __launch_bounds__(256) void k4b(
    const float* __restrict__ x,
    const unsigned short* __restrict__ ZT,
    const unsigned short* __restrict__ Wb,
    const float* __restrict__ cst,
    unsigned short* __restrict__ h2Tg)
{
  const int n = blockIdx.x;
  const int p0 = blockIdx.y * 64;
  const int tid = threadIdx.x;
  const int w = tid >> 6;
  const int l = tid & 63;
  const int cl = l & 15;
  const int lq = l >> 4;
  const int p = p0 + w * 16 + cl;
  const int pc = (p < P_) ? p : (P_ - 1);
  const int swz = (cl & 7) << 4;

  __shared__ short h1t[64 * 64];       // [pcol][krow] bf16, XOR-swizzled rows of 128B
  __shared__ float clds[256];
  for (int i = tid; i < 256; i += 256) clds[i] = cst[i];

  // phase3: y3 = Wout(64x128) . Z(128x16cols per wave)
  bhalf8 bfr[4];
  const unsigned short* zrow = ZT + ((size_t)n * PT_ + p) * 128;
#pragma unroll
  for (int ks = 0; ks < 4; ++ks)
    bfr[ks] = *reinterpret_cast<const bhalf8*>(zrow + ks * 32 + lq * 8);
  fx4 acc[4];
#pragma unroll
  for (int m = 0; m < 4; ++m) { acc[m][0] = 0.f; acc[m][1] = 0.f; acc[m][2] = 0.f; acc[m][3] = 0.f; }
#pragma unroll
  for (int m = 0; m < 4; ++m) {
#pragma unroll
    for (int ks = 0; ks < 4; ++ks) {
      bhalf8 a = *reinterpret_cast<const bhalf8*>(Wb + (m * 16 + cl) * 128 + ks * 32 + lq * 8);
      acc[m] = __builtin_amdgcn_mfma_f32_16x16x32_bf16(a, bfr[ks], acc[m], 0, 0, 0);
    }
  }
  __syncthreads();   // clds ready

  // bn1 + residual + lrelu -> H1 (bf16, transposed+swizzled in LDS)
  float xres[4][4];
#pragma unroll
  for (int m = 0; m < 4; ++m) {
#pragma unroll
    for (int r = 0; r < 4; ++r) {
      int o = m * 16 + lq * 4 + r;
      float xv = x[((size_t)(n * C_ + o)) * (size_t)P_ + pc];
      xres[m][r] = xv;
      float h = acc[m][r] * clds[o] + clds[64 + o] + xv;
      h = (h >= 0.f) ? h : 0.1f * h;
      int byteoff = (w * 16 + cl) * 128 + ((o * 2) ^ swz);
      *reinterpret_cast<short*>(reinterpret_cast<char*>(h1t) + byteoff) = (short)f2bf(h);
    }
  }

  // phase4: f = Wff(64x64) . H1 — per-wave data only, ds ordering within wave suffices
  const unsigned short* Wff = Wb + 8192;
  fx4 acc2[4];
#pragma unroll
  for (int m = 0; m < 4; ++m) { acc2[m][0] = 0.f; acc2[m][1] = 0.f; acc2[m][2] = 0.f; acc2[m][3] = 0.f; }
#pragma unroll
  for (int ks = 0; ks < 2; ++ks) {
    int byteoff = (w * 16 + cl) * 128 + ((ks * 64 + lq * 16) ^ swz);
    bhalf8 b = *reinterpret_cast<const bhalf8*>(reinterpret_cast<char*>(h1t) + byteoff);
#pragma unroll
    for (int m = 0; m < 4; ++m) {
      bhalf8 a = *reinterpret_cast<const bhalf8*>(Wff + (m * 16 + cl) * 64 + ks * 32 + lq * 8);
      acc2[m] = __builtin_amdgcn_mfma_f32_16x16x32_bf16(a, b, acc2[m], 0, 0, 0);
    }
  }

  // bn2 + residual + lrelu -> h2 (bf16) back into LDS (same per-wave rows)
#pragma unroll
  for (int m = 0; m < 4; ++m) {
#pragma unroll
    for (int r = 0; r < 4; ++r) {
      int o = m * 16 + lq * 4 + r;
      float h = acc2[m][r] * clds[128 + o] + clds[192 + o] + xres[m][r];
      h = (h >= 0.f) ? h : 0.1f * h;
      int byteoff = (w * 16 + cl) * 128 + ((o * 2) ^ swz);
      *reinterpret_cast<short*>(reinterpret_cast<char*>(h1t) + byteoff) = (short)f2bf(h);
    }
  }
  __syncthreads();

  // cooperative unswizzle + coalesced global store (mask tail)
  {
    int row = tid >> 2, ch = tid & 3;
    int prow = p0 + row;
    if (prow < P_) {
      int sw = (row & 7) << 4;
      uint4 d0 = *reinterpret_cast<uint4*>(reinterpret_cast<char*>(h1t) + row * 128 + (((2 * ch) * 16) ^ sw));
      uint4 d1 = *reinterpret_cast<uint4*>(reinterpret_cast<char*>(h1t) + row * 128 + (((2 * ch + 1) * 16) ^ sw));
      char* dst = reinterpret_cast<char*>(h2Tg) + ((size_t)n * HROWS + HGUARD + prow) * 256 + ch * 32;
      *reinterpret_cast<uint4*>(dst) = d0;
      *reinterpret_cast<uint4*>(dst + 16) = d1;
    }
  }
}

// ---------------- k4c: temporal conv as K=192 MFMA GEMM + bn3/res/lrelu -> out ----------------
__global__ __launch_bounds__(256) void k4c(
    const unsigned short* __restrict__ h2Tg,
    const unsigned short* __restrict__ Wtb,
    const float* __restrict__ cst,
    float* __restrict__ out)
{
  const int n = blockIdx.x;
  const int p0 = blockIdx.y * 64;
  const int tid = threadIdx.x;
  const int w = tid >> 6;
  const int l = tid & 63;
  const int cl = l & 15;
  const int lq = l >> 4;
  const int p = p0 + w * 16 + cl;

  __shared__ float clds[128];
  if (tid < 128) clds[tid] = cst[256 + tid];

  const unsigned short* hrow = h2Tg + ((size_t)n * HROWS + HGUARD + p) * 128;
  bhalf8 bfr[6];
#pragma unroll
  for (int ks = 0; ks < 6; ++ks) {
    int k0 = ks * 32 + lq * 8;
    int dt = k0 >> 6;
    int i0 = k0 & 63;
    bfr[ks] = *reinterpret_cast<const bhalf8*>(hrow + (size_t)(dt - 1) * 27 * 128 + i0);
  }
  fx4 acc[4];
#pragma unroll
  for (int m = 0; m < 4; ++m) { acc[m][0] = 0.f; acc[m][1] = 0.f; acc[m][2] = 0.f; acc[m][3] = 0.f; }
#pragma unroll
  for (int m = 0; m < 4; ++m) {
#pragma unroll
    for (int ks = 0; ks < 6; ++ks) {
      bhalf8 a = *reinterpret_cast<const bhalf8*>(Wtb + (m * 16 + cl) * 192 + ks * 32 + lq * 8);
      acc[m] = __builtin_amdgcn_mfma_f32_16x16x32_bf16(a, bfr[ks], acc[m], 0, 0, 0);
    }
  }
  __syncthreads();
  if (p < P_) {
#pragma unroll
    for (int m = 0; m < 4; ++m) {
#pragma unroll
      for (int r = 0; r < 4; ++r) {
        int o = m * 16 + lq * 4 + r;
        float hc = bf2f(hrow[o]);
        float val = acc[m][r] * clds[o] + clds[64 + o] + hc;
        val = (val >= 0.f) ? val : 0.1f * val;
        out[((size_t)(n * CO_ + o)) * (size_t)P_ + p] = val;
      }
    }
  }
}

// ================= fallback path (R2 kernels) =================
__global__ __launch_bounds__(256) void k3a(
    const float* __restrict__ x, const float* __restrict__ att,
    const float* __restrict__ w_out, const float* __restrict__ b_out,
    const float* __restrict__ bn1_g, const float* __restrict__ bn1_b,
    const float* __restrict__ bn1_m, const float* __restrict__ bn1_v,
    const float* __restrict__ w_ff, const float* __restrict__ b_ff,
    const float* __restrict__ bn2_g, const float* __restrict__ bn2_b,
    const float* __restrict__ bn2_m, const float* __restrict__ bn2_v,
    float* __restrict__ h2g)
{
  const int n = blockIdx.x;
  const int t0 = blockIdx.y * 2;
  const int tid = threadIdx.x;
  const int v = tid & 31;
  const int tloc = (tid >> 5) & 1;
  const int col = tid & 63;
  const int rg = __builtin_amdgcn_readfirstlane(tid >> 6);
  const int t = t0 + tloc;

  __shared__ float xlds[C_][64];
  __shared__ float zlds[S_ * C_][64];

  for (int i = tid; i < C_ * 64; i += 256) {
    int c = i >> 6, cl = i & 63, tl = cl >> 5, vv = cl & 31;
    xlds[c][cl] = (vv < V_) ? x[((size_t)(n * C_ + c) * T_ + t0 + tl) * V_ + vv] : 0.f;
  }
  float attreg[S_][V_];
  {
    const float* ab = att + (size_t)n * ATT_N + v;
#pragma unroll
    for (int s = 0; s < S_; ++s)
#pragma unroll
      for (int u = 0; u < V_; ++u)
        attreg[s][u] = (v < V_) ? ab[s * 729 + u * 27] : 0.f;
  }
  __syncthreads();
#pragma unroll 1
  for (int cc = 0; cc < 16; ++cc) {
    const int c = rg * 16 + cc;
    float xr[V_];
#pragma unroll
    for (int u = 0; u < V_; ++u) xr[u] = xlds[c][tloc * 32 + u];
    float a0 = 0.f, a1 = 0.f;
#pragma unroll
    for (int u = 0; u < V_; ++u) {
      a0 += xr[u] * attreg[0][u];
      a1 += xr[u] * attreg[1][u];
    }
    zlds[c][col] = a0;
    zlds[C_ + c][col] = a1;
  }
  __syncthreads();
  float acc[16];
#pragma unroll
  for (int oo = 0; oo < 16; ++oo) acc[oo] = 0.f;
#pragma unroll 1
  for (int kc = 0; kc < 4; ++kc) {
    float zk[32];
#pragma unroll
    for (int j = 0; j < 32; ++j) zk[j] = zlds[kc * 32 + j][col];
#pragma unroll
    for (int oo = 0; oo < 16; ++oo) {
      const float* wr = w_out + (rg * 16 + oo) * (S_ * C_) + kc * 32;
      float s = acc[oo];
#pragma unroll
      for (int j = 0; j < 32; ++j) s += wr[j] * zk[j];
      acc[oo] = s;
    }
  }
  float h1v[16];
#pragma unroll
  for (int oo = 0; oo < 16; ++oo) {
    const int o = rg * 16 + oo;
    float y3 = acc[oo] + b_out[o];
    float h = (y3 - bn1_m[o]) * (bn1_g[o] * rsqrtf(bn1_v[o] + 1e-5f)) + bn1_b[o]
              + xlds[o][col];
    h1v[oo] = (h >= 0.f) ? h : 0.1f * h;
  }
  __syncthreads();
#pragma unroll
  for (int oo = 0; oo < 16; ++oo) zlds[rg * 16 + oo][col] = h1v[oo];
  __syncthreads();
#pragma unroll
  for (int oo = 0; oo < 16; ++oo) acc[oo] = 0.f;
#pragma unroll 1
  for (int kc = 0; kc < 2; ++kc) {
    float zk[32];
#pragma unroll
    for (int j = 0; j < 32; ++j) zk[j] = zlds[kc * 32 + j][col];
#pragma unroll
    for (int oo = 0; oo < 16; ++oo) {
      const float* wr = w_ff + (rg * 16 + oo) * C_ + kc * 32;
      float s = acc[oo];
#pragma unroll
      for (int j = 0; j < 32; ++j) s += wr[j] * zk[j];
      acc[oo] = s;
    }
  }
  if (v < V_) {
#pragma unroll
    for (int oo = 0; oo < 16; ++oo) {
      const int o = rg * 16 + oo;
      float f = acc[oo] + b_ff[o];
      float h = (f - bn2_m[o]) * (bn2_g[o] * rsqrtf(bn2_v[o] + 1e-5f)) + bn2_b[o]
                + xlds[o][col];
      h2g[((size_t)(n * CO_ + o) * T_ + t) * V_ + v] = (h >= 0.f) ? h : 0.1f * h;
    }
  }
}

__global__ __launch_bounds__(256) void k3b(
    const float* __restrict__ h2g, const float* __restrict__ w_t,
    const float* __restrict__ b_t,
    const float* __restrict__ bn3_g, const float* __restrict__ bn3_b,
    const float* __restrict__ bn3_m, const float* __restrict__ bn3_v,
    float* __restrict__ out)
{
  const int n = blockIdx.x;
  const int t0 = blockIdx.y * 2;
  const int tid = threadIdx.x;
  const int v = tid & 31;
  const int tloc = (tid >> 5) & 1;
  const int rg = __builtin_amdgcn_readfirstlane(tid >> 6);
  const int t = t0 + tloc;

  __shared__ float hl[C_][4][32];

  for (int idx = tid; idx < C_ * 4 * 32; idx += 256) {
    int i = idx >> 7, r = idx & 127, sl = r >> 5, vv = r & 31;
    int tg = t0 - 1 + sl;
    hl[i][sl][vv] = (vv < V_ && tg >= 0 && tg < T_)
                    ? h2g[((size_t)(n * CO_ + i) * T_ + tg) * V_ + vv] : 0.f;
  }
  __syncthreads();

  float acc[16];
#pragma unroll
  for (int oo = 0; oo < 16; ++oo) acc[oo] = 0.f;
#pragma unroll 1
  for (int ic = 0; ic < 4; ++ic) {
    float h[16][3];
#pragma unroll
    for (int ii = 0; ii < 16; ++ii) {
      h[ii][0] = hl[ic * 16 + ii][tloc][v];
      h[ii][1] = hl[ic * 16 + ii][tloc + 1][v];
      h[ii][2] = hl[ic * 16 + ii][tloc + 2][v];
    }
#pragma unroll
    for (int oo = 0; oo < 16; ++oo) {
      const float* wr = w_t + ((size_t)(rg * 16 + oo) * C_ + ic * 16) * 3;
      float s = acc[oo];
#pragma unroll
      for (int ii = 0; ii < 16; ++ii) {
        s += wr[ii * 3 + 0] * h[ii][0]
           + wr[ii * 3 + 1] * h[ii][1]
           + wr[ii * 3 + 2] * h[ii][2];
      }
      acc[oo] = s;
    }
  }
  if (v < V_) {
#pragma unroll
    for (int oo = 0; oo < 16; ++oo) {
      const int o = rg * 16 + oo;
      float zv = acc[oo] + b_t[o];
      float r = (zv - bn3_m[o]) * (bn3_g[o] * rsqrtf(bn3_v[o] + 1e-5f)) + bn3_b[o]
                + hl[o][tloc + 1][v];
      out[((size_t)(n * CO_ + o) * T_ + t) * V_ + v] = (r >= 0.f) ? r : 0.1f * r;
    }
  }
}

extern "C" void kernel_launch(void* const* d_in, const int* in_sizes, int n_in,
                              void* d_out, int out_size, void* d_ws, size_t ws_size,
                              hipStream_t stream)
{
  (void)in_sizes; (void)n_in; (void)out_size;
  const float* x      = (const float*)d_in[0];
  const float* pe     = (const float*)d_in[1];
  const float* w_in   = (const float*)d_in[2];
  const float* b_in   = (const float*)d_in[3];
  const float* alphas = (const float*)d_in[4];
  const float* att0   = (const float*)d_in[5];
  const float* w_out  = (const float*)d_in[6];
  const float* b_out  = (const float*)d_in[7];
  const float* bn1_g  = (const float*)d_in[8];
  const float* bn1_b  = (const float*)d_in[9];
  const float* bn1_m  = (const float*)d_in[10];
  const float* bn1_v  = (const float*)d_in[11];
  const float* w_ff   = (const float*)d_in[12];
  const float* b_ff   = (const float*)d_in[13];
  const float* bn2_g  = (const float*)d_in[14];
  const float* bn2_b  = (const float*)d_in[15];
  const float* bn2_m  = (const float*)d_in[16];
  const float* bn2_v  = (const float*)d_in[17];
  const float* w_t    = (const float*)d_in[18];
  const float* b_t    = (const float*)d_in[19];
  const float* bn3_g  = (const float*)d_in[20];
  const float* bn3_b  = (const float*)d_in[21];
  const float* bn3_m  = (const float*)d_in[22];
  const float* bn3_v  = (const float*)d_in[23];
  float* out = (float*)d_out;

  char* ws = (char*)d_ws;
  float* partial = (float*)ws;                         // 9,331,200 B
  float* att     = (float*)(ws + 9331200);             // 186,624 B
  unsigned short* Wb  = (unsigned short*)(ws + 9517824);   // 49,152 B
  float* cst          = (float*)(ws + 9566976);            // 1,536 B
  unsigned short* ZT  = (unsigned short*)(ws + 9568512);   // 88,604,672 B
  unsigned short* h2T = (unsigned short*)(ws + 98173184);  // 89,260,032 B
  const size_t need_mfma = 187433216;
  const size_t need_old  = ((size_t)N_ * NCHUNK * ATT_N + (size_t)N_ * ATT_N
                            + (size_t)N_ * CO_ * T_ * V_) * sizeof(float);

  k1_qk_partial<<<dim3(N_, NCHUNK), 256, 0, stream>>>(x, pe, w_in, b_in, partial);
  k2_att_fin<<<(N_ * ATT_N + 255) / 256, 256, 0, stream>>>(partial, alphas, att0, att);

  if (ws_size >= need_mfma) {
    kprep<<<64, 256, 0, stream>>>(w_out, w_ff, w_t, b_out, b_ff, b_t,
        bn1_g, bn1_b, bn1_m, bn1_v, bn2_g, bn2_b, bn2_m, bn2_v,
        bn3_g, bn3_b, bn3_m, bn3_v, Wb, cst, h2T);
    kz_phase2<<<dim3(N_, T_ / 2), 256, 0, stream>>>(x, att, ZT);
    k4b<<<dim3(N_, PTILES), 256, 0, stream>>>(x, ZT, Wb, cst, h2T);
    k4c<<<dim3(N_, PTILES), 256, 0, stream>>>(h2T, Wb + 12288, cst, out);
  } else if (ws_size >= need_old) {
    float* h2g = att + (size_t)N_ * ATT_N;
    k3a<<<dim3(N_, T_ / 2), 256, 0, stream>>>(x, att,
        w_out, b_out, bn1_g, bn1_b, bn1_m, bn1_v,
        w_ff, b_ff, bn2_g, bn2_b, bn2_m, bn2_v, h2g);
    k3b<<<dim3(N_, T_ / 2), 256, 0, stream>>>(h2g, w_t, b_t,
        bn3_g, bn3_b, bn3_m, bn3_v, out);
  }
}

// Round 4
// 370.213 us; speedup vs baseline: 3.6764x; 1.4812x over previous
//
#include <hip/hip_runtime.h>

#define N_ 32
#define C_ 64
#define T_ 400
#define V_ 27
#define S_ 2
#define CI_ 16
#define CO_ 64
#define TCHUNK 8
#define NCHUNK 50
#define ATT_N 1458           // S_*V_*V_
#define P_ 10800             // T_*V_
#define PT_ 10816            // 169*64
#define PTILES 169
#define HGUARD 32
#define HROWS 10896          // HGUARD + PT_ + 48

typedef short bhalf8 __attribute__((ext_vector_type(8)));
typedef float fx4 __attribute__((ext_vector_type(4)));

static __device__ inline unsigned short f2bf(float f) {
  unsigned u = __builtin_bit_cast(unsigned, f);
  u += 0x7fffu + ((u >> 16) & 1u);
  return (unsigned short)(u >> 16);
}
static __device__ inline float bf2f(unsigned short h) {
  unsigned u = ((unsigned)h) << 16;
  return __builtin_bit_cast(float, u);
}

// ================= MFMA path =================

// kprep: bf16 weights (Wout|Wff|Wt|Wi), fused bn consts + b_in, zero h2T guards
__global__ __launch_bounds__(256) void kprep(
    const float* __restrict__ w_out, const float* __restrict__ w_ff,
    const float* __restrict__ w_t, const float* __restrict__ w_in,
    const float* __restrict__ b_out, const float* __restrict__ b_ff,
    const float* __restrict__ b_t, const float* __restrict__ b_in,
    const float* __restrict__ bn1_g, const float* __restrict__ bn1_b,
    const float* __restrict__ bn1_m, const float* __restrict__ bn1_v,
    const float* __restrict__ bn2_g, const float* __restrict__ bn2_b,
    const float* __restrict__ bn2_m, const float* __restrict__ bn2_v,
    const float* __restrict__ bn3_g, const float* __restrict__ bn3_b,
    const float* __restrict__ bn3_m, const float* __restrict__ bn3_v,
    unsigned short* __restrict__ Wb, float* __restrict__ cst,
    unsigned short* __restrict__ h2Tg)
{
  const int tid = threadIdx.x;
  const int bid = blockIdx.x;
  uint4 z; z.x = 0; z.y = 0; z.z = 0; z.w = 0;
  for (int i = bid * 256 + tid; i < N_ * 1536; i += 64 * 256) {
    int n = i / 1536, r = i - n * 1536;
    size_t off = (r < 512) ? (size_t)r * 8 : (size_t)10832 * 128 + (size_t)(r - 512) * 8;
    *reinterpret_cast<uint4*>(h2Tg + (size_t)n * HROWS * 128 + off) = z;
  }
  if (bid != 0) return;
  for (int i = tid; i < 8192; i += 256) Wb[i] = f2bf(w_out[i]);
  for (int i = tid; i < 4096; i += 256) Wb[8192 + i] = f2bf(w_ff[i]);
  for (int i = tid; i < 12288; i += 256) {
    int o = i / 192, r = i - o * 192, dt = r >> 6, ic = r & 63;
    Wb[12288 + i] = f2bf(w_t[(size_t)(o * 64 + ic) * 3 + dt]);
  }
  for (int i = tid; i < 4096; i += 256) Wb[24576 + i] = f2bf(w_in[i]);
  if (tid < 64) {
    int o = tid;
    float a1 = bn1_g[o] * rsqrtf(bn1_v[o] + 1e-5f);
    cst[o] = a1;
    cst[64 + o] = (b_out[o] - bn1_m[o]) * a1 + bn1_b[o];
    float a2 = bn2_g[o] * rsqrtf(bn2_v[o] + 1e-5f);
    cst[128 + o] = a2;
    cst[192 + o] = (b_ff[o] - bn2_m[o]) * a2 + bn2_b[o];
    float a3 = bn3_g[o] * rsqrtf(bn3_v[o] + 1e-5f);
    cst[256 + o] = a3;
    cst[320 + o] = (b_t[o] - bn3_m[o]) * a3 + bn3_b[o];
    cst[384 + o] = b_in[o];
  }
}

// ky: yT[n][p][c] bf16 = transpose(x + pe)
__global__ __launch_bounds__(256) void ky(
    const float* __restrict__ x, const float* __restrict__ pe,
    unsigned short* __restrict__ yT)
{
  const int n = blockIdx.x;
  const int p0 = blockIdx.y * 64;
  const int tid = threadIdx.x;
  __shared__ float xl[64][65];
  {
    int c = tid >> 2, ch = tid & 3;
    const float* xr = x + (size_t)(n * C_ + c) * P_;
    const float* pr = pe + (size_t)c * P_;
    if (p0 + 64 <= P_) {
#pragma unroll
      for (int q = 0; q < 4; ++q) {
        int p = p0 + ch * 16 + q * 4;
        float4 a = *reinterpret_cast<const float4*>(xr + p);
        float4 b = *reinterpret_cast<const float4*>(pr + p);
        xl[c][ch * 16 + q * 4 + 0] = a.x + b.x;
        xl[c][ch * 16 + q * 4 + 1] = a.y + b.y;
        xl[c][ch * 16 + q * 4 + 2] = a.z + b.z;
        xl[c][ch * 16 + q * 4 + 3] = a.w + b.w;
      }
    } else {
#pragma unroll
      for (int j = 0; j < 16; ++j) {
        int p = p0 + ch * 16 + j;
        xl[c][ch * 16 + j] = (p < P_) ? (xr[p] + pr[p]) : 0.f;
      }
    }
  }
  __syncthreads();
  {
    int pr2 = tid >> 2, c0 = (tid & 3) * 16;
    unsigned vals[8];
#pragma unroll
    for (int q = 0; q < 8; ++q) {
      unsigned lo = f2bf(xl[c0 + 2 * q][pr2]);
      unsigned hi = f2bf(xl[c0 + 2 * q + 1][pr2]);
      vals[q] = lo | (hi << 16);
    }
    unsigned short* dst = yT + ((size_t)n * PT_ + p0 + pr2) * 64 + c0;
    uint4 d0; d0.x = vals[0]; d0.y = vals[1]; d0.z = vals[2]; d0.w = vals[3];
    uint4 d1; d1.x = vals[4]; d1.y = vals[5]; d1.z = vals[6]; d1.w = vals[7];
    *reinterpret_cast<uint4*>(dst) = d0;
    *reinterpret_cast<uint4*>(dst + 8) = d1;
  }
}

// k1a: qk = Wi(64x64) . yT  -> qkT[n][m][u32][t*16+ci] bf16  (m: 0=q s0,1=q s1,2=k s0,3=k s1)
__global__ __launch_bounds__(256) void k1a(
    const unsigned short* __restrict__ yT,
    const unsigned short* __restrict__ Wb,
    const float* __restrict__ cst,
    unsigned short* __restrict__ qkT)
{
  const int n = blockIdx.x;
  const int p0 = blockIdx.y * 64;
  const int tid = threadIdx.x;
  const int w = tid >> 6;
  const int l = tid & 63;
  const int cl = l & 15;
  const int lq = l >> 4;
  const int p = p0 + w * 16 + cl;

  __shared__ float clds[64];
  if (tid < 64) clds[tid] = cst[384 + tid];

  bhalf8 bfr[2];
  const unsigned short* yrow = yT + ((size_t)n * PT_ + p) * 64;
  bfr[0] = *reinterpret_cast<const bhalf8*>(yrow + lq * 8);
  bfr[1] = *reinterpret_cast<const bhalf8*>(yrow + 32 + lq * 8);

  const unsigned short* Wi = Wb + 24576;
  fx4 acc[4];
#pragma unroll
  for (int m = 0; m < 4; ++m) { acc[m][0]=0.f; acc[m][1]=0.f; acc[m][2]=0.f; acc[m][3]=0.f; }
#pragma unroll
  for (int m = 0; m < 4; ++m) {
#pragma unroll
    for (int ks = 0; ks < 2; ++ks) {
      bhalf8 a = *reinterpret_cast<const bhalf8*>(Wi + (m * 16 + cl) * 64 + ks * 32 + lq * 8);
      acc[m] = __builtin_amdgcn_mfma_f32_16x16x32_bf16(a, bfr[ks], acc[m], 0, 0, 0);
    }
  }
  __syncthreads();
  if (p < P_) {
    int t = p / 27, u = p - t * 27;
#pragma unroll
    for (int m = 0; m < 4; ++m) {
      unsigned short o0 = f2bf(acc[m][0] + clds[m * 16 + lq * 4 + 0]);
      unsigned short o1 = f2bf(acc[m][1] + clds[m * 16 + lq * 4 + 1]);
      unsigned short o2 = f2bf(acc[m][2] + clds[m * 16 + lq * 4 + 2]);
      unsigned short o3 = f2bf(acc[m][3] + clds[m * 16 + lq * 4 + 3]);
      uint2 d;
      d.x = (unsigned)o0 | ((unsigned)o1 << 16);
      d.y = (unsigned)o2 | ((unsigned)o3 << 16);
      *reinterpret_cast<uint2*>(qkT + (((size_t)(n * 4 + m) * 32 + u) * 6400 + t * 16 + lq * 4)) = d;
    }
  }
}

// k1b: att GEMM over K=6400, finalize tanh*alpha+att0 -> attT[n][s][v32][u32] bf16 (zero-padded)
__global__ __launch_bounds__(256) void k1b(
    const unsigned short* __restrict__ qkT,
    const float* __restrict__ alphas, const float* __restrict__ att0,
    unsigned short* __restrict__ attT)
{
  const int n = blockIdx.x >> 1;
  const int s = blockIdx.x & 1;
  const int tid = threadIdx.x;
  const int w = tid >> 6;
  const int l = tid & 63;
  const int cl = l & 15;
  const int lq = l >> 4;

  const unsigned short* qb = qkT + (size_t)(n * 4 + s) * 32 * 6400;
  const unsigned short* kb = qkT + (size_t)(n * 4 + 2 + s) * 32 * 6400;

  fx4 acc[2][2];
#pragma unroll
  for (int a1 = 0; a1 < 2; ++a1)
#pragma unroll
    for (int a2 = 0; a2 < 2; ++a2) { acc[a1][a2][0]=0.f; acc[a1][a2][1]=0.f; acc[a1][a2][2]=0.f; acc[a1][a2][3]=0.f; }

#pragma unroll 2
  for (int step = 0; step < 50; ++step) {
    int k0 = w * 1600 + step * 32 + lq * 8;
    bhalf8 aq0 = *reinterpret_cast<const bhalf8*>(qb + (size_t)cl * 6400 + k0);
    bhalf8 aq1 = *reinterpret_cast<const bhalf8*>(qb + (size_t)(16 + cl) * 6400 + k0);
    bhalf8 bk0 = *reinterpret_cast<const bhalf8*>(kb + (size_t)cl * 6400 + k0);
    bhalf8 bk1 = *reinterpret_cast<const bhalf8*>(kb + (size_t)(16 + cl) * 6400 + k0);
    acc[0][0] = __builtin_amdgcn_mfma_f32_16x16x32_bf16(aq0, bk0, acc[0][0], 0, 0, 0);
    acc[0][1] = __builtin_amdgcn_mfma_f32_16x16x32_bf16(aq0, bk1, acc[0][1], 0, 0, 0);
    acc[1][0] = __builtin_amdgcn_mfma_f32_16x16x32_bf16(aq1, bk0, acc[1][0], 0, 0, 0);
    acc[1][1] = __builtin_amdgcn_mfma_f32_16x16x32_bf16(aq1, bk1, acc[1][1], 0, 0, 0);
  }

  __shared__ float red[4][4][4][64];
#pragma unroll
  for (int mt = 0; mt < 2; ++mt)
#pragma unroll
    for (int nt = 0; nt < 2; ++nt)
#pragma unroll
      for (int r = 0; r < 4; ++r)
        red[w][mt * 2 + nt][r][l] = acc[mt][nt][r];
  __syncthreads();

  const int mn = w, mt = w >> 1, nt = w & 1;
  const int v = nt * 16 + cl;
  const float alpha = alphas[s];
  unsigned short outs[4];
#pragma unroll
  for (int r = 0; r < 4; ++r) {
    float sum = red[0][mn][r][l] + red[1][mn][r][l] + red[2][mn][r][l] + red[3][mn][r][l];
    int u = mt * 16 + lq * 4 + r;
    float val = 0.f;
    if (u < V_ && v < V_)
      val = tanhf(sum * (1.0f / 6400.0f)) * alpha + att0[(s * V_ + u) * V_ + v];
    outs[r] = f2bf(val);
  }
  uint2 d;
  d.x = (unsigned)outs[0] | ((unsigned)outs[1] << 16);
  d.y = (unsigned)outs[2] | ((unsigned)outs[3] << 16);
  *reinterpret_cast<uint2*>(attT + (((size_t)(n * 2 + s) * 32 + v) * 32 + mt * 16 + lq * 4)) = d;
}

// kz: y2 = x . att per t via MFMA (att B-frags in regs) -> ZT[n][p][128] bf16
__global__ __launch_bounds__(256) void kz_mfma(
    const float* __restrict__ x,
    const unsigned short* __restrict__ attT,
    unsigned short* __restrict__ ZT)
{
  const int n = blockIdx.x;
  const int t0 = blockIdx.y * 16;
  const int tid = threadIdx.x;
  const int w = tid >> 6;
  const int l = tid & 63;
  const int cl = l & 15;
  const int lq = l >> 4;

  bhalf8 batt[2][2];
#pragma unroll
  for (int s = 0; s < 2; ++s)
#pragma unroll
    for (int vt = 0; vt < 2; ++vt)
      batt[s][vt] = *reinterpret_cast<const bhalf8*>(
          attT + ((size_t)(n * 2 + s) * 32 + vt * 16 + cl) * 32 + lq * 8);

#pragma unroll 1
  for (int tt = 0; tt < 4; ++tt) {
    const int t = t0 + w * 4 + tt;
    bhalf8 ax[4];
#pragma unroll
    for (int m = 0; m < 4; ++m) {
      const int c = m * 16 + cl;
      const float* xr = x + (size_t)(n * C_ + c) * P_;
#pragma unroll
      for (int j = 0; j < 8; ++j) {
        int idx = t * 27 + lq * 8 + j;
        idx = (idx < P_) ? idx : (P_ - 1);
        ax[m][j] = (short)f2bf(xr[idx]);
      }
    }
#pragma unroll
    for (int s = 0; s < 2; ++s) {
#pragma unroll
      for (int vt = 0; vt < 2; ++vt) {
        const int v = vt * 16 + cl;
        const int p = t * 27 + v;
#pragma unroll
        for (int m = 0; m < 4; ++m) {
          fx4 z; z[0] = 0.f; z[1] = 0.f; z[2] = 0.f; z[3] = 0.f;
          fx4 dacc = __builtin_amdgcn_mfma_f32_16x16x32_bf16(ax[m], batt[s][vt], z, 0, 0, 0);
          if (v < V_) {
            unsigned short o0 = f2bf(dacc[0]);
            unsigned short o1 = f2bf(dacc[1]);
            unsigned short o2 = f2bf(dacc[2]);
            unsigned short o3 = f2bf(dacc[3]);
            uint2 d;
            d.x = (unsigned)o0 | ((unsigned)o1 << 16);
            d.y = (unsigned)o2 | ((unsigned)o3 << 16);
            *reinterpret_cast<uint2*>(ZT + ((size_t)n * PT_ + p) * 128 + s * 64 + m * 16 + lq * 4) = d;
          }
        }
      }
    }
  }
}

// k4b: MFMA Wout.Z -> bn1/res/lrelu -> Wff.H1 -> bn2/res/lrelu -> h2T bf16
__global__ __launch_bounds__(256) void k4b(
    const float* __restrict__ x,
    const unsigned short* __restrict__ ZT,
    const unsigned short* __restrict__ Wb,
    const float* __restrict__ cst,
    unsigned short* __restrict__ h2Tg)
{
  const int n = blockIdx.x;
  const int p0 = blockIdx.y * 64;
  const int tid = threadIdx.x;
  const int w = tid >> 6;
  const int l = tid & 63;
  const int cl = l & 15;
  const int lq = l >> 4;
  const int p = p0 + w * 16 + cl;
  const int pc = (p < P_) ? p : (P_ - 1);
  const int swz = (cl & 7) << 4;

  __shared__ short h1t[64 * 64];
  __shared__ float clds[256];
  for (int i = tid; i < 256; i += 256) clds[i] = cst[i];

  bhalf8 bfr[4];
  const unsigned short* zrow = ZT + ((size_t)n * PT_ + p) * 128;
#pragma unroll
  for (int ks = 0; ks < 4; ++ks)
    bfr[ks] = *reinterpret_cast<const bhalf8*>(zrow + ks * 32 + lq * 8);
  fx4 acc[4];
#pragma unroll
  for (int m = 0; m < 4; ++m) { acc[m][0]=0.f; acc[m][1]=0.f; acc[m][2]=0.f; acc[m][3]=0.f; }
#pragma unroll
  for (int m = 0; m < 4; ++m) {
#pragma unroll
    for (int ks = 0; ks < 4; ++ks) {
      bhalf8 a = *reinterpret_cast<const bhalf8*>(Wb + (m * 16 + cl) * 128 + ks * 32 + lq * 8);
      acc[m] = __builtin_amdgcn_mfma_f32_16x16x32_bf16(a, bfr[ks], acc[m], 0, 0, 0);
    }
  }
  __syncthreads();

  float xres[4][4];
#pragma unroll
  for (int m = 0; m < 4; ++m) {
#pragma unroll
    for (int r = 0; r < 4; ++r) {
      int o = m * 16 + lq * 4 + r;
      float xv = x[((size_t)(n * C_ + o)) * (size_t)P_ + pc];
      xres[m][r] = xv;
      float h = acc[m][r] * clds[o] + clds[64 + o] + xv;
      h = (h >= 0.f) ? h : 0.1f * h;
      int byteoff = (w * 16 + cl) * 128 + ((o * 2) ^ swz);
      *reinterpret_cast<short*>(reinterpret_cast<char*>(h1t) + byteoff) = (short)f2bf(h);
    }
  }

  const unsigned short* Wff = Wb + 8192;
  fx4 acc2[4];
#pragma unroll
  for (int m = 0; m < 4; ++m) { acc2[m][0]=0.f; acc2[m][1]=0.f; acc2[m][2]=0.f; acc2[m][3]=0.f; }
#pragma unroll
  for (int ks = 0; ks < 2; ++ks) {
    int byteoff = (w * 16 + cl) * 128 + ((ks * 64 + lq * 16) ^ swz);
    bhalf8 b = *reinterpret_cast<const bhalf8*>(reinterpret_cast<char*>(h1t) + byteoff);
#pragma unroll
    for (int m = 0; m < 4; ++m) {
      bhalf8 a = *reinterpret_cast<const bhalf8*>(Wff + (m * 16 + cl) * 64 + ks * 32 + lq * 8);
      acc2[m] = __builtin_amdgcn_mfma_f32_16x16x32_bf16(a, b, acc2[m], 0, 0, 0);
    }
  }

#pragma unroll
  for (int m = 0; m < 4; ++m) {
#pragma unroll
    for (int r = 0; r < 4; ++r) {
      int o = m * 16 + lq * 4 + r;
      float h = acc2[m][r] * clds[128 + o] + clds[192 + o] + xres[m][r];
      h = (h >= 0.f) ? h : 0.1f * h;
      int byteoff = (w * 16 + cl) * 128 + ((o * 2) ^ swz);
      *reinterpret_cast<short*>(reinterpret_cast<char*>(h1t) + byteoff) = (short)f2bf(h);
    }
  }
  __syncthreads();

  {
    int row = tid >> 2, ch = tid & 3;
    int prow = p0 + row;
    if (prow < P_) {
      int sw = (row & 7) << 4;
      uint4 d0 = *reinterpret_cast<uint4*>(reinterpret_cast<char*>(h1t) + row * 128 + (((2 * ch) * 16) ^ sw));
      uint4 d1 = *reinterpret_cast<uint4*>(reinterpret_cast<char*>(h1t) + row * 128 + (((2 * ch + 1) * 16) ^ sw));
      char* dst = reinterpret_cast<char*>(h2Tg) + ((size_t)n * HROWS + HGUARD + prow) * 256 + ch * 32;
      *reinterpret_cast<uint4*>(dst) = d0;
      *reinterpret_cast<uint4*>(dst + 16) = d1;
    }
  }
}

// k4c: temporal conv as K=192 MFMA GEMM + bn3/res/lrelu -> out
__global__ __launch_bounds__(256) void k4c(
    const unsigned short* __restrict__ h2Tg,
    const unsigned short* __restrict__ Wtb,
    const float* __restrict__ cst,
    float* __restrict__ out)
{
  const int n = blockIdx.x;
  const int p0 = blockIdx.y * 64;
  const int tid = threadIdx.x;
  const int w = tid >> 6;
  const int l = tid & 63;
  const int cl = l & 15;
  const int lq = l >> 4;
  const int p = p0 + w * 16 + cl;

  __shared__ float clds[128];
  if (tid < 128) clds[tid] = cst[256 + tid];

  const unsigned short* hrow = h2Tg + ((size_t)n * HROWS + HGUARD + p) * 128;
  bhalf8 bfr[6];
#pragma unroll
  for (int ks = 0; ks < 6; ++ks) {
    int k0 = ks * 32 + lq * 8;
    int dt = k0 >> 6;
    int i0 = k0 & 63;
    bfr[ks] = *reinterpret_cast<const bhalf8*>(hrow + (size_t)(dt - 1) * 27 * 128 + i0);
  }
  fx4 acc[4];
#pragma unroll
  for (int m = 0; m < 4; ++m) { acc[m][0]=0.f; acc[m][1]=0.f; acc[m][2]=0.f; acc[m][3]=0.f; }
#pragma unroll
  for (int m = 0; m < 4; ++m) {
#pragma unroll
    for (int ks = 0; ks < 6; ++ks) {
      bhalf8 a = *reinterpret_cast<const bhalf8*>(Wtb + (m * 16 + cl) * 192 + ks * 32 + lq * 8);
      acc[m] = __builtin_amdgcn_mfma_f32_16x16x32_bf16(a, bfr[ks], acc[m], 0, 0, 0);
    }
  }
  __syncthreads();
  if (p < P_) {
#pragma unroll
    for (int m = 0; m < 4; ++m) {
#pragma unroll
      for (int r = 0; r < 4; ++r) {
        int o = m * 16 + lq * 4 + r;
        float hc = bf2f(hrow[o]);
        float val = acc[m][r] * clds[o] + clds[64 + o] + hc;
        val = (val >= 0.f) ? val : 0.1f * val;
        out[((size_t)(n * CO_ + o)) * (size_t)P_ + p] = val;
      }
    }
  }
}

// ================= fallback path (R2 kernels) =================
__global__ __launch_bounds__(256) void k1_qk_partial(
    const float* __restrict__ x, const float* __restrict__ pe,
    const float* __restrict__ w_in, const float* __restrict__ b_in,
    float* __restrict__ partial)
{
  const int n = blockIdx.x;
  const int chunk = blockIdx.y;
  const int tid = threadIdx.x;
  __shared__ float ylds[C_][28];
  __shared__ float qlds[C_][28];
  __shared__ float wlds[C_][65];
  for (int i = tid; i < C_ * C_; i += 256) wlds[i >> 6][i & 63] = w_in[i];
  float acc[6];
#pragma unroll
  for (int j = 0; j < 6; ++j) acc[j] = 0.f;
  const int t0 = chunk * TCHUNK;
  for (int tt = 0; tt < TCHUNK; ++tt) {
    const int t = t0 + tt;
    __syncthreads();
    for (int i = tid; i < C_ * V_; i += 256) {
      int c = i / V_, v = i - c * V_;
      ylds[c][v] = x[((size_t)(n * C_ + c) * T_ + t) * V_ + v] + pe[(c * T_ + t) * V_ + v];
    }
    __syncthreads();
    for (int i = tid; i < C_ * V_; i += 256) {
      int o = i / V_, v = i - o * V_;
      float s = b_in[o];
#pragma unroll
      for (int c = 0; c < C_; ++c) s += wlds[o][c] * ylds[c][v];
      qlds[o][v] = s;
    }
    __syncthreads();
#pragma unroll
    for (int j = 0; j < 6; ++j) {
      int i = tid + j * 256;
      if (i < ATT_N) {
        int s = i / 729, r = i - s * 729, u = r / 27, v = r - u * 27;
        float a = 0.f;
#pragma unroll
        for (int c = 0; c < CI_; ++c)
          a += qlds[s * CI_ + c][u] * qlds[S_ * CI_ + s * CI_ + c][v];
        acc[j] += a;
      }
    }
  }
  float* dst = partial + (size_t)(n * NCHUNK + chunk) * ATT_N;
#pragma unroll
  for (int j = 0; j < 6; ++j) {
    int i = tid + j * 256;
    if (i < ATT_N) dst[i] = acc[j];
  }
}

__global__ __launch_bounds__(256) void k2_att_fin(
    const float* __restrict__ partial, const float* __restrict__ alphas,
    const float* __restrict__ att0, float* __restrict__ att)
{
  int i = blockIdx.x * 256 + threadIdx.x;
  if (i >= N_ * ATT_N) return;
  int n = i / ATT_N, r = i - n * ATT_N;
  int s = r / 729;
  float a = 0.f;
  const float* p = partial + (size_t)n * NCHUNK * ATT_N + r;
  for (int ch = 0; ch < NCHUNK; ++ch) a += p[(size_t)ch * ATT_N];
  a = tanhf(a * (1.0f / (CI_ * (float)T_))) * alphas[s] + att0[r];
  att[i] = a;
}

__global__ __launch_bounds__(256) void k3a(
    const float* __restrict__ x, const float* __restrict__ att,
    const float* __restrict__ w_out, const float* __restrict__ b_out,
    const float* __restrict__ bn1_g, const float* __restrict__ bn1_b,
    const float* __restrict__ bn1_m, const float* __restrict__ bn1_v,
    const float* __restrict__ w_ff, const float* __restrict__ b_ff,
    const float* __restrict__ bn2_g, const float* __restrict__ bn2_b,
    const float* __restrict__ bn2_m, const float* __restrict__ bn2_v,
    float* __restrict__ h2g)
{
  const int n = blockIdx.x;
  const int t0 = blockIdx.y * 2;
  const int tid = threadIdx.x;
  const int v = tid & 31;
  const int tloc = (tid >> 5) & 1;
  const int col = tid & 63;
  const int rg = __builtin_amdgcn_readfirstlane(tid >> 6);
  const int t = t0 + tloc;

  __shared__ float xlds[C_][64];
  __shared__ float zlds[S_ * C_][64];

  for (int i = tid; i < C_ * 64; i += 256) {
    int c = i >> 6, cl = i & 63, tl = cl >> 5, vv = cl & 31;
    xlds[c][cl] = (vv < V_) ? x[((size_t)(n * C_ + c) * T_ + t0 + tl) * V_ + vv] : 0.f;
  }
  float attreg[S_][V_];
  {
    const float* ab = att + (size_t)n * ATT_N + v;
#pragma unroll
    for (int s = 0; s < S_; ++s)
#pragma unroll
      for (int u = 0; u < V_; ++u)
        attreg[s][u] = (v < V_) ? ab[s * 729 + u * 27] : 0.f;
  }
  __syncthreads();
#pragma unroll 1
  for (int cc = 0; cc < 16; ++cc) {
    const int c = rg * 16 + cc;
    float xr[V_];
#pragma unroll
    for (int u = 0; u < V_; ++u) xr[u] = xlds[c][tloc * 32 + u];
    float a0 = 0.f, a1 = 0.f;
#pragma unroll
    for (int u = 0; u < V_; ++u) {
      a0 += xr[u] * attreg[0][u];
      a1 += xr[u] * attreg[1][u];
    }
    zlds[c][col] = a0;
    zlds[C_ + c][col] = a1;
  }
  __syncthreads();
  float acc[16];
#pragma unroll
  for (int oo = 0; oo < 16; ++oo) acc[oo] = 0.f;
#pragma unroll 1
  for (int kc = 0; kc < 4; ++kc) {
    float zk[32];
#pragma unroll
    for (int j = 0; j < 32; ++j) zk[j] = zlds[kc * 32 + j][col];
#pragma unroll
    for (int oo = 0; oo < 16; ++oo) {
      const float* wr = w_out + (rg * 16 + oo) * (S_ * C_) + kc * 32;
      float s = acc[oo];
#pragma unroll
      for (int j = 0; j < 32; ++j) s += wr[j] * zk[j];
      acc[oo] = s;
    }
  }
  float h1v[16];
#pragma unroll
  for (int oo = 0; oo < 16; ++oo) {
    const int o = rg * 16 + oo;
    float y3 = acc[oo] + b_out[o];
    float h = (y3 - bn1_m[o]) * (bn1_g[o] * rsqrtf(bn1_v[o] + 1e-5f)) + bn1_b[o]
              + xlds[o][col];
    h1v[oo] = (h >= 0.f) ? h : 0.1f * h;
  }
  __syncthreads();
#pragma unroll
  for (int oo = 0; oo < 16; ++oo) zlds[rg * 16 + oo][col] = h1v[oo];
  __syncthreads();
#pragma unroll
  for (int oo = 0; oo < 16; ++oo) acc[oo] = 0.f;
#pragma unroll 1
  for (int kc = 0; kc < 2; ++kc) {
    float zk[32];
#pragma unroll
    for (int j = 0; j < 32; ++j) zk[j] = zlds[kc * 32 + j][col];
#pragma unroll
    for (int oo = 0; oo < 16; ++oo) {
      const float* wr = w_ff + (rg * 16 + oo) * C_ + kc * 32;
      float s = acc[oo];
#pragma unroll
      for (int j = 0; j < 32; ++j) s += wr[j] * zk[j];
      acc[oo] = s;
    }
  }
  if (v < V_) {
#pragma unroll
    for (int oo = 0; oo < 16; ++oo) {
      const int o = rg * 16 + oo;
      float f = acc[oo] + b_ff[o];
      float h = (f - bn2_m[o]) * (bn2_g[o] * rsqrtf(bn2_v[o] + 1e-5f)) + bn2_b[o]
                + xlds[o][col];
      h2g[((size_t)(n * CO_ + o) * T_ + t) * V_ + v] = (h >= 0.f) ? h : 0.1f * h;
    }
  }
}

__global__ __launch_bounds__(256) void k3b(
    const float* __restrict__ h2g, const float* __restrict__ w_t,
    const float* __restrict__ b_t,
    const float* __restrict__ bn3_g, const float* __restrict__ bn3_b,
    const float* __restrict__ bn3_m, const float* __restrict__ bn3_v,
    float* __restrict__ out)
{
  const int n = blockIdx.x;
  const int t0 = blockIdx.y * 2;
  const int tid = threadIdx.x;
  const int v = tid & 31;
  const int tloc = (tid >> 5) & 1;
  const int rg = __builtin_amdgcn_readfirstlane(tid >> 6);
  const int t = t0 + tloc;

  __shared__ float hl[C_][4][32];

  for (int idx = tid; idx < C_ * 4 * 32; idx += 256) {
    int i = idx >> 7, r = idx & 127, sl = r >> 5, vv = r & 31;
    int tg = t0 - 1 + sl;
    hl[i][sl][vv] = (vv < V_ && tg >= 0 && tg < T_)
                    ? h2g[((size_t)(n * CO_ + i) * T_ + tg) * V_ + vv] : 0.f;
  }
  __syncthreads();

  float acc[16];
#pragma unroll
  for (int oo = 0; oo < 16; ++oo) acc[oo] = 0.f;
#pragma unroll 1
  for (int ic = 0; ic < 4; ++ic) {
    float h[16][3];
#pragma unroll
    for (int ii = 0; ii < 16; ++ii) {
      h[ii][0] = hl[ic * 16 + ii][tloc][v];
      h[ii][1] = hl[ic * 16 + ii][tloc + 1][v];
      h[ii][2] = hl[ic * 16 + ii][tloc + 2][v];
    }
#pragma unroll
    for (int oo = 0; oo < 16; ++oo) {
      const float* wr = w_t + ((size_t)(rg * 16 + oo) * C_ + ic * 16) * 3;
      float s = acc[oo];
#pragma unroll
      for (int ii = 0; ii < 16; ++ii) {
        s += wr[ii * 3 + 0] * h[ii][0]
           + wr[ii * 3 + 1] * h[ii][1]
           + wr[ii * 3 + 2] * h[ii][2];
      }
      acc[oo] = s;
    }
  }
  if (v < V_) {
#pragma unroll
    for (int oo = 0; oo < 16; ++oo) {
      const int o = rg * 16 + oo;
      float zv = acc[oo] + b_t[o];
      float r = (zv - bn3_m[o]) * (bn3_g[o] * rsqrtf(bn3_v[o] + 1e-5f)) + bn3_b[o]
                + hl[o][tloc + 1][v];
      out[((size_t)(n * CO_ + o) * T_ + t) * V_ + v] = (r >= 0.f) ? r : 0.1f * r;
    }
  }
}

extern "C" void kernel_launch(void* const* d_in, const int* in_sizes, int n_in,
                              void* d_out, int out_size, void* d_ws, size_t ws_size,
                              hipStream_t stream)
{
  (void)in_sizes; (void)n_in; (void)out_size;
  const float* x      = (const float*)d_in[0];
  const float* pe     = (const float*)d_in[1];
  const float* w_in   = (const float*)d_in[2];
  const float* b_in   = (const float*)d_in[3];
  const float* alphas = (const float*)d_in[4];
  const float* att0   = (const float*)d_in[5];
  const float* w_out  = (const float*)d_in[6];
  const float* b_out  = (const float*)d_in[7];
  const float* bn1_g  = (const float*)d_in[8];
  const float* bn1_b  = (const float*)d_in[9];
  const float* bn1_m  = (const float*)d_in[10];
  const float* bn1_v  = (const float*)d_in[11];
  const float* w_ff   = (const float*)d_in[12];
  const float* b_ff   = (const float*)d_in[13];
  const float* bn2_g  = (const float*)d_in[14];
  const float* bn2_b  = (const float*)d_in[15];
  const float* bn2_m  = (const float*)d_in[16];
  const float* bn2_v  = (const float*)d_in[17];
  const float* w_t    = (const float*)d_in[18];
  const float* b_t    = (const float*)d_in[19];
  const float* bn3_g  = (const float*)d_in[20];
  const float* bn3_b  = (const float*)d_in[21];
  const float* bn3_m  = (const float*)d_in[22];
  const float* bn3_v  = (const float*)d_in[23];
  float* out = (float*)d_out;

  char* ws = (char*)d_ws;
  // MFMA-path layout (ZT aliases the dead yT/qkT region)
  unsigned short* Wb   = (unsigned short*)(ws);              // 57,344 B
  float*          cst  = (float*)(ws + 57344);               // 1,792 B
  unsigned short* attT = (unsigned short*)(ws + 59136);      // 131,072 B
  unsigned short* yT   = (unsigned short*)(ws + 190208);     // 44,302,336 B
  unsigned short* qkT  = (unsigned short*)(ws + 44492544);   // 52,428,800 B
  unsigned short* h2T  = (unsigned short*)(ws + 96921344);   // 89,260,032 B
  unsigned short* ZT   = (unsigned short*)(ws + 190208);     // 88,604,672 B (alias)
  const size_t need_mfma = 186181376;
  const size_t need_old  = ((size_t)N_ * NCHUNK * ATT_N + (size_t)N_ * ATT_N
                            + (size_t)N_ * CO_ * T_ * V_) * sizeof(float);

  if (ws_size >= need_mfma) {
    kprep<<<64, 256, 0, stream>>>(w_out, w_ff, w_t, w_in, b_out, b_ff, b_t, b_in,
        bn1_g, bn1_b, bn1_m, bn1_v, bn2_g, bn2_b, bn2_m, bn2_v,
        bn3_g, bn3_b, bn3_m, bn3_v, Wb, cst, h2T);
    ky<<<dim3(N_, PTILES), 256, 0, stream>>>(x, pe, yT);
    k1a<<<dim3(N_, PTILES), 256, 0, stream>>>(yT, Wb, cst, qkT);
    k1b<<<64, 256, 0, stream>>>(qkT, alphas, att0, attT);
    kz_mfma<<<dim3(N_, 25), 256, 0, stream>>>(x, attT, ZT);
    k4b<<<dim3(N_, PTILES), 256, 0, stream>>>(x, ZT, Wb, cst, h2T);
    k4c<<<dim3(N_, PTILES), 256, 0, stream>>>(h2T, Wb + 12288, cst, out);
  } else if (ws_size >= need_old) {
    float* partial = (float*)ws;
    float* att     = partial + (size_t)N_ * NCHUNK * ATT_N;
    float* h2g     = att + (size_t)N_ * ATT_N;
    k1_qk_partial<<<dim3(N_, NCHUNK), 256, 0, stream>>>(x, pe, w_in, b_in, partial);
    k2_att_fin<<<(N_ * ATT_N + 255) / 256, 256, 0, stream>>>(partial, alphas, att0, att);
    k3a<<<dim3(N_, T_ / 2), 256, 0, stream>>>(x, att,
        w_out, b_out, bn1_g, bn1_b, bn1_m, bn1_v,
        w_ff, b_ff, bn2_g, bn2_b, bn2_m, bn2_v, h2g);
    k3b<<<dim3(N_, T_ / 2), 256, 0, stream>>>(h2g, w_t, b_t,
        bn3_g, bn3_b, bn3_m, bn3_v, out);
  }
}

// Round 5
// 268.900 us; speedup vs baseline: 5.0615x; 1.3768x over previous
//
#include <hip/hip_runtime.h>

#define N_ 32
#define C_ 64
#define T_ 400
#define V_ 27
#define S_ 2
#define CI_ 16
#define CO_ 64
#define TCHUNK 8
#define NCHUNK 50
#define ATT_N 1458           // S_*V_*V_
#define P_ 10800             // T_*V_
#define PT_ 10816            // 169*64
#define PTILES 169
#define HGUARD 32
#define HROWS 10896          // HGUARD + PT_ + 48

typedef short bhalf8 __attribute__((ext_vector_type(8)));
typedef float fx4 __attribute__((ext_vector_type(4)));

static __device__ inline unsigned short f2bf(float f) {
  unsigned u = __builtin_bit_cast(unsigned, f);
  u += 0x7fffu + ((u >> 16) & 1u);
  return (unsigned short)(u >> 16);
}
static __device__ inline float bf2f(unsigned short h) {
  unsigned u = ((unsigned)h) << 16;
  return __builtin_bit_cast(float, u);
}

// ================= MFMA path =================

// kprep: bf16 weights (Wout|Wff|Wt|Wi), fused bn consts + b_in, zero h2T guards
__global__ __launch_bounds__(256) void kprep(
    const float* __restrict__ w_out, const float* __restrict__ w_ff,
    const float* __restrict__ w_t, const float* __restrict__ w_in,
    const float* __restrict__ b_out, const float* __restrict__ b_ff,
    const float* __restrict__ b_t, const float* __restrict__ b_in,
    const float* __restrict__ bn1_g, const float* __restrict__ bn1_b,
    const float* __restrict__ bn1_m, const float* __restrict__ bn1_v,
    const float* __restrict__ bn2_g, const float* __restrict__ bn2_b,
    const float* __restrict__ bn2_m, const float* __restrict__ bn2_v,
    const float* __restrict__ bn3_g, const float* __restrict__ bn3_b,
    const float* __restrict__ bn3_m, const float* __restrict__ bn3_v,
    unsigned short* __restrict__ Wb, float* __restrict__ cst,
    unsigned short* __restrict__ h2Tg)
{
  const int tid = threadIdx.x;
  const int bid = blockIdx.x;
  uint4 z; z.x = 0; z.y = 0; z.z = 0; z.w = 0;
  for (int i = bid * 256 + tid; i < N_ * 1536; i += 64 * 256) {
    int n = i / 1536, r = i - n * 1536;
    size_t off = (r < 512) ? (size_t)r * 8 : (size_t)10832 * 128 + (size_t)(r - 512) * 8;
    *reinterpret_cast<uint4*>(h2Tg + (size_t)n * HROWS * 128 + off) = z;
  }
  if (bid != 0) return;
  for (int i = tid; i < 8192; i += 256) Wb[i] = f2bf(w_out[i]);
  for (int i = tid; i < 4096; i += 256) Wb[8192 + i] = f2bf(w_ff[i]);
  for (int i = tid; i < 12288; i += 256) {
    int o = i / 192, r = i - o * 192, dt = r >> 6, ic = r & 63;
    Wb[12288 + i] = f2bf(w_t[(size_t)(o * 64 + ic) * 3 + dt]);
  }
  for (int i = tid; i < 4096; i += 256) Wb[24576 + i] = f2bf(w_in[i]);
  if (tid < 64) {
    int o = tid;
    float a1 = bn1_g[o] * rsqrtf(bn1_v[o] + 1e-5f);
    cst[o] = a1;
    cst[64 + o] = (b_out[o] - bn1_m[o]) * a1 + bn1_b[o];
    float a2 = bn2_g[o] * rsqrtf(bn2_v[o] + 1e-5f);
    cst[128 + o] = a2;
    cst[192 + o] = (b_ff[o] - bn2_m[o]) * a2 + bn2_b[o];
    float a3 = bn3_g[o] * rsqrtf(bn3_v[o] + 1e-5f);
    cst[256 + o] = a3;
    cst[320 + o] = (b_t[o] - bn3_m[o]) * a3 + bn3_b[o];
    cst[384 + o] = b_in[o];
  }
}

// ky: yT[n][p][c] bf16 = transpose(x + pe)
__global__ __launch_bounds__(256) void ky(
    const float* __restrict__ x, const float* __restrict__ pe,
    unsigned short* __restrict__ yT)
{
  const int n = blockIdx.x;
  const int p0 = blockIdx.y * 64;
  const int tid = threadIdx.x;
  __shared__ float xl[64][65];
  {
    int c = tid >> 2, ch = tid & 3;
    const float* xr = x + (size_t)(n * C_ + c) * P_;
    const float* pr = pe + (size_t)c * P_;
    if (p0 + 64 <= P_) {
#pragma unroll
      for (int q = 0; q < 4; ++q) {
        int p = p0 + ch * 16 + q * 4;
        float4 a = *reinterpret_cast<const float4*>(xr + p);
        float4 b = *reinterpret_cast<const float4*>(pr + p);
        xl[c][ch * 16 + q * 4 + 0] = a.x + b.x;
        xl[c][ch * 16 + q * 4 + 1] = a.y + b.y;
        xl[c][ch * 16 + q * 4 + 2] = a.z + b.z;
        xl[c][ch * 16 + q * 4 + 3] = a.w + b.w;
      }
    } else {
#pragma unroll
      for (int j = 0; j < 16; ++j) {
        int p = p0 + ch * 16 + j;
        xl[c][ch * 16 + j] = (p < P_) ? (xr[p] + pr[p]) : 0.f;
      }
    }
  }
  __syncthreads();
  {
    int pr2 = tid >> 2, c0 = (tid & 3) * 16;
    unsigned vals[8];
#pragma unroll
    for (int q = 0; q < 8; ++q) {
      unsigned lo = f2bf(xl[c0 + 2 * q][pr2]);
      unsigned hi = f2bf(xl[c0 + 2 * q + 1][pr2]);
      vals[q] = lo | (hi << 16);
    }
    unsigned short* dst = yT + ((size_t)n * PT_ + p0 + pr2) * 64 + c0;
    uint4 d0; d0.x = vals[0]; d0.y = vals[1]; d0.z = vals[2]; d0.w = vals[3];
    uint4 d1; d1.x = vals[4]; d1.y = vals[5]; d1.z = vals[6]; d1.w = vals[7];
    *reinterpret_cast<uint4*>(dst) = d0;
    *reinterpret_cast<uint4*>(dst + 8) = d1;
  }
}

// k1a: qk = Wi(64x64) . yT  -> qkT[n][m][u32][t*16+ci] bf16
__global__ __launch_bounds__(256) void k1a(
    const unsigned short* __restrict__ yT,
    const unsigned short* __restrict__ Wb,
    const float* __restrict__ cst,
    unsigned short* __restrict__ qkT)
{
  const int n = blockIdx.x;
  const int p0 = blockIdx.y * 64;
  const int tid = threadIdx.x;
  const int w = tid >> 6;
  const int l = tid & 63;
  const int cl = l & 15;
  const int lq = l >> 4;
  const int p = p0 + w * 16 + cl;

  __shared__ float clds[64];
  if (tid < 64) clds[tid] = cst[384 + tid];

  bhalf8 bfr[2];
  const unsigned short* yrow = yT + ((size_t)n * PT_ + p) * 64;
  bfr[0] = *reinterpret_cast<const bhalf8*>(yrow + lq * 8);
  bfr[1] = *reinterpret_cast<const bhalf8*>(yrow + 32 + lq * 8);

  const unsigned short* Wi = Wb + 24576;
  fx4 acc[4];
#pragma unroll
  for (int m = 0; m < 4; ++m) { acc[m][0]=0.f; acc[m][1]=0.f; acc[m][2]=0.f; acc[m][3]=0.f; }
#pragma unroll
  for (int m = 0; m < 4; ++m) {
#pragma unroll
    for (int ks = 0; ks < 2; ++ks) {
      bhalf8 a = *reinterpret_cast<const bhalf8*>(Wi + (m * 16 + cl) * 64 + ks * 32 + lq * 8);
      acc[m] = __builtin_amdgcn_mfma_f32_16x16x32_bf16(a, bfr[ks], acc[m], 0, 0, 0);
    }
  }
  __syncthreads();
  if (p < P_) {
    int t = p / 27, u = p - t * 27;
#pragma unroll
    for (int m = 0; m < 4; ++m) {
      unsigned short o0 = f2bf(acc[m][0] + clds[m * 16 + lq * 4 + 0]);
      unsigned short o1 = f2bf(acc[m][1] + clds[m * 16 + lq * 4 + 1]);
      unsigned short o2 = f2bf(acc[m][2] + clds[m * 16 + lq * 4 + 2]);
      unsigned short o3 = f2bf(acc[m][3] + clds[m * 16 + lq * 4 + 3]);
      uint2 d;
      d.x = (unsigned)o0 | ((unsigned)o1 << 16);
      d.y = (unsigned)o2 | ((unsigned)o3 << 16);
      *reinterpret_cast<uint2*>(qkT + (((size_t)(n * 4 + m) * 32 + u) * 6400 + t * 16 + lq * 4)) = d;
    }
  }
}

// k1b: att GEMM over K=6400, finalize tanh*alpha+att0 -> attT[n][s][v32][u32] bf16 (zero-padded)
__global__ __launch_bounds__(256) void k1b(
    const unsigned short* __restrict__ qkT,
    const float* __restrict__ alphas, const float* __restrict__ att0,
    unsigned short* __restrict__ attT)
{
  const int n = blockIdx.x >> 1;
  const int s = blockIdx.x & 1;
  const int tid = threadIdx.x;
  const int w = tid >> 6;
  const int l = tid & 63;
  const int cl = l & 15;
  const int lq = l >> 4;

  const unsigned short* qb = qkT + (size_t)(n * 4 + s) * 32 * 6400;
  const unsigned short* kb = qkT + (size_t)(n * 4 + 2 + s) * 32 * 6400;

  fx4 acc[2][2];
#pragma unroll
  for (int a1 = 0; a1 < 2; ++a1)
#pragma unroll
    for (int a2 = 0; a2 < 2; ++a2) { acc[a1][a2][0]=0.f; acc[a1][a2][1]=0.f; acc[a1][a2][2]=0.f; acc[a1][a2][3]=0.f; }

#pragma unroll 2
  for (int step = 0; step < 50; ++step) {
    int k0 = w * 1600 + step * 32 + lq * 8;
    bhalf8 aq0 = *reinterpret_cast<const bhalf8*>(qb + (size_t)cl * 6400 + k0);
    bhalf8 aq1 = *reinterpret_cast<const bhalf8*>(qb + (size_t)(16 + cl) * 6400 + k0);
    bhalf8 bk0 = *reinterpret_cast<const bhalf8*>(kb + (size_t)cl * 6400 + k0);
    bhalf8 bk1 = *reinterpret_cast<const bhalf8*>(kb + (size_t)(16 + cl) * 6400 + k0);
    acc[0][0] = __builtin_amdgcn_mfma_f32_16x16x32_bf16(aq0, bk0, acc[0][0], 0, 0, 0);
    acc[0][1] = __builtin_amdgcn_mfma_f32_16x16x32_bf16(aq0, bk1, acc[0][1], 0, 0, 0);
    acc[1][0] = __builtin_amdgcn_mfma_f32_16x16x32_bf16(aq1, bk0, acc[1][0], 0, 0, 0);
    acc[1][1] = __builtin_amdgcn_mfma_f32_16x16x32_bf16(aq1, bk1, acc[1][1], 0, 0, 0);
  }

  __shared__ float red[4][4][4][64];
#pragma unroll
  for (int mt = 0; mt < 2; ++mt)
#pragma unroll
    for (int nt = 0; nt < 2; ++nt)
#pragma unroll
      for (int r = 0; r < 4; ++r)
        red[w][mt * 2 + nt][r][l] = acc[mt][nt][r];
  __syncthreads();

  const int mn = w, mt = w >> 1, nt = w & 1;
  const int v = nt * 16 + cl;
  const float alpha = alphas[s];
  unsigned short outs[4];
#pragma unroll
  for (int r = 0; r < 4; ++r) {
    float sum = red[0][mn][r][l] + red[1][mn][r][l] + red[2][mn][r][l] + red[3][mn][r][l];
    int u = mt * 16 + lq * 4 + r;
    float val = 0.f;
    if (u < V_ && v < V_)
      val = tanhf(sum * (1.0f / 6400.0f)) * alpha + att0[(s * V_ + u) * V_ + v];
    outs[r] = f2bf(val);
  }
  uint2 d;
  d.x = (unsigned)outs[0] | ((unsigned)outs[1] << 16);
  d.y = (unsigned)outs[2] | ((unsigned)outs[3] << 16);
  *reinterpret_cast<uint2*>(attT + (((size_t)(n * 2 + s) * 32 + v) * 32 + mt * 16 + lq * 4)) = d;
}

// kz: y2 = x . att per t via MFMA; D-frags staged in swizzled LDS, coalesced ZT writes
__global__ __launch_bounds__(256) void kz_mfma(
    const float* __restrict__ x,
    const unsigned short* __restrict__ attT,
    unsigned short* __restrict__ ZT)
{
  const int n = blockIdx.x;
  const int t0 = blockIdx.y * 16;
  const int tid = threadIdx.x;
  const int w = tid >> 6;
  const int l = tid & 63;
  const int cl = l & 15;
  const int lq = l >> 4;

  __shared__ __align__(16) char zst[4][6912];   // per-wave 27 rows x 256B, swizzled

  bhalf8 batt[2][2];
#pragma unroll
  for (int s = 0; s < 2; ++s)
#pragma unroll
    for (int vt = 0; vt < 2; ++vt)
      batt[s][vt] = *reinterpret_cast<const bhalf8*>(
          attT + ((size_t)(n * 2 + s) * 32 + vt * 16 + cl) * 32 + lq * 8);

#pragma unroll 1
  for (int tt = 0; tt < 4; ++tt) {
    const int t = t0 + w * 4 + tt;
    bhalf8 ax[4];
    if (t < T_ - 1) {
#pragma unroll
      for (int m = 0; m < 4; ++m) {
        const float* base = x + (size_t)(n * C_ + m * 16 + cl) * P_ + t * 27 + lq * 8;
        float4 f0 = *reinterpret_cast<const float4*>(base);
        float4 f1 = *reinterpret_cast<const float4*>(base + 4);
        ax[m][0] = (short)f2bf(f0.x); ax[m][1] = (short)f2bf(f0.y);
        ax[m][2] = (short)f2bf(f0.z); ax[m][3] = (short)f2bf(f0.w);
        ax[m][4] = (short)f2bf(f1.x); ax[m][5] = (short)f2bf(f1.y);
        ax[m][6] = (short)f2bf(f1.z); ax[m][7] = (short)f2bf(f1.w);
      }
    } else {
#pragma unroll
      for (int m = 0; m < 4; ++m) {
        const float* xr = x + (size_t)(n * C_ + m * 16 + cl) * P_;
#pragma unroll
        for (int j = 0; j < 8; ++j) {
          int idx = t * 27 + lq * 8 + j;
          idx = (idx < P_) ? idx : (P_ - 1);
          ax[m][j] = (short)f2bf(xr[idx]);
        }
      }
    }
#pragma unroll
    for (int s = 0; s < 2; ++s) {
#pragma unroll
      for (int vt = 0; vt < 2; ++vt) {
        const int v = vt * 16 + cl;
#pragma unroll
        for (int m = 0; m < 4; ++m) {
          fx4 z; z[0] = 0.f; z[1] = 0.f; z[2] = 0.f; z[3] = 0.f;
          fx4 dacc = __builtin_amdgcn_mfma_f32_16x16x32_bf16(ax[m], batt[s][vt], z, 0, 0, 0);
          if (v < V_) {
            unsigned short o0 = f2bf(dacc[0]);
            unsigned short o1 = f2bf(dacc[1]);
            unsigned short o2 = f2bf(dacc[2]);
            unsigned short o3 = f2bf(dacc[3]);
            uint2 d;
            d.x = (unsigned)o0 | ((unsigned)o1 << 16);
            d.y = (unsigned)o2 | ((unsigned)o3 << 16);
            int byteoff = ((s * 64 + m * 16 + lq * 4) * 2) ^ ((v & 7) << 4);
            *reinterpret_cast<uint2*>(zst[w] + v * 256 + byteoff) = d;
          }
        }
      }
    }
    __syncthreads();
    // coalesced readout: 27 rows x 16 uint4
    for (int i = l; i < 432; i += 64) {
      int rr = i >> 4, ch = i & 15;
      uint4 d = *reinterpret_cast<uint4*>(zst[w] + rr * 256 + ((ch * 16) ^ ((rr & 7) << 4)));
      *reinterpret_cast<uint4*>(ZT + ((size_t)n * PT_ + (size_t)t * 27 + rr) * 128 + ch * 8) = d;
    }
    __syncthreads();
  }
}

// k4b: LDS-staged MFMA Wout.Z -> bn1/res/lrelu -> Wff.H1 -> bn2/res/lrelu -> h2T bf16
__global__ __launch_bounds__(256) void k4b(
    const float* __restrict__ x,
    const unsigned short* __restrict__ ZT,
    const unsigned short* __restrict__ Wb,
    const float* __restrict__ cst,
    unsigned short* __restrict__ h2Tg)
{
  const int n = blockIdx.x;
  const int p0 = blockIdx.y * 64;
  const int tid = threadIdx.x;
  const int w = tid >> 6;
  const int l = tid & 63;
  const int cl = l & 15;
  const int lq = l >> 4;
  const int p = p0 + w * 16 + cl;
  const int pc = (p < P_) ? p : (P_ - 1);
  const int swz = (cl & 7) << 4;

  __shared__ __align__(16) char zstg[16384];    // 64 rows x 256B, swizzled
  __shared__ __align__(16) char wout[16384];    // 64 rows x 256B, swizzled
  __shared__ __align__(16) char wffl[8192];     // 64 rows x 128B, swizzled
  __shared__ short h1t[64 * 64];
  __shared__ float clds[256];
  for (int i = tid; i < 256; i += 256) clds[i] = cst[i];

  // stage Z tile + weights (coalesced)
  for (int i = tid; i < 1024; i += 256) {
    int r = i >> 4, ch = i & 15;
    uint4 d = *reinterpret_cast<const uint4*>(ZT + ((size_t)n * PT_ + p0 + r) * 128 + ch * 8);
    *reinterpret_cast<uint4*>(zstg + r * 256 + ((ch * 16) ^ ((r & 7) << 4))) = d;
  }
  for (int i = tid; i < 1024; i += 256) {
    int r = i >> 4, ch = i & 15;
    uint4 d = *reinterpret_cast<const uint4*>(Wb + r * 128 + ch * 8);
    *reinterpret_cast<uint4*>(wout + r * 256 + ((ch * 16) ^ ((r & 7) << 4))) = d;
  }
  for (int i = tid; i < 512; i += 256) {
    int r = i >> 3, ch = i & 7;
    uint4 d = *reinterpret_cast<const uint4*>(Wb + 8192 + r * 64 + ch * 8);
    *reinterpret_cast<uint4*>(wffl + r * 128 + ((ch * 16) ^ ((r & 7) << 4))) = d;
  }
  __syncthreads();

  // phase3: y3 = Wout(64x128) . Z
  const int rl = w * 16 + cl;
  bhalf8 bfr[4];
#pragma unroll
  for (int ks = 0; ks < 4; ++ks)
    bfr[ks] = *reinterpret_cast<const bhalf8*>(zstg + rl * 256 + ((ks * 64 + lq * 16) ^ ((rl & 7) << 4)));
  fx4 acc[4];
#pragma unroll
  for (int m = 0; m < 4; ++m) { acc[m][0]=0.f; acc[m][1]=0.f; acc[m][2]=0.f; acc[m][3]=0.f; }
#pragma unroll
  for (int m = 0; m < 4; ++m) {
    const int row = m * 16 + cl;
#pragma unroll
    for (int ks = 0; ks < 4; ++ks) {
      bhalf8 a = *reinterpret_cast<const bhalf8*>(wout + row * 256 + ((ks * 64 + lq * 16) ^ ((row & 7) << 4)));
      acc[m] = __builtin_amdgcn_mfma_f32_16x16x32_bf16(a, bfr[ks], acc[m], 0, 0, 0);
    }
  }

  // bn1 + residual + lrelu -> H1 (bf16, transposed+swizzled in LDS)
  float xres[4][4];
#pragma unroll
  for (int m = 0; m < 4; ++m) {
#pragma unroll
    for (int r = 0; r < 4; ++r) {
      int o = m * 16 + lq * 4 + r;
      float xv = x[((size_t)(n * C_ + o)) * (size_t)P_ + pc];
      xres[m][r] = xv;
      float h = acc[m][r] * clds[o] + clds[64 + o] + xv;
      h = (h >= 0.f) ? h : 0.1f * h;
      int byteoff = rl * 128 + ((o * 2) ^ swz);
      *reinterpret_cast<short*>(reinterpret_cast<char*>(h1t) + byteoff) = (short)f2bf(h);
    }
  }

  // phase4: f = Wff(64x64) . H1 (per-wave rows, in-order LDS)
  fx4 acc2[4];
#pragma unroll
  for (int m = 0; m < 4; ++m) { acc2[m][0]=0.f; acc2[m][1]=0.f; acc2[m][2]=0.f; acc2[m][3]=0.f; }
#pragma unroll
  for (int ks = 0; ks < 2; ++ks) {
    int byteoff = rl * 128 + ((ks * 64 + lq * 16) ^ swz);
    bhalf8 b = *reinterpret_cast<const bhalf8*>(reinterpret_cast<char*>(h1t) + byteoff);
#pragma unroll
    for (int m = 0; m < 4; ++m) {
      const int row = m * 16 + cl;
      bhalf8 a = *reinterpret_cast<const bhalf8*>(wffl + row * 128 + ((ks * 64 + lq * 16) ^ ((row & 7) << 4)));
      acc2[m] = __builtin_amdgcn_mfma_f32_16x16x32_bf16(a, b, acc2[m], 0, 0, 0);
    }
  }

#pragma unroll
  for (int m = 0; m < 4; ++m) {
#pragma unroll
    for (int r = 0; r < 4; ++r) {
      int o = m * 16 + lq * 4 + r;
      float h = acc2[m][r] * clds[128 + o] + clds[192 + o] + xres[m][r];
      h = (h >= 0.f) ? h : 0.1f * h;
      int byteoff = rl * 128 + ((o * 2) ^ swz);
      *reinterpret_cast<short*>(reinterpret_cast<char*>(h1t) + byteoff) = (short)f2bf(h);
    }
  }
  __syncthreads();

  {
    int row = tid >> 2, ch = tid & 3;
    int prow = p0 + row;
    if (prow < P_) {
      int sw = (row & 7) << 4;
      uint4 d0 = *reinterpret_cast<uint4*>(reinterpret_cast<char*>(h1t) + row * 128 + (((2 * ch) * 16) ^ sw));
      uint4 d1 = *reinterpret_cast<uint4*>(reinterpret_cast<char*>(h1t) + row * 128 + (((2 * ch + 1) * 16) ^ sw));
      char* dst = reinterpret_cast<char*>(h2Tg) + ((size_t)n * HROWS + HGUARD + prow) * 256 + ch * 32;
      *reinterpret_cast<uint4*>(dst) = d0;
      *reinterpret_cast<uint4*>(dst + 16) = d1;
    }
  }
}

// k4c: LDS-staged temporal conv K=192 MFMA GEMM + bn3/res/lrelu -> out
__global__ __launch_bounds__(256) void k4c(
    const unsigned short* __restrict__ h2Tg,
    const unsigned short* __restrict__ Wtb,
    const float* __restrict__ cst,
    float* __restrict__ out)
{
  const int n = blockIdx.x;
  const int p0 = blockIdx.y * 64;
  const int tid = threadIdx.x;
  const int w = tid >> 6;
  const int l = tid & 63;
  const int cl = l & 15;
  const int lq = l >> 4;
  const int p = p0 + w * 16 + cl;

  __shared__ __align__(16) char hst[16384];     // 128 rows x 128B (64 ch), swizzled
  __shared__ __align__(16) char wst[24576];     // 64 rows x 384B (192 ch), swizzled
  __shared__ float clds[128];
  if (tid < 128) clds[tid] = cst[256 + tid];

  // stage h2 tile + halo: rows [p0-32, p0+96)
  const unsigned short* hbase = h2Tg + ((size_t)n * HROWS + HGUARD + p0 - 32) * 128;
  for (int i = tid; i < 1024; i += 256) {
    int r = i >> 3, ch = i & 7;
    uint4 d = *reinterpret_cast<const uint4*>(hbase + (size_t)r * 128 + ch * 8);
    *reinterpret_cast<uint4*>(hst + r * 128 + ((ch * 16) ^ ((r & 7) << 4))) = d;
  }
  // stage Wt (64 rows x 192 ch)
  for (int i = tid; i < 1536; i += 256) {
    int r = i / 24, ch = i - r * 24;
    uint4 d = *reinterpret_cast<const uint4*>(Wtb + r * 192 + ch * 8);
    *reinterpret_cast<uint4*>(wst + r * 384 + ((ch * 16) ^ ((r & 7) << 4))) = d;
  }
  __syncthreads();

  const int rl = 32 + w * 16 + cl;
  bhalf8 bfr[6];
#pragma unroll
  for (int ks = 0; ks < 6; ++ks) {
    int k0 = ks * 32 + lq * 8;
    int dt = k0 >> 6;
    int i0 = k0 & 63;
    int rr = rl + (dt - 1) * 27;
    bfr[ks] = *reinterpret_cast<const bhalf8*>(hst + rr * 128 + ((2 * i0) ^ ((rr & 7) << 4)));
  }
  fx4 acc[4];
#pragma unroll
  for (int m = 0; m < 4; ++m) { acc[m][0]=0.f; acc[m][1]=0.f; acc[m][2]=0.f; acc[m][3]=0.f; }
#pragma unroll
  for (int m = 0; m < 4; ++m) {
    const int row = m * 16 + cl;
#pragma unroll
    for (int ks = 0; ks < 6; ++ks) {
      bhalf8 a = *reinterpret_cast<const bhalf8*>(wst + row * 384 + ((ks * 64 + lq * 16) ^ ((row & 7) << 4)));
      acc[m] = __builtin_amdgcn_mfma_f32_16x16x32_bf16(a, bfr[ks], acc[m], 0, 0, 0);
    }
  }
  if (p < P_) {
#pragma unroll
    for (int m = 0; m < 4; ++m) {
      uint2 hr = *reinterpret_cast<uint2*>(hst + rl * 128 + (((m * 16 + lq * 4) * 2) ^ ((rl & 7) << 4)));
      float hc0 = bf2f((unsigned short)(hr.x & 0xffff));
      float hc1 = bf2f((unsigned short)(hr.x >> 16));
      float hc2 = bf2f((unsigned short)(hr.y & 0xffff));
      float hc3 = bf2f((unsigned short)(hr.y >> 16));
      float hc[4] = {hc0, hc1, hc2, hc3};
#pragma unroll
      for (int r = 0; r < 4; ++r) {
        int o = m * 16 + lq * 4 + r;
        float val = acc[m][r] * clds[o] + clds[64 + o] + hc[r];
        val = (val >= 0.f) ? val : 0.1f * val;
        out[((size_t)(n * CO_ + o)) * (size_t)P_ + p] = val;
      }
    }
  }
}

// ================= fallback path =================
__global__ __launch_bounds__(256) void k1_qk_partial(
    const float* __restrict__ x, const float* __restrict__ pe,
    const float* __restrict__ w_in, const float* __restrict__ b_in,
    float* __restrict__ partial)
{
  const int n = blockIdx.x;
  const int chunk = blockIdx.y;
  const int tid = threadIdx.x;
  __shared__ float ylds[C_][28];
  __shared__ float qlds[C_][28];
  __shared__ float wlds[C_][65];
  for (int i = tid; i < C_ * C_; i += 256) wlds[i >> 6][i & 63] = w_in[i];
  float acc[6];
#pragma unroll
  for (int j = 0; j < 6; ++j) acc[j] = 0.f;
  const int t0 = chunk * TCHUNK;
  for (int tt = 0; tt < TCHUNK; ++tt) {
    const int t = t0 + tt;
    __syncthreads();
    for (int i = tid; i < C_ * V_; i += 256) {
      int c = i / V_, v = i - c * V_;
      ylds[c][v] = x[((size_t)(n * C_ + c) * T_ + t) * V_ + v] + pe[(c * T_ + t) * V_ + v];
    }
    __syncthreads();
    for (int i = tid; i < C_ * V_; i += 256) {
      int o = i / V_, v = i - o * V_;
      float s = b_in[o];
#pragma unroll
      for (int c = 0; c < C_; ++c) s += wlds[o][c] * ylds[c][v];
      qlds[o][v] = s;
    }
    __syncthreads();
#pragma unroll
    for (int j = 0; j < 6; ++j) {
      int i = tid + j * 256;
      if (i < ATT_N) {
        int s = i / 729, r = i - s * 729, u = r / 27, v = r - u * 27;
        float a = 0.f;
#pragma unroll
        for (int c = 0; c < CI_; ++c)
          a += qlds[s * CI_ + c][u] * qlds[S_ * CI_ + s * CI_ + c][v];
        acc[j] += a;
      }
    }
  }
  float* dst = partial + (size_t)(n * NCHUNK + chunk) * ATT_N;
#pragma unroll
  for (int j = 0; j < 6; ++j) {
    int i = tid + j * 256;
    if (i < ATT_N) dst[i] = acc[j];
  }
}

__global__ __launch_bounds__(256) void k2_att_fin(
    const float* __restrict__ partial, const float* __restrict__ alphas,
    const float* __restrict__ att0, float* __restrict__ att)
{
  int i = blockIdx.x * 256 + threadIdx.x;
  if (i >= N_ * ATT_N) return;
  int n = i / ATT_N, r = i - n * ATT_N;
  int s = r / 729;
  float a = 0.f;
  const float* p = partial + (size_t)n * NCHUNK * ATT_N + r;
  for (int ch = 0; ch < NCHUNK; ++ch) a += p[(size_t)ch * ATT_N];
  a = tanhf(a * (1.0f / (CI_ * (float)T_))) * alphas[s] + att0[r];
  att[i] = a;
}

__global__ __launch_bounds__(256) void k3a(
    const float* __restrict__ x, const float* __restrict__ att,
    const float* __restrict__ w_out, const float* __restrict__ b_out,
    const float* __restrict__ bn1_g, const float* __restrict__ bn1_b,
    const float* __restrict__ bn1_m, const float* __restrict__ bn1_v,
    const float* __restrict__ w_ff, const float* __restrict__ b_ff,
    const float* __restrict__ bn2_g, const float* __restrict__ bn2_b,
    const float* __restrict__ bn2_m, const float* __restrict__ bn2_v,
    float* __restrict__ h2g)
{
  const int n = blockIdx.x;
  const int t0 = blockIdx.y * 2;
  const int tid = threadIdx.x;
  const int v = tid & 31;
  const int tloc = (tid >> 5) & 1;
  const int col = tid & 63;
  const int rg = __builtin_amdgcn_readfirstlane(tid >> 6);
  const int t = t0 + tloc;

  __shared__ float xlds[C_][64];
  __shared__ float zlds[S_ * C_][64];

  for (int i = tid; i < C_ * 64; i += 256) {
    int c = i >> 6, cl = i & 63, tl = cl >> 5, vv = cl & 31;
    xlds[c][cl] = (vv < V_) ? x[((size_t)(n * C_ + c) * T_ + t0 + tl) * V_ + vv] : 0.f;
  }
  float attreg[S_][V_];
  {
    const float* ab = att + (size_t)n * ATT_N + v;
#pragma unroll
    for (int s = 0; s < S_; ++s)
#pragma unroll
      for (int u = 0; u < V_; ++u)
        attreg[s][u] = (v < V_) ? ab[s * 729 + u * 27] : 0.f;
  }
  __syncthreads();
#pragma unroll 1
  for (int cc = 0; cc < 16; ++cc) {
    const int c = rg * 16 + cc;
    float xr[V_];
#pragma unroll
    for (int u = 0; u < V_; ++u) xr[u] = xlds[c][tloc * 32 + u];
    float a0 = 0.f, a1 = 0.f;
#pragma unroll
    for (int u = 0; u < V_; ++u) {
      a0 += xr[u] * attreg[0][u];
      a1 += xr[u] * attreg[1][u];
    }
    zlds[c][col] = a0;
    zlds[C_ + c][col] = a1;
  }
  __syncthreads();
  float acc[16];
#pragma unroll
  for (int oo = 0; oo < 16; ++oo) acc[oo] = 0.f;
#pragma unroll 1
  for (int kc = 0; kc < 4; ++kc) {
    float zk[32];
#pragma unroll
    for (int j = 0; j < 32; ++j) zk[j] = zlds[kc * 32 + j][col];
#pragma unroll
    for (int oo = 0; oo < 16; ++oo) {
      const float* wr = w_out + (rg * 16 + oo) * (S_ * C_) + kc * 32;
      float s = acc[oo];
#pragma unroll
      for (int j = 0; j < 32; ++j) s += wr[j] * zk[j];
      acc[oo] = s;
    }
  }
  float h1v[16];
#pragma unroll
  for (int oo = 0; oo < 16; ++oo) {
    const int o = rg * 16 + oo;
    float y3 = acc[oo] + b_out[o];
    float h = (y3 - bn1_m[o]) * (bn1_g[o] * rsqrtf(bn1_v[o] + 1e-5f)) + bn1_b[o]
              + xlds[o][col];
    h1v[oo] = (h >= 0.f) ? h : 0.1f * h;
  }
  __syncthreads();
#pragma unroll
  for (int oo = 0; oo < 16; ++oo) zlds[rg * 16 + oo][col] = h1v[oo];
  __syncthreads();
#pragma unroll
  for (int oo = 0; oo < 16; ++oo) acc[oo] = 0.f;
#pragma unroll 1
  for (int kc = 0; kc < 2; ++kc) {
    float zk[32];
#pragma unroll
    for (int j = 0; j < 32; ++j) zk[j] = zlds[kc * 32 + j][col];
#pragma unroll
    for (int oo = 0; oo < 16; ++oo) {
      const float* wr = w_ff + (rg * 16 + oo) * C_ + kc * 32;
      float s = acc[oo];
#pragma unroll
      for (int j = 0; j < 32; ++j) s += wr[j] * zk[j];
      acc[oo] = s;
    }
  }
  if (v < V_) {
#pragma unroll
    for (int oo = 0; oo < 16; ++oo) {
      const int o = rg * 16 + oo;
      float f = acc[oo] + b_ff[o];
      float h = (f - bn2_m[o]) * (bn2_g[o] * rsqrtf(bn2_v[o] + 1e-5f)) + bn2_b[o]
                + xlds[o][col];
      h2g[((size_t)(n * CO_ + o) * T_ + t) * V_ + v] = (h >= 0.f) ? h : 0.1f * h;
    }
  }
}

__global__ __launch_bounds__(256) void k3b(
    const float* __restrict__ h2g, const float* __restrict__ w_t,
    const float* __restrict__ b_t,
    const float* __restrict__ bn3_g, const float* __restrict__ bn3_b,
    const float* __restrict__ bn3_m, const float* __restrict__ bn3_v,
    float* __restrict__ out)
{
  const int n = blockIdx.x;
  const int t0 = blockIdx.y * 2;
  const int tid = threadIdx.x;
  const int v = tid & 31;
  const int tloc = (tid >> 5) & 1;
  const int rg = __builtin_amdgcn_readfirstlane(tid >> 6);
  const int t = t0 + tloc;

  __shared__ float hl[C_][4][32];

  for (int idx = tid; idx < C_ * 4 * 32; idx += 256) {
    int i = idx >> 7, r = idx & 127, sl = r >> 5, vv = r & 31;
    int tg = t0 - 1 + sl;
    hl[i][sl][vv] = (vv < V_ && tg >= 0 && tg < T_)
                    ? h2g[((size_t)(n * CO_ + i) * T_ + tg) * V_ + vv] : 0.f;
  }
  __syncthreads();

  float acc[16];
#pragma unroll
  for (int oo = 0; oo < 16; ++oo) acc[oo] = 0.f;
#pragma unroll 1
  for (int ic = 0; ic < 4; ++ic) {
    float h[16][3];
#pragma unroll
    for (int ii = 0; ii < 16; ++ii) {
      h[ii][0] = hl[ic * 16 + ii][tloc][v];
      h[ii][1] = hl[ic * 16 + ii][tloc + 1][v];
      h[ii][2] = hl[ic * 16 + ii][tloc + 2][v];
    }
#pragma unroll
    for (int oo = 0; oo < 16; ++oo) {
      const float* wr = w_t + ((size_t)(rg * 16 + oo) * C_ + ic * 16) * 3;
      float s = acc[oo];
#pragma unroll
      for (int ii = 0; ii < 16; ++ii) {
        s += wr[ii * 3 + 0] * h[ii][0]
           + wr[ii * 3 + 1] * h[ii][1]
           + wr[ii * 3 + 2] * h[ii][2];
      }
      acc[oo] = s;
    }
  }
  if (v < V_) {
#pragma unroll
    for (int oo = 0; oo < 16; ++oo) {
      const int o = rg * 16 + oo;
      float zv = acc[oo] + b_t[o];
      float r = (zv - bn3_m[o]) * (bn3_g[o] * rsqrtf(bn3_v[o] + 1e-5f)) + bn3_b[o]
                + hl[o][tloc + 1][v];
      out[((size_t)(n * CO_ + o) * T_ + t) * V_ + v] = (r >= 0.f) ? r : 0.1f * r;
    }
  }
}

extern "C" void kernel_launch(void* const* d_in, const int* in_sizes, int n_in,
                              void* d_out, int out_size, void* d_ws, size_t ws_size,
                              hipStream_t stream)
{
  (void)in_sizes; (void)n_in; (void)out_size;
  const float* x      = (const float*)d_in[0];
  const float* pe     = (const float*)d_in[1];
  const float* w_in   = (const float*)d_in[2];
  const float* b_in   = (const float*)d_in[3];
  const float* alphas = (const float*)d_in[4];
  const float* att0   = (const float*)d_in[5];
  const float* w_out  = (const float*)d_in[6];
  const float* b_out  = (const float*)d_in[7];
  const float* bn1_g  = (const float*)d_in[8];
  const float* bn1_b  = (const float*)d_in[9];
  const float* bn1_m  = (const float*)d_in[10];
  const float* bn1_v  = (const float*)d_in[11];
  const float* w_ff   = (const float*)d_in[12];
  const float* b_ff   = (const float*)d_in[13];
  const float* bn2_g  = (const float*)d_in[14];
  const float* bn2_b  = (const float*)d_in[15];
  const float* bn2_m  = (const float*)d_in[16];
  const float* bn2_v  = (const float*)d_in[17];
  const float* w_t    = (const float*)d_in[18];
  const float* b_t    = (const float*)d_in[19];
  const float* bn3_g  = (const float*)d_in[20];
  const float* bn3_b  = (const float*)d_in[21];
  const float* bn3_m  = (const float*)d_in[22];
  const float* bn3_v  = (const float*)d_in[23];
  float* out = (float*)d_out;

  char* ws = (char*)d_ws;
  unsigned short* Wb   = (unsigned short*)(ws);              // 57,344 B
  float*          cst  = (float*)(ws + 57344);               // 1,792 B
  unsigned short* attT = (unsigned short*)(ws + 59136);      // 131,072 B
  unsigned short* yT   = (unsigned short*)(ws + 190208);     // 44,302,336 B
  unsigned short* qkT  = (unsigned short*)(ws + 44492544);   // 52,428,800 B
  unsigned short* h2T  = (unsigned short*)(ws + 96921344);   // 89,260,032 B
  unsigned short* ZT   = (unsigned short*)(ws + 190208);     // 88,604,672 B (alias)
  const size_t need_mfma = 186181376;
  const size_t need_old  = ((size_t)N_ * NCHUNK * ATT_N + (size_t)N_ * ATT_N
                            + (size_t)N_ * CO_ * T_ * V_) * sizeof(float);

  if (ws_size >= need_mfma) {
    kprep<<<64, 256, 0, stream>>>(w_out, w_ff, w_t, w_in, b_out, b_ff, b_t, b_in,
        bn1_g, bn1_b, bn1_m, bn1_v, bn2_g, bn2_b, bn2_m, bn2_v,
        bn3_g, bn3_b, bn3_m, bn3_v, Wb, cst, h2T);
    ky<<<dim3(N_, PTILES), 256, 0, stream>>>(x, pe, yT);
    k1a<<<dim3(N_, PTILES), 256, 0, stream>>>(yT, Wb, cst, qkT);
    k1b<<<64, 256, 0, stream>>>(qkT, alphas, att0, attT);
    kz_mfma<<<dim3(N_, 25), 256, 0, stream>>>(x, attT, ZT);
    k4b<<<dim3(N_, PTILES), 256, 0, stream>>>(x, ZT, Wb, cst, h2T);
    k4c<<<dim3(N_, PTILES), 256, 0, stream>>>(h2T, Wb + 12288, cst, out);
  } else if (ws_size >= need_old) {
    float* partial = (float*)ws;
    float* att     = partial + (size_t)N_ * NCHUNK * ATT_N;
    float* h2g     = att + (size_t)N_ * ATT_N;
    k1_qk_partial<<<dim3(N_, NCHUNK), 256, 0, stream>>>(x, pe, w_in, b_in, partial);
    k2_att_fin<<<(N_ * ATT_N + 255) / 256, 256, 0, stream>>>(partial, alphas, att0, att);
    k3a<<<dim3(N_, T_ / 2), 256, 0, stream>>>(x, att,
        w_out, b_out, bn1_g, bn1_b, bn1_m, bn1_v,
        w_ff, b_ff, bn2_g, bn2_b, bn2_m, bn2_v, h2g);
    k3b<<<dim3(N_, T_ / 2), 256, 0, stream>>>(h2g, w_t, b_t,
        bn3_g, bn3_b, bn3_m, bn3_v, out);
  }
}

// Round 6
// 197.041 us; speedup vs baseline: 6.9074x; 1.3647x over previous
//
#include <hip/hip_runtime.h>

#define N_ 32
#define C_ 64
#define T_ 400
#define V_ 27
#define S_ 2
#define CI_ 16
#define CO_ 64
#define TCHUNK 8
#define NCHUNK 50
#define ATT_N 1458           // S_*V_*V_
#define P_ 10800             // T_*V_
#define PT_ 10816            // 169*64
#define PTILES 169
#define HGUARD 32
#define HROWS 10896          // HGUARD + P_ + 64

typedef short bhalf8 __attribute__((ext_vector_type(8)));
typedef float fx4 __attribute__((ext_vector_type(4)));

static __device__ inline unsigned short f2bf(float f) {
  unsigned u = __builtin_bit_cast(unsigned, f);
  u += 0x7fffu + ((u >> 16) & 1u);
  return (unsigned short)(u >> 16);
}
static __device__ inline float bf2f(unsigned short h) {
  unsigned u = ((unsigned)h) << 16;
  return __builtin_bit_cast(float, u);
}

// ================= MFMA path =================

// kprep: bf16 weights (Wout|Wff|Wt|Wi), fused bn consts + b_in, zero h2T guards
__global__ __launch_bounds__(256) void kprep(
    const float* __restrict__ w_out, const float* __restrict__ w_ff,
    const float* __restrict__ w_t, const float* __restrict__ w_in,
    const float* __restrict__ b_out, const float* __restrict__ b_ff,
    const float* __restrict__ b_t, const float* __restrict__ b_in,
    const float* __restrict__ bn1_g, const float* __restrict__ bn1_b,
    const float* __restrict__ bn1_m, const float* __restrict__ bn1_v,
    const float* __restrict__ bn2_g, const float* __restrict__ bn2_b,
    const float* __restrict__ bn2_m, const float* __restrict__ bn2_v,
    const float* __restrict__ bn3_g, const float* __restrict__ bn3_b,
    const float* __restrict__ bn3_m, const float* __restrict__ bn3_v,
    unsigned short* __restrict__ Wb, float* __restrict__ cst,
    unsigned short* __restrict__ h2Tg)
{
  const int tid = threadIdx.x;
  const int bid = blockIdx.x;
  uint4 z; z.x = 0; z.y = 0; z.z = 0; z.w = 0;
  // guard rows: head 32 rows (256 uint4/n), tail 64 rows (512 uint4/n); 64-short rows
  for (int i = bid * 256 + tid; i < N_ * 768; i += 64 * 256) {
    int n = i / 768, r = i - n * 768;
    size_t off = (r < 256) ? (size_t)r * 8 : (size_t)10832 * 64 + (size_t)(r - 256) * 8;
    *reinterpret_cast<uint4*>(h2Tg + (size_t)n * HROWS * 64 + off) = z;
  }
  if (bid != 0) return;
  for (int i = tid; i < 8192; i += 256) Wb[i] = f2bf(w_out[i]);
  for (int i = tid; i < 4096; i += 256) Wb[8192 + i] = f2bf(w_ff[i]);
  for (int i = tid; i < 12288; i += 256) {
    int o = i / 192, r = i - o * 192, dt = r >> 6, ic = r & 63;
    Wb[12288 + i] = f2bf(w_t[(size_t)(o * 64 + ic) * 3 + dt]);
  }
  for (int i = tid; i < 4096; i += 256) Wb[24576 + i] = f2bf(w_in[i]);
  if (tid < 64) {
    int o = tid;
    float a1 = bn1_g[o] * rsqrtf(bn1_v[o] + 1e-5f);
    cst[o] = a1;
    cst[64 + o] = (b_out[o] - bn1_m[o]) * a1 + bn1_b[o];
    float a2 = bn2_g[o] * rsqrtf(bn2_v[o] + 1e-5f);
    cst[128 + o] = a2;
    cst[192 + o] = (b_ff[o] - bn2_m[o]) * a2 + bn2_b[o];
    float a3 = bn3_g[o] * rsqrtf(bn3_v[o] + 1e-5f);
    cst[256 + o] = a3;
    cst[320 + o] = (b_t[o] - bn3_m[o]) * a3 + bn3_b[o];
    cst[384 + o] = b_in[o];
  }
}

// k1a2: fused (x+pe) stage + qk = Wi . y  -> qkT[n][m][u32][t*16+ci] bf16
__global__ __launch_bounds__(256) void k1a2(
    const float* __restrict__ x, const float* __restrict__ pe,
    const unsigned short* __restrict__ Wb,
    const float* __restrict__ cst,
    unsigned short* __restrict__ qkT)
{
  const int n = blockIdx.x;
  const int p0 = blockIdx.y * 64;
  const int tid = threadIdx.x;
  const int w = tid >> 6;
  const int l = tid & 63;
  const int cl = l & 15;
  const int lq = l >> 4;
  const int p = p0 + w * 16 + cl;
  const int rl = w * 16 + cl;

  __shared__ float xl[64][65];
  __shared__ float clds[64];
  if (tid < 64) clds[tid] = cst[384 + tid];

  {
    int c = tid >> 2, ch = tid & 3;
    const float* xr = x + (size_t)(n * C_ + c) * P_;
    const float* pr = pe + (size_t)c * P_;
    if (p0 + 64 <= P_) {
#pragma unroll
      for (int q = 0; q < 4; ++q) {
        int pp = p0 + ch * 16 + q * 4;
        float4 a = *reinterpret_cast<const float4*>(xr + pp);
        float4 b = *reinterpret_cast<const float4*>(pr + pp);
        xl[c][ch * 16 + q * 4 + 0] = a.x + b.x;
        xl[c][ch * 16 + q * 4 + 1] = a.y + b.y;
        xl[c][ch * 16 + q * 4 + 2] = a.z + b.z;
        xl[c][ch * 16 + q * 4 + 3] = a.w + b.w;
      }
    } else {
#pragma unroll
      for (int j = 0; j < 16; ++j) {
        int pp = p0 + ch * 16 + j;
        xl[c][ch * 16 + j] = (pp < P_) ? (xr[pp] + pr[pp]) : 0.f;
      }
    }
  }
  __syncthreads();

  // B-frags: col=p(local rl), k=c
  bhalf8 bfr[2];
#pragma unroll
  for (int ks = 0; ks < 2; ++ks)
#pragma unroll
    for (int j = 0; j < 8; ++j)
      bfr[ks][j] = (short)f2bf(xl[ks * 32 + lq * 8 + j][rl]);

  const unsigned short* Wi = Wb + 24576;
  fx4 acc[4];
#pragma unroll
  for (int m = 0; m < 4; ++m) { acc[m][0]=0.f; acc[m][1]=0.f; acc[m][2]=0.f; acc[m][3]=0.f; }
#pragma unroll
  for (int m = 0; m < 4; ++m) {
#pragma unroll
    for (int ks = 0; ks < 2; ++ks) {
      bhalf8 a = *reinterpret_cast<const bhalf8*>(Wi + (m * 16 + cl) * 64 + ks * 32 + lq * 8);
      acc[m] = __builtin_amdgcn_mfma_f32_16x16x32_bf16(a, bfr[ks], acc[m], 0, 0, 0);
    }
  }
  if (p < P_) {
    int t = p / 27, u = p - t * 27;
#pragma unroll
    for (int m = 0; m < 4; ++m) {
      unsigned short o0 = f2bf(acc[m][0] + clds[m * 16 + lq * 4 + 0]);
      unsigned short o1 = f2bf(acc[m][1] + clds[m * 16 + lq * 4 + 1]);
      unsigned short o2 = f2bf(acc[m][2] + clds[m * 16 + lq * 4 + 2]);
      unsigned short o3 = f2bf(acc[m][3] + clds[m * 16 + lq * 4 + 3]);
      uint2 d;
      d.x = (unsigned)o0 | ((unsigned)o1 << 16);
      d.y = (unsigned)o2 | ((unsigned)o3 << 16);
      *reinterpret_cast<uint2*>(qkT + (((size_t)(n * 4 + m) * 32 + u) * 6400 + t * 16 + lq * 4)) = d;
    }
  }
}

// k1b: att GEMM over K=6400, finalize tanh*alpha+att0 -> attT[n][s][v32][u32] bf16 (zero-padded)
__global__ __launch_bounds__(256) void k1b(
    const unsigned short* __restrict__ qkT,
    const float* __restrict__ alphas, const float* __restrict__ att0,
    unsigned short* __restrict__ attT)
{
  const int n = blockIdx.x >> 1;
  const int s = blockIdx.x & 1;
  const int tid = threadIdx.x;
  const int w = tid >> 6;
  const int l = tid & 63;
  const int cl = l & 15;
  const int lq = l >> 4;

  const unsigned short* qb = qkT + (size_t)(n * 4 + s) * 32 * 6400;
  const unsigned short* kb = qkT + (size_t)(n * 4 + 2 + s) * 32 * 6400;

  fx4 acc[2][2];
#pragma unroll
  for (int a1 = 0; a1 < 2; ++a1)
#pragma unroll
    for (int a2 = 0; a2 < 2; ++a2) { acc[a1][a2][0]=0.f; acc[a1][a2][1]=0.f; acc[a1][a2][2]=0.f; acc[a1][a2][3]=0.f; }

#pragma unroll 2
  for (int step = 0; step < 50; ++step) {
    int k0 = w * 1600 + step * 32 + lq * 8;
    bhalf8 aq0 = *reinterpret_cast<const bhalf8*>(qb + (size_t)cl * 6400 + k0);
    bhalf8 aq1 = *reinterpret_cast<const bhalf8*>(qb + (size_t)(16 + cl) * 6400 + k0);
    bhalf8 bk0 = *reinterpret_cast<const bhalf8*>(kb + (size_t)cl * 6400 + k0);
    bhalf8 bk1 = *reinterpret_cast<const bhalf8*>(kb + (size_t)(16 + cl) * 6400 + k0);
    acc[0][0] = __builtin_amdgcn_mfma_f32_16x16x32_bf16(aq0, bk0, acc[0][0], 0, 0, 0);
    acc[0][1] = __builtin_amdgcn_mfma_f32_16x16x32_bf16(aq0, bk1, acc[0][1], 0, 0, 0);
    acc[1][0] = __builtin_amdgcn_mfma_f32_16x16x32_bf16(aq1, bk0, acc[1][0], 0, 0, 0);
    acc[1][1] = __builtin_amdgcn_mfma_f32_16x16x32_bf16(aq1, bk1, acc[1][1], 0, 0, 0);
  }

  __shared__ float red[4][4][4][64];
#pragma unroll
  for (int mt = 0; mt < 2; ++mt)
#pragma unroll
    for (int nt = 0; nt < 2; ++nt)
#pragma unroll
      for (int r = 0; r < 4; ++r)
        red[w][mt * 2 + nt][r][l] = acc[mt][nt][r];
  __syncthreads();

  const int mn = w, mt = w >> 1, nt = w & 1;
  const int v = nt * 16 + cl;
  const float alpha = alphas[s];
  unsigned short outs[4];
#pragma unroll
  for (int r = 0; r < 4; ++r) {
    float sum = red[0][mn][r][l] + red[1][mn][r][l] + red[2][mn][r][l] + red[3][mn][r][l];
    int u = mt * 16 + lq * 4 + r;
    float val = 0.f;
    if (u < V_ && v < V_)
      val = tanhf(sum * (1.0f / 6400.0f)) * alpha + att0[(s * V_ + u) * V_ + v];
    outs[r] = f2bf(val);
  }
  uint2 d;
  d.x = (unsigned)outs[0] | ((unsigned)outs[1] << 16);
  d.y = (unsigned)outs[2] | ((unsigned)outs[3] << 16);
  *reinterpret_cast<uint2*>(attT + (((size_t)(n * 2 + s) * 32 + v) * 32 + mt * 16 + lq * 4)) = d;
}

// kz4b: FUSED x.att (MFMA, Z in LDS) -> Wout -> bn1/res/lrelu -> Wff -> bn2/res/lrelu -> h2T
// block = (n, t-pair); 54 valid p-rows per block.
__global__ __launch_bounds__(256) void kz4b(
    const float* __restrict__ x,
    const unsigned short* __restrict__ attT,
    const unsigned short* __restrict__ Wb,
    const float* __restrict__ cst,
    unsigned short* __restrict__ h2Tg)
{
  const int n = blockIdx.x;
  const int t0 = blockIdx.y * 2;
  const int pbase = t0 * 27;
  const int tid = threadIdx.x;
  const int w = tid >> 6;
  const int l = tid & 63;
  const int cl = l & 15;
  const int lq = l >> 4;

  __shared__ __align__(16) char zstg[16384];    // 64 rows x 256B (128 ch), swizzled
  __shared__ __align__(16) char wout[16384];
  __shared__ __align__(16) char wffl[8192];
  __shared__ short h1t[64 * 64];
  __shared__ float clds[256];
  for (int i = tid; i < 256; i += 256) clds[i] = cst[i];

  // stage weights
  for (int i = tid; i < 1024; i += 256) {
    int r = i >> 4, ch = i & 15;
    uint4 d = *reinterpret_cast<const uint4*>(Wb + r * 128 + ch * 8);
    *reinterpret_cast<uint4*>(wout + r * 256 + ((ch * 16) ^ ((r & 7) << 4))) = d;
  }
  for (int i = tid; i < 512; i += 256) {
    int r = i >> 3, ch = i & 7;
    uint4 d = *reinterpret_cast<const uint4*>(Wb + 8192 + r * 64 + ch * 8);
    *reinterpret_cast<uint4*>(wffl + r * 128 + ((ch * 16) ^ ((r & 7) << 4))) = d;
  }
  // zero pad rows 54..63 of zstg
  {
    uint4 z; z.x = 0; z.y = 0; z.z = 0; z.w = 0;
    for (int i = tid; i < 160; i += 256)
      *reinterpret_cast<uint4*>(zstg + 54 * 256 + i * 16) = z;
  }

  // ---- Z phase: wave w -> t = t0 + (w>>1), s = w&1; 8 MFMAs/wave ----
  {
    const int th = w >> 1;
    const int s = w & 1;
    const int t = t0 + th;
    bhalf8 batt[2];
#pragma unroll
    for (int vt = 0; vt < 2; ++vt)
      batt[vt] = *reinterpret_cast<const bhalf8*>(
          attT + ((size_t)(n * 2 + s) * 32 + vt * 16 + cl) * 32 + lq * 8);
    bhalf8 ax[4];
    if (t * 27 + 31 < P_) {
#pragma unroll
      for (int m = 0; m < 4; ++m) {
        const float* base = x + (size_t)(n * C_ + m * 16 + cl) * P_ + t * 27 + lq * 8;
        float4 f0 = *reinterpret_cast<const float4*>(base);
        float4 f1 = *reinterpret_cast<const float4*>(base + 4);
        ax[m][0] = (short)f2bf(f0.x); ax[m][1] = (short)f2bf(f0.y);
        ax[m][2] = (short)f2bf(f0.z); ax[m][3] = (short)f2bf(f0.w);
        ax[m][4] = (short)f2bf(f1.x); ax[m][5] = (short)f2bf(f1.y);
        ax[m][6] = (short)f2bf(f1.z); ax[m][7] = (short)f2bf(f1.w);
      }
    } else {
#pragma unroll
      for (int m = 0; m < 4; ++m) {
        const float* xr = x + (size_t)(n * C_ + m * 16 + cl) * P_;
#pragma unroll
        for (int j = 0; j < 8; ++j) {
          int idx = t * 27 + lq * 8 + j;
          idx = (idx < P_) ? idx : (P_ - 1);
          ax[m][j] = (short)f2bf(xr[idx]);
        }
      }
    }
#pragma unroll
    for (int vt = 0; vt < 2; ++vt) {
      const int v = vt * 16 + cl;
#pragma unroll
      for (int m = 0; m < 4; ++m) {
        fx4 z; z[0] = 0.f; z[1] = 0.f; z[2] = 0.f; z[3] = 0.f;
        fx4 dacc = __builtin_amdgcn_mfma_f32_16x16x32_bf16(ax[m], batt[vt], z, 0, 0, 0);
        if (v < V_) {
          unsigned short o0 = f2bf(dacc[0]);
          unsigned short o1 = f2bf(dacc[1]);
          unsigned short o2 = f2bf(dacc[2]);
          unsigned short o3 = f2bf(dacc[3]);
          uint2 d;
          d.x = (unsigned)o0 | ((unsigned)o1 << 16);
          d.y = (unsigned)o2 | ((unsigned)o3 << 16);
          int row = th * 27 + v;
          int byteoff = row * 256 + (((s * 64 + m * 16 + lq * 4) * 2) ^ ((row & 7) << 4));
          *reinterpret_cast<uint2*>(zstg + byteoff) = d;
        }
      }
    }
  }
  __syncthreads();

  // ---- phase3: y3 = Wout(64x128) . Z ----
  const int rl = w * 16 + cl;
  const int pidx = pbase + ((rl < 54) ? rl : 53);
  const int swz = (cl & 7) << 4;
  bhalf8 bfr[4];
#pragma unroll
  for (int ks = 0; ks < 4; ++ks)
    bfr[ks] = *reinterpret_cast<const bhalf8*>(zstg + rl * 256 + ((ks * 64 + lq * 16) ^ ((rl & 7) << 4)));
  fx4 acc[4];
#pragma unroll
  for (int m = 0; m < 4; ++m) { acc[m][0]=0.f; acc[m][1]=0.f; acc[m][2]=0.f; acc[m][3]=0.f; }
#pragma unroll
  for (int m = 0; m < 4; ++m) {
    const int row = m * 16 + cl;
#pragma unroll
    for (int ks = 0; ks < 4; ++ks) {
      bhalf8 a = *reinterpret_cast<const bhalf8*>(wout + row * 256 + ((ks * 64 + lq * 16) ^ ((row & 7) << 4)));
      acc[m] = __builtin_amdgcn_mfma_f32_16x16x32_bf16(a, bfr[ks], acc[m], 0, 0, 0);
    }
  }

  float xres[4][4];
#pragma unroll
  for (int m = 0; m < 4; ++m) {
#pragma unroll
    for (int r = 0; r < 4; ++r) {
      int o = m * 16 + lq * 4 + r;
      float xv = x[((size_t)(n * C_ + o)) * (size_t)P_ + pidx];
      xres[m][r] = xv;
      float h = acc[m][r] * clds[o] + clds[64 + o] + xv;
      h = (h >= 0.f) ? h : 0.1f * h;
      int byteoff = rl * 128 + ((o * 2) ^ swz);
      *reinterpret_cast<short*>(reinterpret_cast<char*>(h1t) + byteoff) = (short)f2bf(h);
    }
  }

  // ---- phase4: f = Wff(64x64) . H1 (wave-local rows) ----
  fx4 acc2[4];
#pragma unroll
  for (int m = 0; m < 4; ++m) { acc2[m][0]=0.f; acc2[m][1]=0.f; acc2[m][2]=0.f; acc2[m][3]=0.f; }
#pragma unroll
  for (int ks = 0; ks < 2; ++ks) {
    int byteoff = rl * 128 + ((ks * 64 + lq * 16) ^ swz);
    bhalf8 b = *reinterpret_cast<const bhalf8*>(reinterpret_cast<char*>(h1t) + byteoff);
#pragma unroll
    for (int m = 0; m < 4; ++m) {
      const int row = m * 16 + cl;
      bhalf8 a = *reinterpret_cast<const bhalf8*>(wffl + row * 128 + ((ks * 64 + lq * 16) ^ ((row & 7) << 4)));
      acc2[m] = __builtin_amdgcn_mfma_f32_16x16x32_bf16(a, b, acc2[m], 0, 0, 0);
    }
  }

#pragma unroll
  for (int m = 0; m < 4; ++m) {
#pragma unroll
    for (int r = 0; r < 4; ++r) {
      int o = m * 16 + lq * 4 + r;
      float h = acc2[m][r] * clds[128 + o] + clds[192 + o] + xres[m][r];
      h = (h >= 0.f) ? h : 0.1f * h;
      int byteoff = rl * 128 + ((o * 2) ^ swz);
      *reinterpret_cast<short*>(reinterpret_cast<char*>(h1t) + byteoff) = (short)f2bf(h);
    }
  }
  __syncthreads();

  // coalesced unswizzle + store 54 rows (64 ch, 128B each)
  {
    int row = tid >> 2, ch = tid & 3;
    if (row < 54) {
      int sw = (row & 7) << 4;
      uint4 d0 = *reinterpret_cast<uint4*>(reinterpret_cast<char*>(h1t) + row * 128 + (((2 * ch) * 16) ^ sw));
      uint4 d1 = *reinterpret_cast<uint4*>(reinterpret_cast<char*>(h1t) + row * 128 + (((2 * ch + 1) * 16) ^ sw));
      char* dst = reinterpret_cast<char*>(h2Tg) + ((size_t)n * HROWS + HGUARD + pbase + row) * 128 + ch * 32;
      *reinterpret_cast<uint4*>(dst) = d0;
      *reinterpret_cast<uint4*>(dst + 16) = d1;
    }
  }
}

// k4c: LDS-staged temporal conv K=192 MFMA GEMM + bn3/res/lrelu -> out
__global__ __launch_bounds__(256) void k4c(
    const unsigned short* __restrict__ h2Tg,
    const unsigned short* __restrict__ Wtb,
    const float* __restrict__ cst,
    float* __restrict__ out)
{
  const int n = blockIdx.x;
  const int p0 = blockIdx.y * 64;
  const int tid = threadIdx.x;
  const int w = tid >> 6;
  const int l = tid & 63;
  const int cl = l & 15;
  const int lq = l >> 4;
  const int p = p0 + w * 16 + cl;

  __shared__ __align__(16) char hst[16384];     // 128 rows x 128B (64 ch), swizzled
  __shared__ __align__(16) char wst[24576];     // 64 rows x 384B (192 ch), swizzled
  __shared__ float clds[128];
  if (tid < 128) clds[tid] = cst[256 + tid];

  const unsigned short* hbase = h2Tg + ((size_t)n * HROWS + HGUARD + p0 - 32) * 64;
  for (int i = tid; i < 1024; i += 256) {
    int r = i >> 3, ch = i & 7;
    uint4 d = *reinterpret_cast<const uint4*>(hbase + (size_t)r * 64 + ch * 8);
    *reinterpret_cast<uint4*>(hst + r * 128 + ((ch * 16) ^ ((r & 7) << 4))) = d;
  }
  for (int i = tid; i < 1536; i += 256) {
    int r = i / 24, ch = i - r * 24;
    uint4 d = *reinterpret_cast<const uint4*>(Wtb + r * 192 + ch * 8);
    *reinterpret_cast<uint4*>(wst + r * 384 + ((ch * 16) ^ ((r & 7) << 4))) = d;
  }
  __syncthreads();

  const int rl = 32 + w * 16 + cl;
  bhalf8 bfr[6];
#pragma unroll
  for (int ks = 0; ks < 6; ++ks) {
    int k0 = ks * 32 + lq * 8;
    int dt = k0 >> 6;
    int i0 = k0 & 63;
    int rr = rl + (dt - 1) * 27;
    bfr[ks] = *reinterpret_cast<const bhalf8*>(hst + rr * 128 + ((2 * i0) ^ ((rr & 7) << 4)));
  }
  fx4 acc[4];
#pragma unroll
  for (int m = 0; m < 4; ++m) { acc[m][0]=0.f; acc[m][1]=0.f; acc[m][2]=0.f; acc[m][3]=0.f; }
#pragma unroll
  for (int m = 0; m < 4; ++m) {
    const int row = m * 16 + cl;
#pragma unroll
    for (int ks = 0; ks < 6; ++ks) {
      bhalf8 a = *reinterpret_cast<const bhalf8*>(wst + row * 384 + ((ks * 64 + lq * 16) ^ ((row & 7) << 4)));
      acc[m] = __builtin_amdgcn_mfma_f32_16x16x32_bf16(a, bfr[ks], acc[m], 0, 0, 0);
    }
  }
  if (p < P_) {
#pragma unroll
    for (int m = 0; m < 4; ++m) {
      uint2 hr = *reinterpret_cast<uint2*>(hst + rl * 128 + (((m * 16 + lq * 4) * 2) ^ ((rl & 7) << 4)));
      float hc[4];
      hc[0] = bf2f((unsigned short)(hr.x & 0xffff));
      hc[1] = bf2f((unsigned short)(hr.x >> 16));
      hc[2] = bf2f((unsigned short)(hr.y & 0xffff));
      hc[3] = bf2f((unsigned short)(hr.y >> 16));
#pragma unroll
      for (int r = 0; r < 4; ++r) {
        int o = m * 16 + lq * 4 + r;
        float val = acc[m][r] * clds[o] + clds[64 + o] + hc[r];
        val = (val >= 0.f) ? val : 0.1f * val;
        out[((size_t)(n * CO_ + o)) * (size_t)P_ + p] = val;
      }
    }
  }
}

// ================= fallback path =================
__global__ __launch_bounds__(256) void k1_qk_partial(
    const float* __restrict__ x, const float* __restrict__ pe,
    const float* __restrict__ w_in, const float* __restrict__ b_in,
    float* __restrict__ partial)
{
  const int n = blockIdx.x;
  const int chunk = blockIdx.y;
  const int tid = threadIdx.x;
  __shared__ float ylds[C_][28];
  __shared__ float qlds[C_][28];
  __shared__ float wlds[C_][65];
  for (int i = tid; i < C_ * C_; i += 256) wlds[i >> 6][i & 63] = w_in[i];
  float acc[6];
#pragma unroll
  for (int j = 0; j < 6; ++j) acc[j] = 0.f;
  const int t0 = chunk * TCHUNK;
  for (int tt = 0; tt < TCHUNK; ++tt) {
    const int t = t0 + tt;
    __syncthreads();
    for (int i = tid; i < C_ * V_; i += 256) {
      int c = i / V_, v = i - c * V_;
      ylds[c][v] = x[((size_t)(n * C_ + c) * T_ + t) * V_ + v] + pe[(c * T_ + t) * V_ + v];
    }
    __syncthreads();
    for (int i = tid; i < C_ * V_; i += 256) {
      int o = i / V_, v = i - o * V_;
      float s = b_in[o];
#pragma unroll
      for (int c = 0; c < C_; ++c) s += wlds[o][c] * ylds[c][v];
      qlds[o][v] = s;
    }
    __syncthreads();
#pragma unroll
    for (int j = 0; j < 6; ++j) {
      int i = tid + j * 256;
      if (i < ATT_N) {
        int s = i / 729, r = i - s * 729, u = r / 27, v = r - u * 27;
        float a = 0.f;
#pragma unroll
        for (int c = 0; c < CI_; ++c)
          a += qlds[s * CI_ + c][u] * qlds[S_ * CI_ + s * CI_ + c][v];
        acc[j] += a;
      }
    }
  }
  float* dst = partial + (size_t)(n * NCHUNK + chunk) * ATT_N;
#pragma unroll
  for (int j = 0; j < 6; ++j) {
    int i = tid + j * 256;
    if (i < ATT_N) dst[i] = acc[j];
  }
}

__global__ __launch_bounds__(256) void k2_att_fin(
    const float* __restrict__ partial, const float* __restrict__ alphas,
    const float* __restrict__ att0, float* __restrict__ att)
{
  int i = blockIdx.x * 256 + threadIdx.x;
  if (i >= N_ * ATT_N) return;
  int n = i / ATT_N, r = i - n * ATT_N;
  int s = r / 729;
  float a = 0.f;
  const float* p = partial + (size_t)n * NCHUNK * ATT_N + r;
  for (int ch = 0; ch < NCHUNK; ++ch) a += p[(size_t)ch * ATT_N];
  a = tanhf(a * (1.0f / (CI_ * (float)T_))) * alphas[s] + att0[r];
  att[i] = a;
}

__global__ __launch_bounds__(256) void k3a(
    const float* __restrict__ x, const float* __restrict__ att,
    const float* __restrict__ w_out, const float* __restrict__ b_out,
    const float* __restrict__ bn1_g, const float* __restrict__ bn1_b,
    const float* __restrict__ bn1_m, const float* __restrict__ bn1_v,
    const float* __restrict__ w_ff, const float* __restrict__ b_ff,
    const float* __restrict__ bn2_g, const float* __restrict__ bn2_b,
    const float* __restrict__ bn2_m, const float* __restrict__ bn2_v,
    float* __restrict__ h2g)
{
  const int n = blockIdx.x;
  const int t0 = blockIdx.y * 2;
  const int tid = threadIdx.x;
  const int v = tid & 31;
  const int tloc = (tid >> 5) & 1;
  const int col = tid & 63;
  const int rg = __builtin_amdgcn_readfirstlane(tid >> 6);
  const int t = t0 + tloc;

  __shared__ float xlds[C_][64];
  __shared__ float zlds[S_ * C_][64];

  for (int i = tid; i < C_ * 64; i += 256) {
    int c = i >> 6, cl = i & 63, tl = cl >> 5, vv = cl & 31;
    xlds[c][cl] = (vv < V_) ? x[((size_t)(n * C_ + c) * T_ + t0 + tl) * V_ + vv] : 0.f;
  }
  float attreg[S_][V_];
  {
    const float* ab = att + (size_t)n * ATT_N + v;
#pragma unroll
    for (int s = 0; s < S_; ++s)
#pragma unroll
      for (int u = 0; u < V_; ++u)
        attreg[s][u] = (v < V_) ? ab[s * 729 + u * 27] : 0.f;
  }
  __syncthreads();
#pragma unroll 1
  for (int cc = 0; cc < 16; ++cc) {
    const int c = rg * 16 + cc;
    float xr[V_];
#pragma unroll
    for (int u = 0; u < V_; ++u) xr[u] = xlds[c][tloc * 32 + u];
    float a0 = 0.f, a1 = 0.f;
#pragma unroll
    for (int u = 0; u < V_; ++u) {
      a0 += xr[u] * attreg[0][u];
      a1 += xr[u] * attreg[1][u];
    }
    zlds[c][col] = a0;
    zlds[C_ + c][col] = a1;
  }
  __syncthreads();
  float acc[16];
#pragma unroll
  for (int oo = 0; oo < 16; ++oo) acc[oo] = 0.f;
#pragma unroll 1
  for (int kc = 0; kc < 4; ++kc) {
    float zk[32];
#pragma unroll
    for (int j = 0; j < 32; ++j) zk[j] = zlds[kc * 32 + j][col];
#pragma unroll
    for (int oo = 0; oo < 16; ++oo) {
      const float* wr = w_out + (rg * 16 + oo) * (S_ * C_) + kc * 32;
      float s = acc[oo];
#pragma unroll
      for (int j = 0; j < 32; ++j) s += wr[j] * zk[j];
      acc[oo] = s;
    }
  }
  float h1v[16];
#pragma unroll
  for (int oo = 0; oo < 16; ++oo) {
    const int o = rg * 16 + oo;
    float y3 = acc[oo] + b_out[o];
    float h = (y3 - bn1_m[o]) * (bn1_g[o] * rsqrtf(bn1_v[o] + 1e-5f)) + bn1_b[o]
              + xlds[o][col];
    h1v[oo] = (h >= 0.f) ? h : 0.1f * h;
  }
  __syncthreads();
#pragma unroll
  for (int oo = 0; oo < 16; ++oo) zlds[rg * 16 + oo][col] = h1v[oo];
  __syncthreads();
#pragma unroll
  for (int oo = 0; oo < 16; ++oo) acc[oo] = 0.f;
#pragma unroll 1
  for (int kc = 0; kc < 2; ++kc) {
    float zk[32];
#pragma unroll
    for (int j = 0; j < 32; ++j) zk[j] = zlds[kc * 32 + j][col];
#pragma unroll
    for (int oo = 0; oo < 16; ++oo) {
      const float* wr = w_ff + (rg * 16 + oo) * C_ + kc * 32;
      float s = acc[oo];
#pragma unroll
      for (int j = 0; j < 32; ++j) s += wr[j] * zk[j];
      acc[oo] = s;
    }
  }
  if (v < V_) {
#pragma unroll
    for (int oo = 0; oo < 16; ++oo) {
      const int o = rg * 16 + oo;
      float f = acc[oo] + b_ff[o];
      float h = (f - bn2_m[o]) * (bn2_g[o] * rsqrtf(bn2_v[o] + 1e-5f)) + bn2_b[o]
                + xlds[o][col];
      h2g[((size_t)(n * CO_ + o) * T_ + t) * V_ + v] = (h >= 0.f) ? h : 0.1f * h;
    }
  }
}

__global__ __launch_bounds__(256) void k3b(
    const float* __restrict__ h2g, const float* __restrict__ w_t,
    const float* __restrict__ b_t,
    const float* __restrict__ bn3_g, const float* __restrict__ bn3_b,
    const float* __restrict__ bn3_m, const float* __restrict__ bn3_v,
    float* __restrict__ out)
{
  const int n = blockIdx.x;
  const int t0 = blockIdx.y * 2;
  const int tid = threadIdx.x;
  const int v = tid & 31;
  const int tloc = (tid >> 5) & 1;
  const int rg = __builtin_amdgcn_readfirstlane(tid >> 6);
  const int t = t0 + tloc;

  __shared__ float hl[C_][4][32];

  for (int idx = tid; idx < C_ * 4 * 32; idx += 256) {
    int i = idx >> 7, r = idx & 127, sl = r >> 5, vv = r & 31;
    int tg = t0 - 1 + sl;
    hl[i][sl][vv] = (vv < V_ && tg >= 0 && tg < T_)
                    ? h2g[((size_t)(n * CO_ + i) * T_ + tg) * V_ + vv] : 0.f;
  }
  __syncthreads();

  float acc[16];
#pragma unroll
  for (int oo = 0; oo < 16; ++oo) acc[oo] = 0.f;
#pragma unroll 1
  for (int ic = 0; ic < 4; ++ic) {
    float h[16][3];
#pragma unroll
    for (int ii = 0; ii < 16; ++ii) {
      h[ii][0] = hl[ic * 16 + ii][tloc][v];
      h[ii][1] = hl[ic * 16 + ii][tloc + 1][v];
      h[ii][2] = hl[ic * 16 + ii][tloc + 2][v];
    }
#pragma unroll
    for (int oo = 0; oo < 16; ++oo) {
      const float* wr = w_t + ((size_t)(rg * 16 + oo) * C_ + ic * 16) * 3;
      float s = acc[oo];
#pragma unroll
      for (int ii = 0; ii < 16; ++ii) {
        s += wr[ii * 3 + 0] * h[ii][0]
           + wr[ii * 3 + 1] * h[ii][1]
           + wr[ii * 3 + 2] * h[ii][2];
      }
      acc[oo] = s;
    }
  }
  if (v < V_) {
#pragma unroll
    for (int oo = 0; oo < 16; ++oo) {
      const int o = rg * 16 + oo;
      float zv = acc[oo] + b_t[o];
      float r = (zv - bn3_m[o]) * (bn3_g[o] * rsqrtf(bn3_v[o] + 1e-5f)) + bn3_b[o]
                + hl[o][tloc + 1][v];
      out[((size_t)(n * CO_ + o) * T_ + t) * V_ + v] = (r >= 0.f) ? r : 0.1f * r;
    }
  }
}

extern "C" void kernel_launch(void* const* d_in, const int* in_sizes, int n_in,
                              void* d_out, int out_size, void* d_ws, size_t ws_size,
                              hipStream_t stream)
{
  (void)in_sizes; (void)n_in; (void)out_size;
  const float* x      = (const float*)d_in[0];
  const float* pe     = (const float*)d_in[1];
  const float* w_in   = (const float*)d_in[2];
  const float* b_in   = (const float*)d_in[3];
  const float* alphas = (const float*)d_in[4];
  const float* att0   = (const float*)d_in[5];
  const float* w_out  = (const float*)d_in[6];
  const float* b_out  = (const float*)d_in[7];
  const float* bn1_g  = (const float*)d_in[8];
  const float* bn1_b  = (const float*)d_in[9];
  const float* bn1_m  = (const float*)d_in[10];
  const float* bn1_v  = (const float*)d_in[11];
  const float* w_ff   = (const float*)d_in[12];
  const float* b_ff   = (const float*)d_in[13];
  const float* bn2_g  = (const float*)d_in[14];
  const float* bn2_b  = (const float*)d_in[15];
  const float* bn2_m  = (const float*)d_in[16];
  const float* bn2_v  = (const float*)d_in[17];
  const float* w_t    = (const float*)d_in[18];
  const float* b_t    = (const float*)d_in[19];
  const float* bn3_g  = (const float*)d_in[20];
  const float* bn3_b  = (const float*)d_in[21];
  const float* bn3_m  = (const float*)d_in[22];
  const float* bn3_v  = (const float*)d_in[23];
  float* out = (float*)d_out;

  char* ws = (char*)d_ws;
  unsigned short* Wb   = (unsigned short*)(ws);              // 57,344 B
  float*          cst  = (float*)(ws + 57344);               // 1,792 B
  unsigned short* attT = (unsigned short*)(ws + 59136);      // 131,072 B
  unsigned short* qkT  = (unsigned short*)(ws + 190208);     // 52,428,800 B
  unsigned short* h2T  = (unsigned short*)(ws + 52619008);   // 44,630,016 B
  const size_t need_mfma = 97249024;
  const size_t need_old  = ((size_t)N_ * NCHUNK * ATT_N + (size_t)N_ * ATT_N
                            + (size_t)N_ * CO_ * T_ * V_) * sizeof(float);

  if (ws_size >= need_mfma) {
    kprep<<<64, 256, 0, stream>>>(w_out, w_ff, w_t, w_in, b_out, b_ff, b_t, b_in,
        bn1_g, bn1_b, bn1_m, bn1_v, bn2_g, bn2_b, bn2_m, bn2_v,
        bn3_g, bn3_b, bn3_m, bn3_v, Wb, cst, h2T);
    k1a2<<<dim3(N_, PTILES), 256, 0, stream>>>(x, pe, Wb, cst, qkT);
    k1b<<<64, 256, 0, stream>>>(qkT, alphas, att0, attT);
    kz4b<<<dim3(N_, T_ / 2), 256, 0, stream>>>(x, attT, Wb, cst, h2T);
    k4c<<<dim3(N_, PTILES), 256, 0, stream>>>(h2T, Wb + 12288, cst, out);
  } else if (ws_size >= need_old) {
    float* partial = (float*)ws;
    float* att     = partial + (size_t)N_ * NCHUNK * ATT_N;
    float* h2g     = att + (size_t)N_ * ATT_N;
    k1_qk_partial<<<dim3(N_, NCHUNK), 256, 0, stream>>>(x, pe, w_in, b_in, partial);
    k2_att_fin<<<(N_ * ATT_N + 255) / 256, 256, 0, stream>>>(partial, alphas, att0, att);
    k3a<<<dim3(N_, T_ / 2), 256, 0, stream>>>(x, att,
        w_out, b_out, bn1_g, bn1_b, bn1_m, bn1_v,
        w_ff, b_ff, bn2_g, bn2_b, bn2_m, bn2_v, h2g);
    k3b<<<dim3(N_, T_ / 2), 256, 0, stream>>>(h2g, w_t, b_t,
        bn3_g, bn3_b, bn3_m, bn3_v, out);
  }
}

// Round 7
// 175.394 us; speedup vs baseline: 7.7599x; 1.1234x over previous
//
#include <hip/hip_runtime.h>

#define N_ 32
#define C_ 64
#define T_ 400
#define V_ 27
#define S_ 2
#define CI_ 16
#define CO_ 64
#define TCHUNK 8
#define NCHUNK 50
#define ATT_N 1458           // S_*V_*V_
#define P_ 10800             // T_*V_
#define PT_ 10816            // 169*64
#define PTILES 169
#define HGUARD 32
#define HROWS 10896          // HGUARD + P_ + 64

typedef short bhalf8 __attribute__((ext_vector_type(8)));
typedef float fx4 __attribute__((ext_vector_type(4)));

static __device__ inline unsigned short f2bf(float f) {
  unsigned u = __builtin_bit_cast(unsigned, f);
  u += 0x7fffu + ((u >> 16) & 1u);
  return (unsigned short)(u >> 16);
}
static __device__ inline float bf2f(unsigned short h) {
  unsigned u = ((unsigned)h) << 16;
  return __builtin_bit_cast(float, u);
}

// ================= MFMA path =================

// kprep: bf16 weights (Wout|Wff|Wt|Wi), fused bn consts + b_in, zero h2T guards
__global__ __launch_bounds__(256) void kprep(
    const float* __restrict__ w_out, const float* __restrict__ w_ff,
    const float* __restrict__ w_t, const float* __restrict__ w_in,
    const float* __restrict__ b_out, const float* __restrict__ b_ff,
    const float* __restrict__ b_t, const float* __restrict__ b_in,
    const float* __restrict__ bn1_g, const float* __restrict__ bn1_b,
    const float* __restrict__ bn1_m, const float* __restrict__ bn1_v,
    const float* __restrict__ bn2_g, const float* __restrict__ bn2_b,
    const float* __restrict__ bn2_m, const float* __restrict__ bn2_v,
    const float* __restrict__ bn3_g, const float* __restrict__ bn3_b,
    const float* __restrict__ bn3_m, const float* __restrict__ bn3_v,
    unsigned short* __restrict__ Wb, float* __restrict__ cst,
    unsigned short* __restrict__ h2Tg)
{
  const int tid = threadIdx.x;
  const int bid = blockIdx.x;
  uint4 z; z.x = 0; z.y = 0; z.z = 0; z.w = 0;
  for (int i = bid * 256 + tid; i < N_ * 768; i += 64 * 256) {
    int n = i / 768, r = i - n * 768;
    size_t off = (r < 256) ? (size_t)r * 8 : (size_t)10832 * 64 + (size_t)(r - 256) * 8;
    *reinterpret_cast<uint4*>(h2Tg + (size_t)n * HROWS * 64 + off) = z;
  }
  if (bid != 0) return;
  for (int i = tid; i < 8192; i += 256) Wb[i] = f2bf(w_out[i]);
  for (int i = tid; i < 4096; i += 256) Wb[8192 + i] = f2bf(w_ff[i]);
  for (int i = tid; i < 12288; i += 256) {
    int o = i / 192, r = i - o * 192, dt = r >> 6, ic = r & 63;
    Wb[12288 + i] = f2bf(w_t[(size_t)(o * 64 + ic) * 3 + dt]);
  }
  for (int i = tid; i < 4096; i += 256) Wb[24576 + i] = f2bf(w_in[i]);
  if (tid < 64) {
    int o = tid;
    float a1 = bn1_g[o] * rsqrtf(bn1_v[o] + 1e-5f);
    cst[o] = a1;
    cst[64 + o] = (b_out[o] - bn1_m[o]) * a1 + bn1_b[o];
    float a2 = bn2_g[o] * rsqrtf(bn2_v[o] + 1e-5f);
    cst[128 + o] = a2;
    cst[192 + o] = (b_ff[o] - bn2_m[o]) * a2 + bn2_b[o];
    float a3 = bn3_g[o] * rsqrtf(bn3_v[o] + 1e-5f);
    cst[256 + o] = a3;
    cst[320 + o] = (b_t[o] - bn3_m[o]) * a3 + bn3_b[o];
    cst[384 + o] = b_in[o];
  }
}

// k1a2: fused (x+pe) stage + qk = Wi . y  -> qk2[n][m][p][ci16] bf16 (p-major, coalesced)
__global__ __launch_bounds__(256) void k1a2(
    const float* __restrict__ x, const float* __restrict__ pe,
    const unsigned short* __restrict__ Wb,
    const float* __restrict__ cst,
    unsigned short* __restrict__ qk2)
{
  const int n = blockIdx.x;
  const int p0 = blockIdx.y * 64;
  const int tid = threadIdx.x;
  const int w = tid >> 6;
  const int l = tid & 63;
  const int cl = l & 15;
  const int lq = l >> 4;
  const int p = p0 + w * 16 + cl;
  const int rl = w * 16 + cl;

  __shared__ float xl[64][65];
  __shared__ float clds[64];
  if (tid < 64) clds[tid] = cst[384 + tid];

  {
    int c = tid >> 2, ch = tid & 3;
    const float* xr = x + (size_t)(n * C_ + c) * P_;
    const float* pr = pe + (size_t)c * P_;
    if (p0 + 64 <= P_) {
#pragma unroll
      for (int q = 0; q < 4; ++q) {
        int pp = p0 + ch * 16 + q * 4;
        float4 a = *reinterpret_cast<const float4*>(xr + pp);
        float4 b = *reinterpret_cast<const float4*>(pr + pp);
        xl[c][ch * 16 + q * 4 + 0] = a.x + b.x;
        xl[c][ch * 16 + q * 4 + 1] = a.y + b.y;
        xl[c][ch * 16 + q * 4 + 2] = a.z + b.z;
        xl[c][ch * 16 + q * 4 + 3] = a.w + b.w;
      }
    } else {
#pragma unroll
      for (int j = 0; j < 16; ++j) {
        int pp = p0 + ch * 16 + j;
        xl[c][ch * 16 + j] = (pp < P_) ? (xr[pp] + pr[pp]) : 0.f;
      }
    }
  }
  __syncthreads();

  bhalf8 bfr[2];
#pragma unroll
  for (int ks = 0; ks < 2; ++ks)
#pragma unroll
    for (int j = 0; j < 8; ++j)
      bfr[ks][j] = (short)f2bf(xl[ks * 32 + lq * 8 + j][rl]);

  const unsigned short* Wi = Wb + 24576;
  fx4 acc[4];
#pragma unroll
  for (int m = 0; m < 4; ++m) { acc[m][0]=0.f; acc[m][1]=0.f; acc[m][2]=0.f; acc[m][3]=0.f; }
#pragma unroll
  for (int m = 0; m < 4; ++m) {
#pragma unroll
    for (int ks = 0; ks < 2; ++ks) {
      bhalf8 a = *reinterpret_cast<const bhalf8*>(Wi + (m * 16 + cl) * 64 + ks * 32 + lq * 8);
      acc[m] = __builtin_amdgcn_mfma_f32_16x16x32_bf16(a, bfr[ks], acc[m], 0, 0, 0);
    }
  }
  if (p < P_) {
#pragma unroll
    for (int m = 0; m < 4; ++m) {
      unsigned short o0 = f2bf(acc[m][0] + clds[m * 16 + lq * 4 + 0]);
      unsigned short o1 = f2bf(acc[m][1] + clds[m * 16 + lq * 4 + 1]);
      unsigned short o2 = f2bf(acc[m][2] + clds[m * 16 + lq * 4 + 2]);
      unsigned short o3 = f2bf(acc[m][3] + clds[m * 16 + lq * 4 + 3]);
      uint2 d;
      d.x = (unsigned)o0 | ((unsigned)o1 << 16);
      d.y = (unsigned)o2 | ((unsigned)o3 << 16);
      *reinterpret_cast<uint2*>(qk2 + ((size_t)(n * 4 + m) * PT_ + p) * 16 + lq * 4) = d;
    }
  }
}

// k1b: att partial GEMM; block=(ns, kq): K quadrant of 1600. Writes fp32 partials.
__global__ __launch_bounds__(256) void k1b(
    const unsigned short* __restrict__ qk2,
    float* __restrict__ pws)
{
  const int ns = blockIdx.x;           // n*2+s
  const int kq = blockIdx.y;           // 0..3
  const int n = ns >> 1, s = ns & 1;
  const int tid = threadIdx.x;
  const int w = tid >> 6;
  const int l = tid & 63;
  const int cl = l & 15;
  const int lq = l >> 4;

  const unsigned short* qb = qk2 + (size_t)(n * 4 + s) * PT_ * 16;
  const unsigned short* kb = qk2 + (size_t)(n * 4 + 2 + s) * PT_ * 16;
  const int ci0 = (lq & 1) * 8;
  const int tof = lq >> 1;

  fx4 acc[2][2];
#pragma unroll
  for (int a1 = 0; a1 < 2; ++a1)
#pragma unroll
    for (int a2 = 0; a2 < 2; ++a2) { acc[a1][a2][0]=0.f; acc[a1][a2][1]=0.f; acc[a1][a2][2]=0.f; acc[a1][a2][3]=0.f; }

  // chunks c of 32 K-elems; block covers [kq*50, kq*50+50), wave-strided
  for (int c = kq * 50 + w; c < kq * 50 + 50; c += 4) {
    const int t = c * 2 + tof;
    const size_t ro = ((size_t)t * 27) * 16 + ci0;
    bhalf8 aq0 = *reinterpret_cast<const bhalf8*>(qb + ro + (size_t)cl * 16);
    bhalf8 aq1 = *reinterpret_cast<const bhalf8*>(qb + ro + (size_t)(16 + cl) * 16);
    bhalf8 bk0 = *reinterpret_cast<const bhalf8*>(kb + ro + (size_t)cl * 16);
    bhalf8 bk1 = *reinterpret_cast<const bhalf8*>(kb + ro + (size_t)(16 + cl) * 16);
    acc[0][0] = __builtin_amdgcn_mfma_f32_16x16x32_bf16(aq0, bk0, acc[0][0], 0, 0, 0);
    acc[0][1] = __builtin_amdgcn_mfma_f32_16x16x32_bf16(aq0, bk1, acc[0][1], 0, 0, 0);
    acc[1][0] = __builtin_amdgcn_mfma_f32_16x16x32_bf16(aq1, bk0, acc[1][0], 0, 0, 0);
    acc[1][1] = __builtin_amdgcn_mfma_f32_16x16x32_bf16(aq1, bk1, acc[1][1], 0, 0, 0);
  }

  __shared__ float red[4][4][4][64];
#pragma unroll
  for (int mt = 0; mt < 2; ++mt)
#pragma unroll
    for (int nt = 0; nt < 2; ++nt)
#pragma unroll
      for (int r = 0; r < 4; ++r)
        red[w][mt * 2 + nt][r][l] = acc[mt][nt][r];
  __syncthreads();

  const int mt = w >> 1, nt = w & 1;
  const int v = nt * 16 + cl;
  float4 o;
  float* op = reinterpret_cast<float*>(&o);
#pragma unroll
  for (int r = 0; r < 4; ++r)
    op[r] = red[0][w][r][l] + red[1][w][r][l] + red[2][w][r][l] + red[3][w][r][l];
  *reinterpret_cast<float4*>(pws + ((size_t)kq * 64 + ns) * 1024 + v * 32 + mt * 16 + lq * 4) = o;
}

// k1c: reduce 4 K-quadrants + tanh finalize -> attT[ns][v32][u32] bf16 (zero-padded)
__global__ __launch_bounds__(256) void k1c(
    const float* __restrict__ pws,
    const float* __restrict__ alphas, const float* __restrict__ att0,
    unsigned short* __restrict__ attT)
{
  int idx = blockIdx.x * 256 + threadIdx.x;   // 0..65535
  int ns = idx >> 10, j = idx & 1023;
  int v = j >> 5, u = j & 31;
  int s = ns & 1;
  float sum = pws[idx] + pws[65536 + idx] + pws[131072 + idx] + pws[196608 + idx];
  float val = 0.f;
  if (u < V_ && v < V_)
    val = tanhf(sum * (1.0f / 6400.0f)) * alphas[s] + att0[(s * V_ + u) * V_ + v];
  attT[idx] = f2bf(val);
}

// kz4b: FUSED x.att (MFMA, Z in LDS) -> Wout -> bn1/res/lrelu -> Wff -> bn2/res/lrelu -> h2T
__global__ __launch_bounds__(256) void kz4b(
    const float* __restrict__ x,
    const unsigned short* __restrict__ attT,
    const unsigned short* __restrict__ Wb,
    const float* __restrict__ cst,
    unsigned short* __restrict__ h2Tg)
{
  const int n = blockIdx.x;
  const int t0 = blockIdx.y * 2;
  const int pbase = t0 * 27;
  const int tid = threadIdx.x;
  const int w = tid >> 6;
  const int l = tid & 63;
  const int cl = l & 15;
  const int lq = l >> 4;

  __shared__ __align__(16) char zstg[16384];
  __shared__ __align__(16) char wout[16384];
  __shared__ __align__(16) char wffl[8192];
  __shared__ short h1t[64 * 64];
  __shared__ float clds[256];
  for (int i = tid; i < 256; i += 256) clds[i] = cst[i];

  for (int i = tid; i < 1024; i += 256) {
    int r = i >> 4, ch = i & 15;
    uint4 d = *reinterpret_cast<const uint4*>(Wb + r * 128 + ch * 8);
    *reinterpret_cast<uint4*>(wout + r * 256 + ((ch * 16) ^ ((r & 7) << 4))) = d;
  }
  for (int i = tid; i < 512; i += 256) {
    int r = i >> 3, ch = i & 7;
    uint4 d = *reinterpret_cast<const uint4*>(Wb + 8192 + r * 64 + ch * 8);
    *reinterpret_cast<uint4*>(wffl + r * 128 + ((ch * 16) ^ ((r & 7) << 4))) = d;
  }
  {
    uint4 z; z.x = 0; z.y = 0; z.z = 0; z.w = 0;
    for (int i = tid; i < 160; i += 256)
      *reinterpret_cast<uint4*>(zstg + 54 * 256 + i * 16) = z;
  }

  {
    const int th = w >> 1;
    const int s = w & 1;
    const int t = t0 + th;
    bhalf8 batt[2];
#pragma unroll
    for (int vt = 0; vt < 2; ++vt)
      batt[vt] = *reinterpret_cast<const bhalf8*>(
          attT + ((size_t)(n * 2 + s) * 32 + vt * 16 + cl) * 32 + lq * 8);
    bhalf8 ax[4];
    if (t * 27 + 31 < P_) {
#pragma unroll
      for (int m = 0; m < 4; ++m) {
        const float* base = x + (size_t)(n * C_ + m * 16 + cl) * P_ + t * 27 + lq * 8;
        float4 f0 = *reinterpret_cast<const float4*>(base);
        float4 f1 = *reinterpret_cast<const float4*>(base + 4);
        ax[m][0] = (short)f2bf(f0.x); ax[m][1] = (short)f2bf(f0.y);
        ax[m][2] = (short)f2bf(f0.z); ax[m][3] = (short)f2bf(f0.w);
        ax[m][4] = (short)f2bf(f1.x); ax[m][5] = (short)f2bf(f1.y);
        ax[m][6] = (short)f2bf(f1.z); ax[m][7] = (short)f2bf(f1.w);
      }
    } else {
#pragma unroll
      for (int m = 0; m < 4; ++m) {
        const float* xr = x + (size_t)(n * C_ + m * 16 + cl) * P_;
#pragma unroll
        for (int j = 0; j < 8; ++j) {
          int idx = t * 27 + lq * 8 + j;
          idx = (idx < P_) ? idx : (P_ - 1);
          ax[m][j] = (short)f2bf(xr[idx]);
        }
      }
    }
#pragma unroll
    for (int vt = 0; vt < 2; ++vt) {
      const int v = vt * 16 + cl;
#pragma unroll
      for (int m = 0; m < 4; ++m) {
        fx4 z; z[0] = 0.f; z[1] = 0.f; z[2] = 0.f; z[3] = 0.f;
        fx4 dacc = __builtin_amdgcn_mfma_f32_16x16x32_bf16(ax[m], batt[vt], z, 0, 0, 0);
        if (v < V_) {
          unsigned short o0 = f2bf(dacc[0]);
          unsigned short o1 = f2bf(dacc[1]);
          unsigned short o2 = f2bf(dacc[2]);
          unsigned short o3 = f2bf(dacc[3]);
          uint2 d;
          d.x = (unsigned)o0 | ((unsigned)o1 << 16);
          d.y = (unsigned)o2 | ((unsigned)o3 << 16);
          int row = th * 27 + v;
          int byteoff = row * 256 + (((s * 64 + m * 16 + lq * 4) * 2) ^ ((row & 7) << 4));
          *reinterpret_cast<uint2*>(zstg + byteoff) = d;
        }
      }
    }
  }
  __syncthreads();

  const int rl = w * 16 + cl;
  const int pidx = pbase + ((rl < 54) ? rl : 53);
  const int swz = (cl & 7) << 4;
  bhalf8 bfr[4];
#pragma unroll
  for (int ks = 0; ks < 4; ++ks)
    bfr[ks] = *reinterpret_cast<const bhalf8*>(zstg + rl * 256 + ((ks * 64 + lq * 16) ^ ((rl & 7) << 4)));
  fx4 acc[4];
#pragma unroll
  for (int m = 0; m < 4; ++m) { acc[m][0]=0.f; acc[m][1]=0.f; acc[m][2]=0.f; acc[m][3]=0.f; }
#pragma unroll
  for (int m = 0; m < 4; ++m) {
    const int row = m * 16 + cl;
#pragma unroll
    for (int ks = 0; ks < 4; ++ks) {
      bhalf8 a = *reinterpret_cast<const bhalf8*>(wout + row * 256 + ((ks * 64 + lq * 16) ^ ((row & 7) << 4)));
      acc[m] = __builtin_amdgcn_mfma_f32_16x16x32_bf16(a, bfr[ks], acc[m], 0, 0, 0);
    }
  }

  float xres[4][4];
#pragma unroll
  for (int m = 0; m < 4; ++m) {
#pragma unroll
    for (int r = 0; r < 4; ++r) {
      int o = m * 16 + lq * 4 + r;
      float xv = x[((size_t)(n * C_ + o)) * (size_t)P_ + pidx];
      xres[m][r] = xv;
      float h = acc[m][r] * clds[o] + clds[64 + o] + xv;
      h = (h >= 0.f) ? h : 0.1f * h;
      int byteoff = rl * 128 + ((o * 2) ^ swz);
      *reinterpret_cast<short*>(reinterpret_cast<char*>(h1t) + byteoff) = (short)f2bf(h);
    }
  }

  fx4 acc2[4];
#pragma unroll
  for (int m = 0; m < 4; ++m) { acc2[m][0]=0.f; acc2[m][1]=0.f; acc2[m][2]=0.f; acc2[m][3]=0.f; }
#pragma unroll
  for (int ks = 0; ks < 2; ++ks) {
    int byteoff = rl * 128 + ((ks * 64 + lq * 16) ^ swz);
    bhalf8 b = *reinterpret_cast<const bhalf8*>(reinterpret_cast<char*>(h1t) + byteoff);
#pragma unroll
    for (int m = 0; m < 4; ++m) {
      const int row = m * 16 + cl;
      bhalf8 a = *reinterpret_cast<const bhalf8*>(wffl + row * 128 + ((ks * 64 + lq * 16) ^ ((row & 7) << 4)));
      acc2[m] = __builtin_amdgcn_mfma_f32_16x16x32_bf16(a, b, acc2[m], 0, 0, 0);
    }
  }

#pragma unroll
  for (int m = 0; m < 4; ++m) {
#pragma unroll
    for (int r = 0; r < 4; ++r) {
      int o = m * 16 + lq * 4 + r;
      float h = acc2[m][r] * clds[128 + o] + clds[192 + o] + xres[m][r];
      h = (h >= 0.f) ? h : 0.1f * h;
      int byteoff = rl * 128 + ((o * 2) ^ swz);
      *reinterpret_cast<short*>(reinterpret_cast<char*>(h1t) + byteoff) = (short)f2bf(h);
    }
  }
  __syncthreads();

  {
    int row = tid >> 2, ch = tid & 3;
    if (row < 54) {
      int sw = (row & 7) << 4;
      uint4 d0 = *reinterpret_cast<uint4*>(reinterpret_cast<char*>(h1t) + row * 128 + (((2 * ch) * 16) ^ sw));
      uint4 d1 = *reinterpret_cast<uint4*>(reinterpret_cast<char*>(h1t) + row * 128 + (((2 * ch + 1) * 16) ^ sw));
      char* dst = reinterpret_cast<char*>(h2Tg) + ((size_t)n * HROWS + HGUARD + pbase + row) * 128 + ch * 32;
      *reinterpret_cast<uint4*>(dst) = d0;
      *reinterpret_cast<uint4*>(dst + 16) = d1;
    }
  }
}

// k4c: LDS-staged temporal conv K=192 MFMA GEMM + bn3/res/lrelu -> out
__global__ __launch_bounds__(256) void k4c(
    const unsigned short* __restrict__ h2Tg,
    const unsigned short* __restrict__ Wtb,
    const float* __restrict__ cst,
    float* __restrict__ out)
{
  const int n = blockIdx.x;
  const int p0 = blockIdx.y * 64;
  const int tid = threadIdx.x;
  const int w = tid >> 6;
  const int l = tid & 63;
  const int cl = l & 15;
  const int lq = l >> 4;
  const int p = p0 + w * 16 + cl;

  __shared__ __align__(16) char hst[16384];
  __shared__ __align__(16) char wst[24576];
  __shared__ float clds[128];
  if (tid < 128) clds[tid] = cst[256 + tid];

  const unsigned short* hbase = h2Tg + ((size_t)n * HROWS + HGUARD + p0 - 32) * 64;
  for (int i = tid; i < 1024; i += 256) {
    int r = i >> 3, ch = i & 7;
    uint4 d = *reinterpret_cast<const uint4*>(hbase + (size_t)r * 64 + ch * 8);
    *reinterpret_cast<uint4*>(hst + r * 128 + ((ch * 16) ^ ((r & 7) << 4))) = d;
  }
  for (int i = tid; i < 1536; i += 256) {
    int r = i / 24, ch = i - r * 24;
    uint4 d = *reinterpret_cast<const uint4*>(Wtb + r * 192 + ch * 8);
    *reinterpret_cast<uint4*>(wst + r * 384 + ((ch * 16) ^ ((r & 7) << 4))) = d;
  }
  __syncthreads();

  const int rl = 32 + w * 16 + cl;
  bhalf8 bfr[6];
#pragma unroll
  for (int ks = 0; ks < 6; ++ks) {
    int k0 = ks * 32 + lq * 8;
    int dt = k0 >> 6;
    int i0 = k0 & 63;
    int rr = rl + (dt - 1) * 27;
    bfr[ks] = *reinterpret_cast<const bhalf8*>(hst + rr * 128 + ((2 * i0) ^ ((rr & 7) << 4)));
  }
  fx4 acc[4];
#pragma unroll
  for (int m = 0; m < 4; ++m) { acc[m][0]=0.f; acc[m][1]=0.f; acc[m][2]=0.f; acc[m][3]=0.f; }
#pragma unroll
  for (int m = 0; m < 4; ++m) {
    const int row = m * 16 + cl;
#pragma unroll
    for (int ks = 0; ks < 6; ++ks) {
      bhalf8 a = *reinterpret_cast<const bhalf8*>(wst + row * 384 + ((ks * 64 + lq * 16) ^ ((row & 7) << 4)));
      acc[m] = __builtin_amdgcn_mfma_f32_16x16x32_bf16(a, bfr[ks], acc[m], 0, 0, 0);
    }
  }
  if (p < P_) {
#pragma unroll
    for (int m = 0; m < 4; ++m) {
      uint2 hr = *reinterpret_cast<uint2*>(hst + rl * 128 + (((m * 16 + lq * 4) * 2) ^ ((rl & 7) << 4)));
      float hc[4];
      hc[0] = bf2f((unsigned short)(hr.x & 0xffff));
      hc[1] = bf2f((unsigned short)(hr.x >> 16));
      hc[2] = bf2f((unsigned short)(hr.y & 0xffff));
      hc[3] = bf2f((unsigned short)(hr.y >> 16));
#pragma unroll
      for (int r = 0; r < 4; ++r) {
        int o = m * 16 + lq * 4 + r;
        float val = acc[m][r] * clds[o] + clds[64 + o] + hc[r];
        val = (val >= 0.f) ? val : 0.1f * val;
        out[((size_t)(n * CO_ + o)) * (size_t)P_ + p] = val;
      }
    }
  }
}

// ================= fallback path =================
__global__ __launch_bounds__(256) void k1_qk_partial(
    const float* __restrict__ x, const float* __restrict__ pe,
    const float* __restrict__ w_in, const float* __restrict__ b_in,
    float* __restrict__ partial)
{
  const int n = blockIdx.x;
  const int chunk = blockIdx.y;
  const int tid = threadIdx.x;
  __shared__ float ylds[C_][28];
  __shared__ float qlds[C_][28];
  __shared__ float wlds[C_][65];
  for (int i = tid; i < C_ * C_; i += 256) wlds[i >> 6][i & 63] = w_in[i];
  float acc[6];
#pragma unroll
  for (int j = 0; j < 6; ++j) acc[j] = 0.f;
  const int t0 = chunk * TCHUNK;
  for (int tt = 0; tt < TCHUNK; ++tt) {
    const int t = t0 + tt;
    __syncthreads();
    for (int i = tid; i < C_ * V_; i += 256) {
      int c = i / V_, v = i - c * V_;
      ylds[c][v] = x[((size_t)(n * C_ + c) * T_ + t) * V_ + v] + pe[(c * T_ + t) * V_ + v];
    }
    __syncthreads();
    for (int i = tid; i < C_ * V_; i += 256) {
      int o = i / V_, v = i - o * V_;
      float s = b_in[o];
#pragma unroll
      for (int c = 0; c < C_; ++c) s += wlds[o][c] * ylds[c][v];
      qlds[o][v] = s;
    }
    __syncthreads();
#pragma unroll
    for (int j = 0; j < 6; ++j) {
      int i = tid + j * 256;
      if (i < ATT_N) {
        int s = i / 729, r = i - s * 729, u = r / 27, v = r - u * 27;
        float a = 0.f;
#pragma unroll
        for (int c = 0; c < CI_; ++c)
          a += qlds[s * CI_ + c][u] * qlds[S_ * CI_ + s * CI_ + c][v];
        acc[j] += a;
      }
    }
  }
  float* dst = partial + (size_t)(n * NCHUNK + chunk) * ATT_N;
#pragma unroll
  for (int j = 0; j < 6; ++j) {
    int i = tid + j * 256;
    if (i < ATT_N) dst[i] = acc[j];
  }
}

__global__ __launch_bounds__(256) void k2_att_fin(
    const float* __restrict__ partial, const float* __restrict__ alphas,
    const float* __restrict__ att0, float* __restrict__ att)
{
  int i = blockIdx.x * 256 + threadIdx.x;
  if (i >= N_ * ATT_N) return;
  int n = i / ATT_N, r = i - n * ATT_N;
  int s = r / 729;
  float a = 0.f;
  const float* p = partial + (size_t)n * NCHUNK * ATT_N + r;
  for (int ch = 0; ch < NCHUNK; ++ch) a += p[(size_t)ch * ATT_N];
  a = tanhf(a * (1.0f / (CI_ * (float)T_))) * alphas[s] + att0[r];
  att[i] = a;
}

__global__ __launch_bounds__(256) void k3a(
    const float* __restrict__ x, const float* __restrict__ att,
    const float* __restrict__ w_out, const float* __restrict__ b_out,
    const float* __restrict__ bn1_g, const float* __restrict__ bn1_b,
    const float* __restrict__ bn1_m, const float* __restrict__ bn1_v,
    const float* __restrict__ w_ff, const float* __restrict__ b_ff,
    const float* __restrict__ bn2_g, const float* __restrict__ bn2_b,
    const float* __restrict__ bn2_m, const float* __restrict__ bn2_v,
    float* __restrict__ h2g)
{
  const int n = blockIdx.x;
  const int t0 = blockIdx.y * 2;
  const int tid = threadIdx.x;
  const int v = tid & 31;
  const int tloc = (tid >> 5) & 1;
  const int col = tid & 63;
  const int rg = __builtin_amdgcn_readfirstlane(tid >> 6);
  const int t = t0 + tloc;

  __shared__ float xlds[C_][64];
  __shared__ float zlds[S_ * C_][64];

  for (int i = tid; i < C_ * 64; i += 256) {
    int c = i >> 6, cl = i & 63, tl = cl >> 5, vv = cl & 31;
    xlds[c][cl] = (vv < V_) ? x[((size_t)(n * C_ + c) * T_ + t0 + tl) * V_ + vv] : 0.f;
  }
  float attreg[S_][V_];
  {
    const float* ab = att + (size_t)n * ATT_N + v;
#pragma unroll
    for (int s = 0; s < S_; ++s)
#pragma unroll
      for (int u = 0; u < V_; ++u)
        attreg[s][u] = (v < V_) ? ab[s * 729 + u * 27] : 0.f;
  }
  __syncthreads();
#pragma unroll 1
  for (int cc = 0; cc < 16; ++cc) {
    const int c = rg * 16 + cc;
    float xr[V_];
#pragma unroll
    for (int u = 0; u < V_; ++u) xr[u] = xlds[c][tloc * 32 + u];
    float a0 = 0.f, a1 = 0.f;
#pragma unroll
    for (int u = 0; u < V_; ++u) {
      a0 += xr[u] * attreg[0][u];
      a1 += xr[u] * attreg[1][u];
    }
    zlds[c][col] = a0;
    zlds[C_ + c][col] = a1;
  }
  __syncthreads();
  float acc[16];
#pragma unroll
  for (int oo = 0; oo < 16; ++oo) acc[oo] = 0.f;
#pragma unroll 1
  for (int kc = 0; kc < 4; ++kc) {
    float zk[32];
#pragma unroll
    for (int j = 0; j < 32; ++j) zk[j] = zlds[kc * 32 + j][col];
#pragma unroll
    for (int oo = 0; oo < 16; ++oo) {
      const float* wr = w_out + (rg * 16 + oo) * (S_ * C_) + kc * 32;
      float s = acc[oo];
#pragma unroll
      for (int j = 0; j < 32; ++j) s += wr[j] * zk[j];
      acc[oo] = s;
    }
  }
  float h1v[16];
#pragma unroll
  for (int oo = 0; oo < 16; ++oo) {
    const int o = rg * 16 + oo;
    float y3 = acc[oo] + b_out[o];
    float h = (y3 - bn1_m[o]) * (bn1_g[o] * rsqrtf(bn1_v[o] + 1e-5f)) + bn1_b[o]
              + xlds[o][col];
    h1v[oo] = (h >= 0.f) ? h : 0.1f * h;
  }
  __syncthreads();
#pragma unroll
  for (int oo = 0; oo < 16; ++oo) zlds[rg * 16 + oo][col] = h1v[oo];
  __syncthreads();
#pragma unroll
  for (int oo = 0; oo < 16; ++oo) acc[oo] = 0.f;
#pragma unroll 1
  for (int kc = 0; kc < 2; ++kc) {
    float zk[32];
#pragma unroll
    for (int j = 0; j < 32; ++j) zk[j] = zlds[kc * 32 + j][col];
#pragma unroll
    for (int oo = 0; oo < 16; ++oo) {
      const float* wr = w_ff + (rg * 16 + oo) * C_ + kc * 32;
      float s = acc[oo];
#pragma unroll
      for (int j = 0; j < 32; ++j) s += wr[j] * zk[j];
      acc[oo] = s;
    }
  }
  if (v < V_) {
#pragma unroll
    for (int oo = 0; oo < 16; ++oo) {
      const int o = rg * 16 + oo;
      float f = acc[oo] + b_ff[o];
      float h = (f - bn2_m[o]) * (bn2_g[o] * rsqrtf(bn2_v[o] + 1e-5f)) + bn2_b[o]
                + xlds[o][col];
      h2g[((size_t)(n * CO_ + o) * T_ + t) * V_ + v] = (h >= 0.f) ? h : 0.1f * h;
    }
  }
}

__global__ __launch_bounds__(256) void k3b(
    const float* __restrict__ h2g, const float* __restrict__ w_t,
    const float* __restrict__ b_t,
    const float* __restrict__ bn3_g, const float* __restrict__ bn3_b,
    const float* __restrict__ bn3_m, const float* __restrict__ bn3_v,
    float* __restrict__ out)
{
  const int n = blockIdx.x;
  const int t0 = blockIdx.y * 2;
  const int tid = threadIdx.x;
  const int v = tid & 31;
  const int tloc = (tid >> 5) & 1;
  const int rg = __builtin_amdgcn_readfirstlane(tid >> 6);
  const int t = t0 + tloc;

  __shared__ float hl[C_][4][32];

  for (int idx = tid; idx < C_ * 4 * 32; idx += 256) {
    int i = idx >> 7, r = idx & 127, sl = r >> 5, vv = r & 31;
    int tg = t0 - 1 + sl;
    hl[i][sl][vv] = (vv < V_ && tg >= 0 && tg < T_)
                    ? h2g[((size_t)(n * CO_ + i) * T_ + tg) * V_ + vv] : 0.f;
  }
  __syncthreads();

  float acc[16];
#pragma unroll
  for (int oo = 0; oo < 16; ++oo) acc[oo] = 0.f;
#pragma unroll 1
  for (int ic = 0; ic < 4; ++ic) {
    float h[16][3];
#pragma unroll
    for (int ii = 0; ii < 16; ++ii) {
      h[ii][0] = hl[ic * 16 + ii][tloc][v];
      h[ii][1] = hl[ic * 16 + ii][tloc + 1][v];
      h[ii][2] = hl[ic * 16 + ii][tloc + 2][v];
    }
#pragma unroll
    for (int oo = 0; oo < 16; ++oo) {
      const float* wr = w_t + ((size_t)(rg * 16 + oo) * C_ + ic * 16) * 3;
      float s = acc[oo];
#pragma unroll
      for (int ii = 0; ii < 16; ++ii) {
        s += wr[ii * 3 + 0] * h[ii][0]
           + wr[ii * 3 + 1] * h[ii][1]
           + wr[ii * 3 + 2] * h[ii][2];
      }
      acc[oo] = s;
    }
  }
  if (v < V_) {
#pragma unroll
    for (int oo = 0; oo < 16; ++oo) {
      const int o = rg * 16 + oo;
      float zv = acc[oo] + b_t[o];
      float r = (zv - bn3_m[o]) * (bn3_g[o] * rsqrtf(bn3_v[o] + 1e-5f)) + bn3_b[o]
                + hl[o][tloc + 1][v];
      out[((size_t)(n * CO_ + o) * T_ + t) * V_ + v] = (r >= 0.f) ? r : 0.1f * r;
    }
  }
}

extern "C" void kernel_launch(void* const* d_in, const int* in_sizes, int n_in,
                              void* d_out, int out_size, void* d_ws, size_t ws_size,
                              hipStream_t stream)
{
  (void)in_sizes; (void)n_in; (void)out_size;
  const float* x      = (const float*)d_in[0];
  const float* pe     = (const float*)d_in[1];
  const float* w_in   = (const float*)d_in[2];
  const float* b_in   = (const float*)d_in[3];
  const float* alphas = (const float*)d_in[4];
  const float* att0   = (const float*)d_in[5];
  const float* w_out  = (const float*)d_in[6];
  const float* b_out  = (const float*)d_in[7];
  const float* bn1_g  = (const float*)d_in[8];
  const float* bn1_b  = (const float*)d_in[9];
  const float* bn1_m  = (const float*)d_in[10];
  const float* bn1_v  = (const float*)d_in[11];
  const float* w_ff   = (const float*)d_in[12];
  const float* b_ff   = (const float*)d_in[13];
  const float* bn2_g  = (const float*)d_in[14];
  const float* bn2_b  = (const float*)d_in[15];
  const float* bn2_m  = (const float*)d_in[16];
  const float* bn2_v  = (const float*)d_in[17];
  const float* w_t    = (const float*)d_in[18];
  const float* b_t    = (const float*)d_in[19];
  const float* bn3_g  = (const float*)d_in[20];
  const float* bn3_b  = (const float*)d_in[21];
  const float* bn3_m  = (const float*)d_in[22];
  const float* bn3_v  = (const float*)d_in[23];
  float* out = (float*)d_out;

  char* ws = (char*)d_ws;
  unsigned short* Wb   = (unsigned short*)(ws);              // 57,344 B
  float*          cst  = (float*)(ws + 57344);               // 1,792 B
  unsigned short* attT = (unsigned short*)(ws + 59136);      // 131,072 B
  float*          pws  = (float*)(ws + 190208);              // 1,048,576 B
  unsigned short* qk2  = (unsigned short*)(ws + 1238784);    // 44,302,336 B
  unsigned short* h2T  = (unsigned short*)(ws + 45541120);   // 44,630,016 B
  const size_t need_mfma = 90171136;
  const size_t need_old  = ((size_t)N_ * NCHUNK * ATT_N + (size_t)N_ * ATT_N
                            + (size_t)N_ * CO_ * T_ * V_) * sizeof(float);

  if (ws_size >= need_mfma) {
    kprep<<<64, 256, 0, stream>>>(w_out, w_ff, w_t, w_in, b_out, b_ff, b_t, b_in,
        bn1_g, bn1_b, bn1_m, bn1_v, bn2_g, bn2_b, bn2_m, bn2_v,
        bn3_g, bn3_b, bn3_m, bn3_v, Wb, cst, h2T);
    k1a2<<<dim3(N_, PTILES), 256, 0, stream>>>(x, pe, Wb, cst, qk2);
    k1b<<<dim3(64, 4), 256, 0, stream>>>(qk2, pws);
    k1c<<<256, 256, 0, stream>>>(pws, alphas, att0, attT);
    kz4b<<<dim3(N_, T_ / 2), 256, 0, stream>>>(x, attT, Wb, cst, h2T);
    k4c<<<dim3(N_, PTILES), 256, 0, stream>>>(h2T, Wb + 12288, cst, out);
  } else if (ws_size >= need_old) {
    float* partial = (float*)ws;
    float* att     = partial + (size_t)N_ * NCHUNK * ATT_N;
    float* h2g     = att + (size_t)N_ * ATT_N;
    k1_qk_partial<<<dim3(N_, NCHUNK), 256, 0, stream>>>(x, pe, w_in, b_in, partial);
    k2_att_fin<<<(N_ * ATT_N + 255) / 256, 256, 0, stream>>>(partial, alphas, att0, att);
    k3a<<<dim3(N_, T_ / 2), 256, 0, stream>>>(x, att,
        w_out, b_out, bn1_g, bn1_b, bn1_m, bn1_v,
        w_ff, b_ff, bn2_g, bn2_b, bn2_m, bn2_v, h2g);
    k3b<<<dim3(N_, T_ / 2), 256, 0, stream>>>(h2g, w_t, b_t,
        bn3_g, bn3_b, bn3_m, bn3_v, out);
  }
}